// Round 12
// baseline (1534.971 us; speedup 1.0000x reference)
//
#include <hip/hip_runtime.h>
#include <math.h>

#define DEV static __device__ __forceinline__

DEV float4 ld4(const float* p){ return *(const float4*)p; }
DEV float2 ld2(const float* p){ return *(const float2*)p; }
DEV void   st4(float* p, float4 v){ *(float4*)p = v; }
DEV float4 f4add(float4 a, float4 b){ return make_float4(a.x+b.x,a.y+b.y,a.z+b.z,a.w+b.w); }
DEV float4 f4fma(float s, float4 a, float4 c){ return make_float4(fmaf(s,a.x,c.x),fmaf(s,a.y,c.y),fmaf(s,a.z,c.z),fmaf(s,a.w,c.w)); }

// bf16 helpers (RNE pack, exact unpack)
DEV float  b2f(ushort u){ return __uint_as_float(((unsigned)u) << 16); }
DEV ushort f2b(float f){
    unsigned u = __float_as_uint(f);
    return (ushort)((u + 0x7FFFu + ((u >> 16) & 1u)) >> 16);
}
DEV float4 b2f4(ushort4 v){ return make_float4(b2f(v.x), b2f(v.y), b2f(v.z), b2f(v.w)); }
DEV ushort4 f2b4(float4 v){ ushort4 o; o.x=f2b(v.x); o.y=f2b(v.y); o.z=f2b(v.z); o.w=f2b(v.w); return o; }

typedef __attribute__((ext_vector_type(8))) short short8v;            // 8 bf16 = 4 VGPR
typedef __attribute__((ext_vector_type(8))) unsigned short ushort8v;
typedef __attribute__((ext_vector_type(4))) float f32x4;

DEV short8v ld_a8(const ushort* p){   // 8B-aligned 16B LDS read as 2x b64
    ushort4 a = *(const ushort4*)p;
    ushort4 b = *(const ushort4*)(p+4);
    short8v r;
    r[0]=a.x; r[1]=a.y; r[2]=a.z; r[3]=a.w;
    r[4]=b.x; r[5]=b.y; r[6]=b.z; r[7]=b.w;
    return r;
}

// ---------------- GNN: embedding tables  T[161][128] = emb_f @ W_slice ----------------
__global__ __launch_bounds__(128) void build_tables_k(
    const float* __restrict__ ea, const float* __restrict__ ed, const float* __restrict__ ec,
    const float* __restrict__ eh, const float* __restrict__ ear, const float* __restrict__ ech,
    const float* __restrict__ Wm, float* __restrict__ T)
{
    int r = blockIdx.x, c = threadIdx.x;
    const float* e; int dim, woff, rl;
    if      (r < 120) { e=ea;  dim=64; woff=0;   rl=r; }
    else if (r < 132) { e=ed;  dim=16; woff=64;  rl=r-120; }
    else if (r < 147) { e=ec;  dim=16; woff=80;  rl=r-132; }
    else if (r < 155) { e=eh;  dim=8;  woff=96;  rl=r-147; }
    else if (r < 157) { e=ear; dim=4;  woff=104; rl=r-155; }
    else              { e=ech; dim=4;  woff=108; rl=r-157; }
    float acc = 0.f;
    for (int k = 0; k < dim; ++k) acc += e[rl*dim + k] * Wm[(woff + k)*128 + c];
    T[r*128 + c] = acc;
}

__global__ __launch_bounds__(256) void embed_lookup_k(
    const int* __restrict__ xi, const float* __restrict__ charge,
    const float* __restrict__ T, const float* __restrict__ wq,
    ushort* __restrict__ H, int N)
{
    int t = threadIdx.x;
    int node = blockIdx.x*8 + (t >> 5);
    if (node >= N) return;
    int c = (t & 31)*4;
    const int* xp = xi + node*6;
    float4 acc = ld4(T + (       xp[0])*128 + c);
    acc = f4add(acc, ld4(T + (120+xp[1])*128 + c));
    acc = f4add(acc, ld4(T + (132+xp[2])*128 + c));
    acc = f4add(acc, ld4(T + (147+xp[3])*128 + c));
    acc = f4add(acc, ld4(T + (155+xp[4])*128 + c));
    acc = f4add(acc, ld4(T + (157+xp[5])*128 + c));
    if (charge) acc = f4fma(charge[node], ld4(wq + c), acc);
    *(ushort4*)(H + (size_t)node*128 + c) = f2b4(acc);
}

// ---------------- GCN degree / norm / CSR build ----------------
__global__ void init_deg_k(float* deg, int N){ int i = blockIdx.x*256+threadIdx.x; if (i<N) deg[i]=1.f; }

__global__ void deg_scatter_k(const int* __restrict__ col, const float* __restrict__ ew, float* deg, int E){
    int e = blockIdx.x*256+threadIdx.x; if (e>=E) return;
    unsafeAtomicAdd(deg + col[e], ew ? ew[e] : 1.f);
}

__global__ void dis_k(const float* __restrict__ deg, float* __restrict__ dis, int N){
    int i = blockIdx.x*256+threadIdx.x; if (i<N) dis[i] = 1.f/sqrtf(deg[i]);
}

__global__ void count_in_k(const int* __restrict__ col, int* __restrict__ cnt, int E){
    int e = blockIdx.x*256+threadIdx.x; if (e>=E) return;
    atomicAdd(&cnt[col[e]], 1);
}

// ---- multi-block exclusive scan (3 phases; 1024 elems / block) ----
__global__ __launch_bounds__(256) void blocksum_k(const int* __restrict__ cnt, int* __restrict__ bsum, int N){
    int b = blockIdx.x, t = threadIdx.x;
    int base = b*1024 + t*4;
    int s = 0;
    if (base + 3 < N) { int4 v = *(const int4*)(cnt + base); s = v.x + v.y + v.z + v.w; }
    else { for (int i = 0; i < 4; ++i) { int idx = base + i; if (idx < N) s += cnt[idx]; } }
    __shared__ int red[256];
    red[t] = s; __syncthreads();
    for (int off = 128; off; off >>= 1) { if (t < off) red[t] += red[t+off]; __syncthreads(); }
    if (!t) bsum[b] = red[0];
}

__global__ __launch_bounds__(256) void scan_bsum_k(int* __restrict__ bsum, int NB){
    int t = threadIdx.x;
    __shared__ int sh[256];
    sh[t] = (t < NB) ? bsum[t] : 0;
    __syncthreads();
    for (int off = 1; off < 256; off <<= 1) {
        int v = (t >= off) ? sh[t-off] : 0;
        __syncthreads();
        sh[t] += v;
        __syncthreads();
    }
    if (t < NB) bsum[t] = (t == 0) ? 0 : sh[t-1];
}

__global__ __launch_bounds__(256) void scan_apply_k(int* cur, const int* __restrict__ bsum,
                                                    int* __restrict__ rowptr, int N, int E){
    int b = blockIdx.x, t = threadIdx.x;
    int base = b*1024 + t*4;
    int c[4]; int s = 0;
    #pragma unroll
    for (int i = 0; i < 4; ++i) { int idx = base + i; c[i] = (idx < N) ? cur[idx] : 0; s += c[i]; }
    __shared__ int sh[256];
    sh[t] = s; __syncthreads();
    for (int off = 1; off < 256; off <<= 1) {
        int v = (t >= off) ? sh[t-off] : 0;
        __syncthreads();
        sh[t] += v;
        __syncthreads();
    }
    int run = bsum[b] + ((t == 0) ? 0 : sh[t-1]);
    #pragma unroll
    for (int i = 0; i < 4; ++i) {
        int idx = base + i;
        if (idx < N) { rowptr[idx] = run; cur[idx] = run; run += c[i]; }
    }
    if (b == 0 && t == 0) rowptr[N] = E;
}

__global__ void fill_csr_k(const int* __restrict__ row, const int* __restrict__ col,
                           const float* __restrict__ ew, const float* __restrict__ dis,
                           int* __restrict__ cursor, int* __restrict__ csr_src,
                           float* __restrict__ csr_nrm, int E)
{
    int e = blockIdx.x*256+threadIdx.x; if (e>=E) return;
    int r = row[e], c = col[e];
    int pos = atomicAdd(&cursor[c], 1);
    csr_src[pos] = r;
    csr_nrm[pos] = dis[r] * (ew ? ew[e] : 1.f) * dis[c];
}

// O[i] = bias + dis[i]^2 * H[i] + sum_j nrm_j * H[src_j]   -- bf16 in/out, fp32 math
__global__ __launch_bounds__(256) void gcn_gather_k(
    const ushort* __restrict__ H, const int* __restrict__ rowptr,
    const int* __restrict__ csr_src, const float* __restrict__ csr_nrm,
    const float* __restrict__ dis, const float* __restrict__ bias,
    ushort* __restrict__ O, int N)
{
    int node = blockIdx.x*8 + (threadIdx.x >> 5);
    if (node >= N) return;
    int lane = (threadIdx.x & 31)*4;
    float s = dis[node]; s *= s;
    float4 h = b2f4(*(const ushort4*)(H + (size_t)node*128 + lane));
    float4 b = ld4(bias + lane);
    float4 acc = f4fma(s, h, b);
    int j = rowptr[node], end = rowptr[node+1];
    for (; j + 4 <= end; j += 4) {
        int   s0 = csr_src[j],   s1 = csr_src[j+1], s2 = csr_src[j+2], s3 = csr_src[j+3];
        float n0 = csr_nrm[j],   n1 = csr_nrm[j+1], n2 = csr_nrm[j+2], n3 = csr_nrm[j+3];
        float4 h0 = b2f4(*(const ushort4*)(H + (size_t)s0*128 + lane));
        float4 h1 = b2f4(*(const ushort4*)(H + (size_t)s1*128 + lane));
        float4 h2 = b2f4(*(const ushort4*)(H + (size_t)s2*128 + lane));
        float4 h3 = b2f4(*(const ushort4*)(H + (size_t)s3*128 + lane));
        acc = f4fma(n0, h0, acc);
        acc = f4fma(n1, h1, acc);
        acc = f4fma(n2, h2, acc);
        acc = f4fma(n3, h3, acc);
    }
    for (; j < end; ++j) {
        float4 h0 = b2f4(*(const ushort4*)(H + (size_t)csr_src[j]*128 + lane));
        acc = f4fma(csr_nrm[j], h0, acc);
    }
    *(ushort4*)(O + (size_t)node*128 + lane) = f2b4(acc);
}

// O = relu(A) @ W via bf16 MFMA; A:[N,128] bf16, W:[128,128] f32, O bf16
__global__ __launch_bounds__(256) void gemm_mfma_k(
    const ushort* __restrict__ A, const float* __restrict__ W,
    ushort* __restrict__ O, int N)
{
    __shared__ ushort WsF[16384];
    __shared__ ushort As[64*136];
    int t = threadIdx.x;
    for (int i = t; i < 16384; i += 256) {
        int j = i & 7, col = (i >> 3) & 15, kg = (i >> 7) & 3, ks = (i >> 9) & 3, ct = i >> 11;
        WsF[i] = f2b(W[(ks*32 + kg*8 + j)*128 + ct*16 + col]);
    }
    int row0 = blockIdx.x*64;
    for (int i = t; i < 64*32; i += 256) {
        int r = i >> 5, c4 = (i & 31)*4;
        ushort4 v = *(const ushort4*)(A + (size_t)(row0 + r)*128 + c4);
        v.x = (v.x & 0x8000) ? 0 : v.x;
        v.y = (v.y & 0x8000) ? 0 : v.y;
        v.z = (v.z & 0x8000) ? 0 : v.z;
        v.w = (v.w & 0x8000) ? 0 : v.w;
        *(ushort4*)(As + r*136 + c4) = v;
    }
    __syncthreads();
    int w = t >> 6, l = t & 63;
    int m16 = l & 15, kg = l >> 4;
    short8v af[4];
    #pragma unroll
    for (int ks = 0; ks < 4; ++ks)
        af[ks] = *(const short8v*)(As + (w*16 + m16)*136 + ks*32 + kg*8);
    #pragma unroll
    for (int ct = 0; ct < 8; ++ct) {
        f32x4 acc = {0.f, 0.f, 0.f, 0.f};
        #pragma unroll
        for (int ks = 0; ks < 4; ++ks) {
            short8v bf = *(const short8v*)(WsF + ((ct*4 + ks)*4 + kg)*128 + m16*8);
            acc = __builtin_amdgcn_mfma_f32_16x16x32_bf16(af[ks], bf, acc, 0, 0, 0);
        }
        int col = ct*16 + m16;
        int rbase = row0 + w*16 + kg*4;
        #pragma unroll
        for (int j = 0; j < 4; ++j)
            O[(size_t)(rbase + j)*128 + col] = f2b(acc[j]);
    }
}

// ---------------- mean pool (bf16 input) ----------------
__global__ __launch_bounds__(128) void mean_pool_sum_k(
    const ushort* __restrict__ X, const int* __restrict__ bv,
    float* __restrict__ featp, int chunk, int N)
{
    __shared__ float acc[16*128];
    int t = threadIdx.x;
    for (int b = 0; b < 16; ++b) acc[b*128 + t] = 0.f;
    int i0 = blockIdx.x * chunk;
    int iend = min(i0 + chunk, N);
    int bcur = bv[i0];
    float r = 0.f;
    for (int i = i0; i < iend; ++i) {
        int b = bv[i];
        if (b != bcur) { acc[bcur*128 + t] += r; r = 0.f; bcur = b; }
        r += fmaxf(b2f(X[(size_t)i*128 + t]), 0.f);
    }
    acc[bcur*128 + t] += r;
    for (int b = 0; b < 16; ++b) {
        float v = acc[b*128 + t];
        if (v != 0.f) unsafeAtomicAdd(featp + b*512 + t, v);
    }
}

__global__ void count_batch_k(const int* __restrict__ bv, float* __restrict__ cnt, int N){
    __shared__ int h[16];
    int t = threadIdx.x;
    if (t < 16) h[t] = 0;
    __syncthreads();
    int i = blockIdx.x*256 + t;
    if (i < N) atomicAdd(&h[bv[i]], 1);
    __syncthreads();
    if (t < 16 && h[t]) unsafeAtomicAdd(&cnt[t], (float)h[t]);
}

// ---------------- voxel fp32 NCDHW -> bf16 channels-last [n][64^3][2] ----------------
__global__ __launch_bounds__(256) void cvt_cl0_k(const float* __restrict__ vox, unsigned* __restrict__ out){
    int idx = blockIdx.x*256 + threadIdx.x;       // 16 * 262144
    int n = idx >> 18, v = idx & 262143;
    float a = vox[((size_t)n*2    )*262144 + v];
    float b = vox[((size_t)n*2 + 1)*262144 + v];
    out[idx] = (unsigned)f2b(a) | ((unsigned)f2b(b) << 16);
}

// conv1 weight prepack: k = rowIdx*16 + dx*4 + ci (ci padded 2->4, rows padded 9->10)
// layout [ks 5][kg 4][col 16][j 8]; zero where rowIdx>=9 | dx==3 | ci>=2
__global__ void wfrag1_k(const float* __restrict__ wt, ushort* __restrict__ out){
    int i = blockIdx.x*256 + threadIdx.x;
    if (i >= 2560) return;
    int j = i & 7, col = (i >> 3) & 15, kg = (i >> 7) & 3, ks = i >> 9;
    int rowIdx = ks*2 + (kg >> 1);
    int dx = (kg & 1)*2 + (j >> 2), ci = j & 3;
    ushort v = 0;
    if (rowIdx < 9 && dx < 3 && ci < 2)
        v = f2b(wt[(col*2 + ci)*27 + (rowIdx/3)*9 + (rowIdx%3)*3 + dx]);
    out[i] = v;
}

// conv1 implicit-GEMM MFMA: CL bf16 [n][64^3][2] -> pooled max/min CL [n][32^3][16] + stats
__global__ __launch_bounds__(256) void conv1_mfma_k(
    const ushort* __restrict__ Xcl0, const ushort* __restrict__ wf,
    const float* __restrict__ bias,
    ushort* __restrict__ outmax, ushort* __restrict__ outmin, float* __restrict__ stats)
{
    __shared__ __align__(16) ushort Ast[2896];    // [10z][4y][18x][4ci-pad] (2880) + guard
    __shared__ __align__(16) ushort Bfr[2560];
    __shared__ float red[128];

    int tid = threadIdx.x;
    int n = blockIdx.y;
    int bx = blockIdx.x;
    int xb = bx & 3, yb = (bx >> 2) & 31, zb = bx >> 7;
    int w = tid >> 6, l = tid & 63;
    int col = l & 15, kg = l >> 4;

    for (int i = tid; i < 320; i += 256)
        *(ushort8v*)(Bfr + i*8) = *(const ushort8v*)(wf + i*8);
    // stage 720 positions (10z*4y*18x), 4 ushorts each (2ci + 2 zero-pad)
    for (int i = tid; i < 720; i += 256) {
        int z = i/72, r = i - z*72, y = r/18, x = r - y*18;
        int gz = zb*8 - 1 + z, gy = yb*2 - 1 + y, gx = xb*16 - 1 + x;
        unsigned packed = 0;
        if ((unsigned)gz < 64u && (unsigned)gy < 64u && (unsigned)gx < 64u)
            packed = *(const unsigned*)(Xcl0 + ((((size_t)n << 18) + ((gz*64 + gy)*64 + gx)) << 1));
        *(uint2*)(Ast + i*4) = make_uint2(packed, 0u);
    }
    if (tid < 2) *(uint2*)(Ast + 2880 + tid*4) = make_uint2(0u, 0u);  // zero guard (dx==3 reads)
    __syncthreads();

    int halfoff = (kg & 1)*2;
    f32x4 acc[4];
    #pragma unroll
    for (int mt = 0; mt < 4; ++mt) acc[mt] = (f32x4){0.f,0.f,0.f,0.f};

    #pragma unroll
    for (int ks = 0; ks < 5; ++ks) {
        int rowIdx = ks*2 + (kg >> 1); if (rowIdx >= 9) rowIdx = 0;   // B is zero there
        int kd = rowIdx/3, kh = rowIdx - kd*3;
        int off = kd*288 + kh*72 + (col + halfoff)*4;
        short8v bb = *(const short8v*)(Bfr + (ks*4 + kg)*128 + col*8);
        #pragma unroll
        for (int mt = 0; mt < 4; ++mt) {
            const ushort* p = Ast + (2*w + (mt>>1))*288 + (mt&1)*72 + off;
            short8v a = ld_a8(p);
            acc[mt] = __builtin_amdgcn_mfma_f32_16x16x32_bf16(a, bb, acc[mt], 0, 0, 0);
        }
    }

    int zp = zb*4 + w, yp = yb;
    float bl = bias[col];
    float s = 0.f, q = 0.f;
    float mx0=-1e30f, mx1=-1e30f, mn0=1e30f, mn1=1e30f;
    #pragma unroll
    for (int mt = 0; mt < 4; ++mt)
        #pragma unroll
        for (int j = 0; j < 4; ++j) {
            float v = acc[mt][j] + bl;
            s += v; q = fmaf(v, v, q);
            if (j < 2) { mx0 = fmaxf(mx0, v); mn0 = fminf(mn0, v); }
            else       { mx1 = fmaxf(mx1, v); mn1 = fminf(mn1, v); }
        }
    s += __shfl_xor(s, 16); s += __shfl_xor(s, 32);
    q += __shfl_xor(q, 16); q += __shfl_xor(q, 32);
    if (kg == 0) { red[(w*16 + col)*2] = s; red[(w*16 + col)*2 + 1] = q; }
    size_t ob = ((((size_t)(n*32 + zp))*32 + yp)*32 + xb*8 + kg*2)*16 + col;
    outmax[ob]      = f2b(mx0); outmin[ob]      = f2b(mn0);
    outmax[ob + 16] = f2b(mx1); outmin[ob + 16] = f2b(mn1);
    __syncthreads();
    if (tid < 32) {
        float t = red[tid] + red[32 + tid] + red[64 + tid] + red[96 + tid];
        unsafeAtomicAdd(&stats[tid], t);
    }
}

__global__ void bn_final_k(const float* __restrict__ stats, const float* __restrict__ g,
                           const float* __restrict__ b, float* __restrict__ sc, float* __restrict__ sh,
                           int C, float invN)
{
    int c = threadIdx.x; if (c >= C) return;
    float m = stats[c*2] * invN;
    float v = stats[c*2+1] * invN - m*m;
    float s = g[c] * rsqrtf(v + 1e-5f);
    sc[c] = s; sh[c] = b[c] - m*s;
}

// prepack conv weights into MFMA B-fragment order (bf16), K padded to 448 per ci-half
__global__ void wfrag_k(const float* __restrict__ wt, ushort* __restrict__ out,
                        int CIN, int COT, int total)
{
    int i = blockIdx.x*256 + threadIdx.x;
    if (i >= total) return;
    int per_h = COT*7168;
    int h  = i / per_h;
    int r0 = i - h*per_h;
    int ct = r0 / 7168;
    int r  = r0 - ct*7168;
    int ks = r >> 9;
    int r2 = r & 511;
    int kg = r2 >> 7, col = (r2 >> 3) & 15, j = r2 & 7;
    int k = ks*32 + kg*8 + j;
    int nbr = k >> 4, ci = (k & 15) + h*16;
    out[i] = (nbr < 27) ? f2b(wt[((size_t)(ct*16 + col)*CIN + ci)*27 + nbr]) : (ushort)0;
}

// ---------------- implicit-GEMM MFMA conv + bias + BN-stats + max/min pool -----------
template<int CIHALVES, int COT, int D, int CIN, int COUT>
__global__ __launch_bounds__(256) void conv_mfma_k(
    const ushort* __restrict__ Xcl, const ushort* __restrict__ WfragG,
    const float* __restrict__ bias,
    ushort* __restrict__ outmax, ushort* __restrict__ outmin, float* __restrict__ stats)
{
    constexpr int PD = D/2;
    constexpr int XT = D/16, YT = D/2;
    __shared__ __align__(16) ushort Ast[17280];
    __shared__ __align__(16) ushort Bfr[COT*7168];
    __shared__ float red[4*COT*32];

    int tid = threadIdx.x;
    int n = blockIdx.y;
    int bx = blockIdx.x;
    int xb = bx % XT, yb = (bx/XT) % YT, zb = bx/(XT*YT);
    int w = tid >> 6, l = tid & 63;
    int col = l & 15, kg = l >> 4;

    int laneoff[14];
    #pragma unroll
    for (int ks = 0; ks < 14; ++ks) {
        int nbr = ks*2 + (l >> 5);
        if (nbr >= 27) nbr = 0;
        int dz = nbr/9, r9 = nbr - dz*9, dy = r9/3, dx = r9 - dy*3;
        laneoff[ks] = dz*1728 + dy*432 + (col + dx)*24 + ((l>>4)&1)*8;
    }
    int Mbase[4];
    #pragma unroll
    for (int mt = 0; mt < 4; ++mt)
        Mbase[mt] = (2*w + (mt>>1))*1728 + (mt&1)*432;

    f32x4 acc[4][COT];
    #pragma unroll
    for (int mt = 0; mt < 4; ++mt)
        #pragma unroll
        for (int ct = 0; ct < COT; ++ct)
            acc[mt][ct] = (f32x4){0.f,0.f,0.f,0.f};

    for (int h = 0; h < CIHALVES; ++h) {
        __syncthreads();
        for (int i = tid; i < 1440; i += 256) {
            int vec = i >> 1, hi8 = (i & 1) << 3;
            int z = vec/72, r = vec - z*72, y = r/18, x = r - y*18;
            int gz = zb*8 - 1 + z, gy = yb*2 - 1 + y, gx = xb*16 - 1 + x;
            ushort8v val = {0,0,0,0,0,0,0,0};
            if ((unsigned)gz < (unsigned)D && (unsigned)gy < (unsigned)D && (unsigned)gx < (unsigned)D) {
                size_t gi = (((size_t)n*D*D*D) + ((size_t)gz*D + gy)*D + gx)*CIN + h*16 + hi8;
                val = *(const ushort8v*)(Xcl + gi);
            }
            *(ushort8v*)(Ast + (vec)*24 + hi8) = val;
        }
        for (int i = tid; i < COT*896; i += 256)
            *(ushort8v*)(Bfr + i*8) = *(const ushort8v*)(WfragG + (size_t)h*COT*7168 + i*8);
        __syncthreads();

        #pragma unroll
        for (int ks = 0; ks < 14; ++ks) {
            short8v a[4];
            #pragma unroll
            for (int mt = 0; mt < 4; ++mt)
                a[mt] = *(const short8v*)(Ast + Mbase[mt] + laneoff[ks]);
            short8v bb[COT];
            #pragma unroll
            for (int ct = 0; ct < COT; ++ct)
                bb[ct] = *(const short8v*)(Bfr + ct*7168 + ks*512 + kg*128 + col*8);
            #pragma unroll
            for (int mt = 0; mt < 4; ++mt)
                #pragma unroll
                for (int ct = 0; ct < COT; ++ct)
                    acc[mt][ct] = __builtin_amdgcn_mfma_f32_16x16x32_bf16(a[mt], bb[ct], acc[mt][ct], 0, 0, 0);
        }
    }

    int zp = zb*4 + w, yp = yb;
    #pragma unroll
    for (int ct = 0; ct < COT; ++ct) {
        float bl = bias[ct*16 + col];
        float s = 0.f, q = 0.f;
        float mx0 = -1e30f, mx1 = -1e30f, mn0 = 1e30f, mn1 = 1e30f;
        #pragma unroll
        for (int mt = 0; mt < 4; ++mt) {
            #pragma unroll
            for (int j = 0; j < 4; ++j) {
                float v = acc[mt][ct][j] + bl;
                s += v; q = fmaf(v, v, q);
                if (j < 2) { mx0 = fmaxf(mx0, v); mn0 = fminf(mn0, v); }
                else       { mx1 = fmaxf(mx1, v); mn1 = fminf(mn1, v); }
            }
        }
        s += __shfl_xor(s, 16); s += __shfl_xor(s, 32);
        q += __shfl_xor(q, 16); q += __shfl_xor(q, 32);
        if (kg == 0) {
            red[((w*COT + ct)*16 + col)*2]     = s;
            red[((w*COT + ct)*16 + col)*2 + 1] = q;
        }
        size_t ob = (((size_t)((n*PD + zp)*PD + yp))*PD + xb*8 + kg*2)*COUT + ct*16 + col;
        outmax[ob]        = f2b(mx0);
        outmin[ob]        = f2b(mn0);
        outmax[ob + COUT] = f2b(mx1);
        outmin[ob + COUT] = f2b(mn1);
    }
    __syncthreads();
    if (tid < COT*32) {
        int ct = tid >> 5, r = tid & 31, c2 = r >> 1, sq = r & 1;
        float t = red[((0*COT + ct)*16 + c2)*2 + sq] + red[((1*COT + ct)*16 + c2)*2 + sq]
                + red[((2*COT + ct)*16 + c2)*2 + sq] + red[((3*COT + ct)*16 + c2)*2 + sq];
        unsafeAtomicAdd(&stats[(ct*16 + c2)*2 + sq], t);
    }
}

// channels-last bf16 pooled max/min -> BN+ReLU -> bf16
__global__ __launch_bounds__(256) void bn_select_cl23_k(
    const ushort* __restrict__ mx, const ushort* __restrict__ mn,
    const float* __restrict__ sc, const float* __restrict__ sh,
    ushort* __restrict__ out, int cmask, int total)
{
    int idx = blockIdx.x*256 + threadIdx.x;
    if (idx >= total) return;
    int ci = idx & cmask;
    float s = sc[ci];
    float v = b2f((s >= 0.f) ? mx[idx] : mn[idx]);
    out[idx] = f2b(fmaxf(fmaf(v, s, sh[ci]), 0.f));
}

// fc: X channels-last bf16 [16][512][64]; W k-index = c*512 + sp
__global__ __launch_bounds__(128) void fc_acc_k(
    const ushort* __restrict__ X, const float* __restrict__ W, float* __restrict__ featv)
{
    int t = threadIdx.x;
    int k0 = blockIdx.x*256;
    float acc[16];
    #pragma unroll
    for (int b = 0; b < 16; ++b) acc[b] = 0.f;
    for (int k = k0; k < k0 + 256; ++k) {
        float w = W[(size_t)k*128 + t];
        int c = k >> 9, sp = k & 511;
        #pragma unroll
        for (int b = 0; b < 16; ++b)
            acc[b] = fmaf(b2f(X[(size_t)((b*512 + sp))*64 + c]), w, acc[b]);
    }
    for (int b = 0; b < 16; ++b) unsafeAtomicAdd(featv + b*512 + t, acc[b]);
}

// ---------------- small dense layers ----------------
__global__ __launch_bounds__(256) void head_k(
    const float* __restrict__ X, const float* __restrict__ W, const float* __restrict__ b,
    float* __restrict__ O, int K, int Ncol, int relu)
{
    int t = blockIdx.x*256 + threadIdx.x;
    if (t >= 16*Ncol) return;
    int bi = t / Ncol, c = t % Ncol;
    float acc = b[c];
    for (int k = 0; k < K; ++k) acc = fmaf(X[bi*K + k], W[k*Ncol + c], acc);
    if (relu) acc = fmaxf(acc, 0.f);
    O[bi*Ncol + c] = acc;
}

__global__ void gebn_k(const float* __restrict__ g2, const float* __restrict__ g,
                       const float* __restrict__ b, float* __restrict__ featg)
{
    int c = threadIdx.x;
    float m = 0.f;
    for (int i = 0; i < 16; ++i) m += g2[i*128 + c];
    m *= (1.f/16.f);
    float v = 0.f;
    for (int i = 0; i < 16; ++i) { float d = g2[i*128 + c] - m; v += d*d; }
    v *= (1.f/16.f);
    float s = g[c] * rsqrtf(v + 1e-5f);
    for (int i = 0; i < 16; ++i)
        featg[i*512 + c] = fmaxf((g2[i*128 + c] - m)*s + b[c], 0.f);
}

__global__ void finalize_feat_k(float* __restrict__ feat, const float* __restrict__ cntm,
                                const float* __restrict__ cntz, const float* __restrict__ fcb)
{
    int t = blockIdx.x*256 + threadIdx.x;
    if (t >= 8192) return;
    int bi = t >> 9, c = t & 511;
    float v = feat[t];
    if      (c < 128) v /= fmaxf(cntm[bi], 1.f);
    else if (c < 256) v /= fmaxf(cntz[bi], 1.f);
    else if (c >= 384) v = fmaxf(v + fcb[c - 384], 0.f);
    feat[t] = v;
}

// =====================================================================================
extern "C" void kernel_launch(void* const* d_in, const int* in_sizes, int n_in,
                              void* d_out, int out_size, void* d_ws, size_t ws_size,
                              hipStream_t stream)
{
    const int*   mol_x  = (const int*)  d_in[0];
    const float* mol_q  = (const float*)d_in[1];
    const int*   mol_ei = (const int*)  d_in[2];
    const float* mol_ew = (const float*)d_in[3];
    const int*   mol_bv = (const int*)  d_in[4];
    const int*   zeo_x  = (const int*)  d_in[5];
    const int*   zeo_ei = (const int*)  d_in[6];
    const int*   zeo_bv = (const int*)  d_in[7];
    const float* voxel  = (const float*)d_in[8];
    const float* gattr  = (const float*)d_in[9];
    const float* ea  = (const float*)d_in[10];
    const float* ed  = (const float*)d_in[11];
    const float* ec  = (const float*)d_in[12];
    const float* eh  = (const float*)d_in[13];
    const float* ear = (const float*)d_in[14];
    const float* ech = (const float*)d_in[15];
    const float* mc1w=(const float*)d_in[16]; const float* mc1b=(const float*)d_in[17];
    const float* mc2w=(const float*)d_in[18]; const float* mc2b=(const float*)d_in[19];
    const float* zc1w=(const float*)d_in[20]; const float* zc1b=(const float*)d_in[21];
    const float* zc2w=(const float*)d_in[22]; const float* zc2b=(const float*)d_in[23];
    const float* cv1w=(const float*)d_in[24]; const float* cv1b=(const float*)d_in[25];
    const float* bn1g=(const float*)d_in[26]; const float* bn1b=(const float*)d_in[27];
    const float* cv2w=(const float*)d_in[28]; const float* cv2b=(const float*)d_in[29];
    const float* bn2g=(const float*)d_in[30]; const float* bn2b=(const float*)d_in[31];
    const float* cv3w=(const float*)d_in[32]; const float* cv3b=(const float*)d_in[33];
    const float* bn3g=(const float*)d_in[34]; const float* bn3b=(const float*)d_in[35];
    const float* fcw =(const float*)d_in[36]; const float* fcb =(const float*)d_in[37];
    const float* ge1w=(const float*)d_in[38]; const float* ge1b=(const float*)d_in[39];
    const float* ge2w=(const float*)d_in[40]; const float* ge2b=(const float*)d_in[41];
    const float* gbng=(const float*)d_in[42]; const float* gbnb=(const float*)d_in[43];
    const float* h1w =(const float*)d_in[44]; const float* h1b =(const float*)d_in[45];
    const float* h2w =(const float*)d_in[46]; const float* h2b =(const float*)d_in[47];
    const float* h3w =(const float*)d_in[48]; const float* h3b =(const float*)d_in[49];

    const int Nm = in_sizes[0]/6, Em = in_sizes[2]/2;
    const int Nz = in_sizes[5]/6, Ez = in_sizes[6]/2;
    const int NBm = (Nm + 1023)/1024, NBz = (Nz + 1023)/1024;

    float* WS = (float*)d_ws;
    float* A  = WS;
    float* Bb = WS + 16777216;
    float* S  = WS + 33554432;
    ushort* X0 = (ushort*)A;
    ushort* X1 = (ushort*)A + 16777216;
    ushort* X2 = (ushort*)Bb;
    ushort* X3 = (ushort*)Bb + 16777216;
    // conv-phase channels-last bf16 buffers (GNN buffers dead by then)
    ushort* Au   = (ushort*)A;
    ushort* pm1  = Au;                      // [16][32^3][16]
    ushort* pn1  = Au + 8388608;
    ushort* Xcl0 = Au + 16777216;           // [16][64^3][2]
    ushort* Xcl1 = (ushort*)Bb;             // [16][32^3][16]
    ushort* pm2  = Au;                      // [16][16^3][32]
    ushort* pn2  = Au + 2097152;
    ushort* Xcl2 = Au + 4194304;
    ushort* pm3  = (ushort*)Bb;             // [16][8^3][64]
    ushort* pn3  = (ushort*)Bb + 524288;
    ushort* Xcl3 = (ushort*)Bb + 1048576;
    float* deg  = S;
    float* dis  = S + 131072;
    float* csr_nrm = S + 262144;
    float* T    = S + 786432;
    float* cntm = S + 807040;
    float* cntz = S + 807056;
    float* feat = S + 807072;
    float* st1  = S + 815264; float* st2 = st1 + 32; float* st3 = st1 + 96;
    float* sc1  = S + 815488; float* sh1 = sc1 + 16;
    float* sc2  = sc1 + 32;   float* sh2 = sc1 + 64;
    float* sc3  = sc1 + 96;   float* sh3 = sc1 + 160;
    float* g1   = S + 815712;
    float* g2   = S + 816736;
    float* H1   = S + 818784;
    float* H2   = S + 826976;
    int* rowptr  = (int*)(S + 831072);          // 131073
    int* cursor  = (int*)(S + 962176);          // 131072
    int* csr_src = (int*)(S + 1093248);         // 524288 (ends S+1617536)
    ushort* wf2 = (ushort*)(S + 1617536);       // 14336 ush
    ushort* wf3 = (ushort*)(S + 1624704);       // 57344 ush
    int* bsum   = (int*)(S + 1653376);          // 256 ints
    ushort* wf1 = (ushort*)(S + 1653632);       // 2560 ush (ends S+1654912)

    hipMemsetAsync(S, 0, (size_t)831072*sizeof(float), stream);

    // weight prepacks for MFMA convs
    wfrag1_k<<<10,256,0,stream>>>(cv1w, wf1);
    wfrag_k<<<56,256,0,stream>>>(cv2w, wf2, 16, 2, 14336);
    wfrag_k<<<224,256,0,stream>>>(cv3w, wf3, 32, 4, 57344);

    // ---------------- molecule branch ----------------
    build_tables_k<<<161,128,0,stream>>>(ea,ed,ec,eh,ear,ech, mc1w, T);
    init_deg_k   <<<Nm/256,256,0,stream>>>(deg, Nm);
    deg_scatter_k<<<Em/256,256,0,stream>>>(mol_ei+Em, mol_ew, deg, Em);
    dis_k        <<<Nm/256,256,0,stream>>>(deg, dis, Nm);
    hipMemsetAsync(cursor, 0, (size_t)Nm*sizeof(int), stream);
    count_in_k   <<<Em/256,256,0,stream>>>(mol_ei+Em, cursor, Em);
    blocksum_k   <<<NBm,256,0,stream>>>(cursor, bsum, Nm);
    scan_bsum_k  <<<1,256,0,stream>>>(bsum, NBm);
    scan_apply_k <<<NBm,256,0,stream>>>(cursor, bsum, rowptr, Nm, Em);
    fill_csr_k   <<<Em/256,256,0,stream>>>(mol_ei, mol_ei+Em, mol_ew, dis, cursor, csr_src, csr_nrm, Em);
    embed_lookup_k<<<Nm/8,256,0,stream>>>(mol_x, mol_q, T, mc1w + 112*128, X0, Nm);
    gcn_gather_k <<<Nm/8,256,0,stream>>>(X0, rowptr, csr_src, csr_nrm, dis, mc1b, X1, Nm);
    gemm_mfma_k  <<<Nm/64,256,0,stream>>>(X1, mc2w, X2, Nm);
    gcn_gather_k <<<Nm/8,256,0,stream>>>(X2, rowptr, csr_src, csr_nrm, dis, mc2b, X3, Nm);
    count_batch_k<<<Nm/256,256,0,stream>>>(mol_bv, cntm, Nm);
    mean_pool_sum_k<<<256,128,0,stream>>>(X3, mol_bv, feat + 0, (Nm+255)/256, Nm);

    // ---------------- zeolite branch ----------------
    build_tables_k<<<161,128,0,stream>>>(ea,ed,ec,eh,ear,ech, zc1w, T);
    init_deg_k   <<<Nz/256,256,0,stream>>>(deg, Nz);
    deg_scatter_k<<<Ez/256,256,0,stream>>>(zeo_ei+Ez, nullptr, deg, Ez);
    dis_k        <<<Nz/256,256,0,stream>>>(deg, dis, Nz);
    hipMemsetAsync(cursor, 0, (size_t)Nz*sizeof(int), stream);
    count_in_k   <<<Ez/256,256,0,stream>>>(zeo_ei+Ez, cursor, Ez);
    blocksum_k   <<<NBz,256,0,stream>>>(cursor, bsum, Nz);
    scan_bsum_k  <<<1,256,0,stream>>>(bsum, NBz);
    scan_apply_k <<<NBz,256,0,stream>>>(cursor, bsum, rowptr, Nz, Ez);
    fill_csr_k   <<<Ez/256,256,0,stream>>>(zeo_ei, zeo_ei+Ez, nullptr, dis, cursor, csr_src, csr_nrm, Ez);
    embed_lookup_k<<<Nz/8,256,0,stream>>>(zeo_x, nullptr, T, nullptr, X0, Nz);
    gcn_gather_k <<<Nz/8,256,0,stream>>>(X0, rowptr, csr_src, csr_nrm, dis, zc1b, X1, Nz);
    gemm_mfma_k  <<<Nz/64,256,0,stream>>>(X1, zc2w, X2, Nz);
    gcn_gather_k <<<Nz/8,256,0,stream>>>(X2, rowptr, csr_src, csr_nrm, dis, zc2b, X3, Nz);
    count_batch_k<<<Nz/256,256,0,stream>>>(zeo_bv, cntz, Nz);
    mean_pool_sum_k<<<256,128,0,stream>>>(X3, zeo_bv, feat + 128, (Nz+255)/256, Nz);

    // ---------------- voxel CNN (all layers MFMA implicit-GEMM) ----------------
    cvt_cl0_k<<<16384,256,0,stream>>>(voxel, (unsigned*)Xcl0);
    conv1_mfma_k<<<dim3(1024,16),256,0,stream>>>(Xcl0, wf1, cv1b, pm1, pn1, st1);
    bn_final_k<<<1,64,0,stream>>>(st1, bn1g, bn1b, sc1, sh1, 16, 1.f/(16.f*262144.f));
    bn_select_cl23_k<<<32768,256,0,stream>>>(pm1, pn1, sc1, sh1, Xcl1, 15, 8388608);

    conv_mfma_k<1,2,32,16,32><<<dim3(128,16),256,0,stream>>>(Xcl1, wf2, cv2b, pm2, pn2, st2);
    bn_final_k<<<1,64,0,stream>>>(st2, bn2g, bn2b, sc2, sh2, 32, 1.f/(16.f*32768.f));
    bn_select_cl23_k<<<8192,256,0,stream>>>(pm2, pn2, sc2, sh2, Xcl2, 31, 2097152);

    conv_mfma_k<2,4,16,32,64><<<dim3(16,16),256,0,stream>>>(Xcl2, wf3, cv3b, pm3, pn3, st3);
    bn_final_k<<<1,64,0,stream>>>(st3, bn3g, bn3b, sc3, sh3, 64, 1.f/(16.f*4096.f));
    bn_select_cl23_k<<<2048,256,0,stream>>>(pm3, pn3, sc3, sh3, Xcl3, 63, 524288);

    fc_acc_k<<<128,128,0,stream>>>(Xcl3, fcw, feat + 384);

    // ---------------- global encoder ----------------
    head_k<<<4,256,0,stream>>>(gattr, ge1w, ge1b, g1, 17, 64, 1);
    head_k<<<8,256,0,stream>>>(g1, ge2w, ge2b, g2, 64, 128, 0);
    gebn_k<<<1,128,0,stream>>>(g2, gbng, gbnb, feat + 256);

    // ---------------- fusion head ----------------
    finalize_feat_k<<<32,256,0,stream>>>(feat, cntm, cntz, fcb);
    head_k<<<32,256,0,stream>>>(feat, h1w, h1b, H1, 512, 512, 1);
    head_k<<<16,256,0,stream>>>(H1, h2w, h2b, H2, 512, 256, 1);
    head_k<<<1,256,0,stream>>>(H2, h3w, h3b, (float*)d_out, 256, 3, 0);
}

// Round 13
// 1370.829 us; speedup vs baseline: 1.1197x; 1.1197x over previous
//
#include <hip/hip_runtime.h>
#include <math.h>

#define DEV static __device__ __forceinline__

DEV float4 ld4(const float* p){ return *(const float4*)p; }
DEV float2 ld2(const float* p){ return *(const float2*)p; }
DEV void   st4(float* p, float4 v){ *(float4*)p = v; }
DEV float4 f4add(float4 a, float4 b){ return make_float4(a.x+b.x,a.y+b.y,a.z+b.z,a.w+b.w); }
DEV float4 f4fma(float s, float4 a, float4 c){ return make_float4(fmaf(s,a.x,c.x),fmaf(s,a.y,c.y),fmaf(s,a.z,c.z),fmaf(s,a.w,c.w)); }

// bf16 helpers (RNE pack, exact unpack)
DEV float  b2f(ushort u){ return __uint_as_float(((unsigned)u) << 16); }
DEV ushort f2b(float f){
    unsigned u = __float_as_uint(f);
    return (ushort)((u + 0x7FFFu + ((u >> 16) & 1u)) >> 16);
}
DEV float4 b2f4(ushort4 v){ return make_float4(b2f(v.x), b2f(v.y), b2f(v.z), b2f(v.w)); }
DEV ushort4 f2b4(float4 v){ ushort4 o; o.x=f2b(v.x); o.y=f2b(v.y); o.z=f2b(v.z); o.w=f2b(v.w); return o; }

typedef __attribute__((ext_vector_type(8))) short short8v;            // 8 bf16 = 4 VGPR
typedef __attribute__((ext_vector_type(8))) unsigned short ushort8v;
typedef __attribute__((ext_vector_type(4))) float f32x4;

DEV short8v ld_a8(const ushort* p){   // 8B-aligned 16B LDS read as 2x b64
    ushort4 a = *(const ushort4*)p;
    ushort4 b = *(const ushort4*)(p+4);
    short8v r;
    r[0]=a.x; r[1]=a.y; r[2]=a.z; r[3]=a.w;
    r[4]=b.x; r[5]=b.y; r[6]=b.z; r[7]=b.w;
    return r;
}

// ---------------- GNN: embedding tables  T[161][128] = emb_f @ W_slice ----------------
__global__ __launch_bounds__(128) void build_tables_k(
    const float* __restrict__ ea, const float* __restrict__ ed, const float* __restrict__ ec,
    const float* __restrict__ eh, const float* __restrict__ ear, const float* __restrict__ ech,
    const float* __restrict__ Wm, float* __restrict__ T)
{
    int r = blockIdx.x, c = threadIdx.x;
    const float* e; int dim, woff, rl;
    if      (r < 120) { e=ea;  dim=64; woff=0;   rl=r; }
    else if (r < 132) { e=ed;  dim=16; woff=64;  rl=r-120; }
    else if (r < 147) { e=ec;  dim=16; woff=80;  rl=r-132; }
    else if (r < 155) { e=eh;  dim=8;  woff=96;  rl=r-147; }
    else if (r < 157) { e=ear; dim=4;  woff=104; rl=r-155; }
    else              { e=ech; dim=4;  woff=108; rl=r-157; }
    float acc = 0.f;
    for (int k = 0; k < dim; ++k) acc += e[rl*dim + k] * Wm[(woff + k)*128 + c];
    T[r*128 + c] = acc;
}

__global__ __launch_bounds__(256) void embed_lookup_k(
    const int* __restrict__ xi, const float* __restrict__ charge,
    const float* __restrict__ T, const float* __restrict__ wq,
    ushort* __restrict__ H, int N)
{
    int t = threadIdx.x;
    int node = blockIdx.x*8 + (t >> 5);
    if (node >= N) return;
    int c = (t & 31)*4;
    const int* xp = xi + node*6;
    float4 acc = ld4(T + (       xp[0])*128 + c);
    acc = f4add(acc, ld4(T + (120+xp[1])*128 + c));
    acc = f4add(acc, ld4(T + (132+xp[2])*128 + c));
    acc = f4add(acc, ld4(T + (147+xp[3])*128 + c));
    acc = f4add(acc, ld4(T + (155+xp[4])*128 + c));
    acc = f4add(acc, ld4(T + (157+xp[5])*128 + c));
    if (charge) acc = f4fma(charge[node], ld4(wq + c), acc);
    *(ushort4*)(H + (size_t)node*128 + c) = f2b4(acc);
}

// ---------------- GCN degree / norm / CSR build ----------------
__global__ void init_deg_k(float* deg, int N){ int i = blockIdx.x*256+threadIdx.x; if (i<N) deg[i]=1.f; }

__global__ void deg_scatter_k(const int* __restrict__ col, const float* __restrict__ ew, float* deg, int E){
    int e = blockIdx.x*256+threadIdx.x; if (e>=E) return;
    unsafeAtomicAdd(deg + col[e], ew ? ew[e] : 1.f);
}

__global__ void dis_k(const float* __restrict__ deg, float* __restrict__ dis, int N){
    int i = blockIdx.x*256+threadIdx.x; if (i<N) dis[i] = 1.f/sqrtf(deg[i]);
}

__global__ void count_in_k(const int* __restrict__ col, int* __restrict__ cnt, int E){
    int e = blockIdx.x*256+threadIdx.x; if (e>=E) return;
    atomicAdd(&cnt[col[e]], 1);
}

// ---- multi-block exclusive scan (3 phases; 1024 elems / block) ----
__global__ __launch_bounds__(256) void blocksum_k(const int* __restrict__ cnt, int* __restrict__ bsum, int N){
    int b = blockIdx.x, t = threadIdx.x;
    int base = b*1024 + t*4;
    int s = 0;
    if (base + 3 < N) { int4 v = *(const int4*)(cnt + base); s = v.x + v.y + v.z + v.w; }
    else { for (int i = 0; i < 4; ++i) { int idx = base + i; if (idx < N) s += cnt[idx]; } }
    __shared__ int red[256];
    red[t] = s; __syncthreads();
    for (int off = 128; off; off >>= 1) { if (t < off) red[t] += red[t+off]; __syncthreads(); }
    if (!t) bsum[b] = red[0];
}

__global__ __launch_bounds__(256) void scan_bsum_k(int* __restrict__ bsum, int NB){
    int t = threadIdx.x;
    __shared__ int sh[256];
    sh[t] = (t < NB) ? bsum[t] : 0;
    __syncthreads();
    for (int off = 1; off < 256; off <<= 1) {
        int v = (t >= off) ? sh[t-off] : 0;
        __syncthreads();
        sh[t] += v;
        __syncthreads();
    }
    if (t < NB) bsum[t] = (t == 0) ? 0 : sh[t-1];
}

__global__ __launch_bounds__(256) void scan_apply_k(int* cur, const int* __restrict__ bsum,
                                                    int* __restrict__ rowptr, int N, int E){
    int b = blockIdx.x, t = threadIdx.x;
    int base = b*1024 + t*4;
    int c[4]; int s = 0;
    #pragma unroll
    for (int i = 0; i < 4; ++i) { int idx = base + i; c[i] = (idx < N) ? cur[idx] : 0; s += c[i]; }
    __shared__ int sh[256];
    sh[t] = s; __syncthreads();
    for (int off = 1; off < 256; off <<= 1) {
        int v = (t >= off) ? sh[t-off] : 0;
        __syncthreads();
        sh[t] += v;
        __syncthreads();
    }
    int run = bsum[b] + ((t == 0) ? 0 : sh[t-1]);
    #pragma unroll
    for (int i = 0; i < 4; ++i) {
        int idx = base + i;
        if (idx < N) { rowptr[idx] = run; cur[idx] = run; run += c[i]; }
    }
    if (b == 0 && t == 0) rowptr[N] = E;
}

__global__ void fill_csr_k(const int* __restrict__ row, const int* __restrict__ col,
                           const float* __restrict__ ew, const float* __restrict__ dis,
                           int* __restrict__ cursor, int* __restrict__ csr_src,
                           float* __restrict__ csr_nrm, int E)
{
    int e = blockIdx.x*256+threadIdx.x; if (e>=E) return;
    int r = row[e], c = col[e];
    int pos = atomicAdd(&cursor[c], 1);
    csr_src[pos] = r;
    csr_nrm[pos] = dis[r] * (ew ? ew[e] : 1.f) * dis[c];
}

// O[i] = bias + dis[i]^2 * H[i] + sum_j nrm_j * H[src_j]   -- bf16 in/out, fp32 math
__global__ __launch_bounds__(256) void gcn_gather_k(
    const ushort* __restrict__ H, const int* __restrict__ rowptr,
    const int* __restrict__ csr_src, const float* __restrict__ csr_nrm,
    const float* __restrict__ dis, const float* __restrict__ bias,
    ushort* __restrict__ O, int N)
{
    int node = blockIdx.x*8 + (threadIdx.x >> 5);
    if (node >= N) return;
    int lane = (threadIdx.x & 31)*4;
    float s = dis[node]; s *= s;
    float4 h = b2f4(*(const ushort4*)(H + (size_t)node*128 + lane));
    float4 b = ld4(bias + lane);
    float4 acc = f4fma(s, h, b);
    int j = rowptr[node], end = rowptr[node+1];
    for (; j + 4 <= end; j += 4) {
        int   s0 = csr_src[j],   s1 = csr_src[j+1], s2 = csr_src[j+2], s3 = csr_src[j+3];
        float n0 = csr_nrm[j],   n1 = csr_nrm[j+1], n2 = csr_nrm[j+2], n3 = csr_nrm[j+3];
        float4 h0 = b2f4(*(const ushort4*)(H + (size_t)s0*128 + lane));
        float4 h1 = b2f4(*(const ushort4*)(H + (size_t)s1*128 + lane));
        float4 h2 = b2f4(*(const ushort4*)(H + (size_t)s2*128 + lane));
        float4 h3 = b2f4(*(const ushort4*)(H + (size_t)s3*128 + lane));
        acc = f4fma(n0, h0, acc);
        acc = f4fma(n1, h1, acc);
        acc = f4fma(n2, h2, acc);
        acc = f4fma(n3, h3, acc);
    }
    for (; j < end; ++j) {
        float4 h0 = b2f4(*(const ushort4*)(H + (size_t)csr_src[j]*128 + lane));
        acc = f4fma(csr_nrm[j], h0, acc);
    }
    *(ushort4*)(O + (size_t)node*128 + lane) = f2b4(acc);
}

// O = relu(A) @ W via bf16 MFMA; A:[N,128] bf16, W:[128,128] f32, O bf16
__global__ __launch_bounds__(256) void gemm_mfma_k(
    const ushort* __restrict__ A, const float* __restrict__ W,
    ushort* __restrict__ O, int N)
{
    __shared__ ushort WsF[16384];
    __shared__ ushort As[64*136];
    int t = threadIdx.x;
    for (int i = t; i < 16384; i += 256) {
        int j = i & 7, col = (i >> 3) & 15, kg = (i >> 7) & 3, ks = (i >> 9) & 3, ct = i >> 11;
        WsF[i] = f2b(W[(ks*32 + kg*8 + j)*128 + ct*16 + col]);
    }
    int row0 = blockIdx.x*64;
    for (int i = t; i < 64*32; i += 256) {
        int r = i >> 5, c4 = (i & 31)*4;
        ushort4 v = *(const ushort4*)(A + (size_t)(row0 + r)*128 + c4);
        v.x = (v.x & 0x8000) ? 0 : v.x;
        v.y = (v.y & 0x8000) ? 0 : v.y;
        v.z = (v.z & 0x8000) ? 0 : v.z;
        v.w = (v.w & 0x8000) ? 0 : v.w;
        *(ushort4*)(As + r*136 + c4) = v;
    }
    __syncthreads();
    int w = t >> 6, l = t & 63;
    int m16 = l & 15, kg = l >> 4;
    short8v af[4];
    #pragma unroll
    for (int ks = 0; ks < 4; ++ks)
        af[ks] = *(const short8v*)(As + (w*16 + m16)*136 + ks*32 + kg*8);
    #pragma unroll
    for (int ct = 0; ct < 8; ++ct) {
        f32x4 acc = {0.f, 0.f, 0.f, 0.f};
        #pragma unroll
        for (int ks = 0; ks < 4; ++ks) {
            short8v bf = *(const short8v*)(WsF + ((ct*4 + ks)*4 + kg)*128 + m16*8);
            acc = __builtin_amdgcn_mfma_f32_16x16x32_bf16(af[ks], bf, acc, 0, 0, 0);
        }
        int col = ct*16 + m16;
        int rbase = row0 + w*16 + kg*4;
        #pragma unroll
        for (int j = 0; j < 4; ++j)
            O[(size_t)(rbase + j)*128 + col] = f2b(acc[j]);
    }
}

// ---------------- mean pool (bf16 input) ----------------
__global__ __launch_bounds__(128) void mean_pool_sum_k(
    const ushort* __restrict__ X, const int* __restrict__ bv,
    float* __restrict__ featp, int chunk, int N)
{
    __shared__ float acc[16*128];
    int t = threadIdx.x;
    for (int b = 0; b < 16; ++b) acc[b*128 + t] = 0.f;
    int i0 = blockIdx.x * chunk;
    int iend = min(i0 + chunk, N);
    int bcur = bv[i0];
    float r = 0.f;
    for (int i = i0; i < iend; ++i) {
        int b = bv[i];
        if (b != bcur) { acc[bcur*128 + t] += r; r = 0.f; bcur = b; }
        r += fmaxf(b2f(X[(size_t)i*128 + t]), 0.f);
    }
    acc[bcur*128 + t] += r;
    for (int b = 0; b < 16; ++b) {
        float v = acc[b*128 + t];
        if (v != 0.f) unsafeAtomicAdd(featp + b*512 + t, v);
    }
}

__global__ void count_batch_k(const int* __restrict__ bv, float* __restrict__ cnt, int N){
    __shared__ int h[16];
    int t = threadIdx.x;
    if (t < 16) h[t] = 0;
    __syncthreads();
    int i = blockIdx.x*256 + t;
    if (i < N) atomicAdd(&h[bv[i]], 1);
    __syncthreads();
    if (t < 16 && h[t]) unsafeAtomicAdd(&cnt[t], (float)h[t]);
}

// ---------------- voxel fp32 NCDHW -> bf16 channels-last [n][64^3][2] ----------------
__global__ __launch_bounds__(256) void cvt_cl0_k(const float* __restrict__ vox, unsigned* __restrict__ out){
    int idx = blockIdx.x*256 + threadIdx.x;       // 16 * 262144
    int n = idx >> 18, v = idx & 262143;
    float a = vox[((size_t)n*2    )*262144 + v];
    float b = vox[((size_t)n*2 + 1)*262144 + v];
    out[idx] = (unsigned)f2b(a) | ((unsigned)f2b(b) << 16);
}

// conv1 weight prepack: k = rowIdx*16 + dx*4 + ci (ci padded 2->4, rows padded 9->10)
__global__ void wfrag1_k(const float* __restrict__ wt, ushort* __restrict__ out){
    int i = blockIdx.x*256 + threadIdx.x;
    if (i >= 2560) return;
    int j = i & 7, col = (i >> 3) & 15, kg = (i >> 7) & 3, ks = i >> 9;
    int rowIdx = ks*2 + (kg >> 1);
    int dx = (kg & 1)*2 + (j >> 2), ci = j & 3;
    ushort v = 0;
    if (rowIdx < 9 && dx < 3 && ci < 2)
        v = f2b(wt[(col*2 + ci)*27 + (rowIdx/3)*9 + (rowIdx%3)*3 + dx]);
    out[i] = v;
}

// conv1 implicit-GEMM MFMA: CL bf16 [n][64^3][2] -> pooled max/min CL [n][32^3][16]
// stats -> PARTIAL buffer [128][32] to kill same-address atomic serialization
__global__ __launch_bounds__(256) void conv1_mfma_k(
    const ushort* __restrict__ Xcl0, const ushort* __restrict__ wf,
    const float* __restrict__ bias,
    ushort* __restrict__ outmax, ushort* __restrict__ outmin, float* __restrict__ stats_part)
{
    __shared__ __align__(16) ushort Ast[2896];    // [10z][4y][18x][4ci-pad] (2880) + guard
    __shared__ __align__(16) ushort Bfr[2560];
    __shared__ float red[128];

    int tid = threadIdx.x;
    int n = blockIdx.y;
    int bx = blockIdx.x;
    int xb = bx & 3, yb = (bx >> 2) & 31, zb = bx >> 7;
    int w = tid >> 6, l = tid & 63;
    int col = l & 15, kg = l >> 4;

    for (int i = tid; i < 320; i += 256)
        *(ushort8v*)(Bfr + i*8) = *(const ushort8v*)(wf + i*8);
    for (int i = tid; i < 720; i += 256) {
        int z = i/72, r = i - z*72, y = r/18, x = r - y*18;
        int gz = zb*8 - 1 + z, gy = yb*2 - 1 + y, gx = xb*16 - 1 + x;
        unsigned packed = 0;
        if ((unsigned)gz < 64u && (unsigned)gy < 64u && (unsigned)gx < 64u)
            packed = *(const unsigned*)(Xcl0 + ((((size_t)n << 18) + ((gz*64 + gy)*64 + gx)) << 1));
        *(uint2*)(Ast + i*4) = make_uint2(packed, 0u);
    }
    if (tid < 2) *(uint2*)(Ast + 2880 + tid*4) = make_uint2(0u, 0u);
    __syncthreads();

    int halfoff = (kg & 1)*2;
    f32x4 acc[4];
    #pragma unroll
    for (int mt = 0; mt < 4; ++mt) acc[mt] = (f32x4){0.f,0.f,0.f,0.f};

    #pragma unroll
    for (int ks = 0; ks < 5; ++ks) {
        int rowIdx = ks*2 + (kg >> 1); if (rowIdx >= 9) rowIdx = 0;
        int kd = rowIdx/3, kh = rowIdx - kd*3;
        int off = kd*288 + kh*72 + (col + halfoff)*4;
        short8v bb = *(const short8v*)(Bfr + (ks*4 + kg)*128 + col*8);
        #pragma unroll
        for (int mt = 0; mt < 4; ++mt) {
            const ushort* p = Ast + (2*w + (mt>>1))*288 + (mt&1)*72 + off;
            short8v a = ld_a8(p);
            acc[mt] = __builtin_amdgcn_mfma_f32_16x16x32_bf16(a, bb, acc[mt], 0, 0, 0);
        }
    }

    int zp = zb*4 + w, yp = yb;
    float bl = bias[col];
    float s = 0.f, q = 0.f;
    float mx0=-1e30f, mx1=-1e30f, mn0=1e30f, mn1=1e30f;
    #pragma unroll
    for (int mt = 0; mt < 4; ++mt)
        #pragma unroll
        for (int j = 0; j < 4; ++j) {
            float v = acc[mt][j] + bl;
            s += v; q = fmaf(v, v, q);
            if (j < 2) { mx0 = fmaxf(mx0, v); mn0 = fminf(mn0, v); }
            else       { mx1 = fmaxf(mx1, v); mn1 = fminf(mn1, v); }
        }
    s += __shfl_xor(s, 16); s += __shfl_xor(s, 32);
    q += __shfl_xor(q, 16); q += __shfl_xor(q, 32);
    if (kg == 0) { red[(w*16 + col)*2] = s; red[(w*16 + col)*2 + 1] = q; }
    size_t ob = ((((size_t)(n*32 + zp))*32 + yp)*32 + xb*8 + kg*2)*16 + col;
    outmax[ob]      = f2b(mx0); outmin[ob]      = f2b(mn0);
    outmax[ob + 16] = f2b(mx1); outmin[ob + 16] = f2b(mn1);
    __syncthreads();
    if (tid < 32) {
        float t = red[tid] + red[32 + tid] + red[64 + tid] + red[96 + tid];
        unsafeAtomicAdd(&stats_part[((bx & 127) << 5) + tid], t);
    }
}

// sum partial stats -> final stats (plain store; out buffer pre-zeroed/overwritten)
__global__ void stats_reduce_k(const float* __restrict__ part, float* __restrict__ out,
                               int npart, int n)
{
    int c = blockIdx.x*64 + threadIdx.x;
    if (c >= n) return;
    float s = 0.f;
    for (int p = 0; p < npart; ++p) s += part[p*n + c];
    out[c] = s;
}

__global__ void bn_final_k(const float* __restrict__ stats, const float* __restrict__ g,
                           const float* __restrict__ b, float* __restrict__ sc, float* __restrict__ sh,
                           int C, float invN)
{
    int c = threadIdx.x; if (c >= C) return;
    float m = stats[c*2] * invN;
    float v = stats[c*2+1] * invN - m*m;
    float s = g[c] * rsqrtf(v + 1e-5f);
    sc[c] = s; sh[c] = b[c] - m*s;
}

// prepack conv weights into MFMA B-fragment order (bf16), K padded to 448 per ci-half
__global__ void wfrag_k(const float* __restrict__ wt, ushort* __restrict__ out,
                        int CIN, int COT, int total)
{
    int i = blockIdx.x*256 + threadIdx.x;
    if (i >= total) return;
    int per_h = COT*7168;
    int h  = i / per_h;
    int r0 = i - h*per_h;
    int ct = r0 / 7168;
    int r  = r0 - ct*7168;
    int ks = r >> 9;
    int r2 = r & 511;
    int kg = r2 >> 7, col = (r2 >> 3) & 15, j = r2 & 7;
    int k = ks*32 + kg*8 + j;
    int nbr = k >> 4, ci = (k & 15) + h*16;
    out[i] = (nbr < 27) ? f2b(wt[((size_t)(ct*16 + col)*CIN + ci)*27 + nbr]) : (ushort)0;
}

// ---------------- implicit-GEMM MFMA conv + bias + BN-stats(partial) + max/min pool ----
template<int CIHALVES, int COT, int D, int CIN, int COUT>
__global__ __launch_bounds__(256) void conv_mfma_k(
    const ushort* __restrict__ Xcl, const ushort* __restrict__ WfragG,
    const float* __restrict__ bias,
    ushort* __restrict__ outmax, ushort* __restrict__ outmin,
    float* __restrict__ stats_part, int pmask)
{
    constexpr int PD = D/2;
    constexpr int XT = D/16, YT = D/2;
    __shared__ __align__(16) ushort Ast[17280];
    __shared__ __align__(16) ushort Bfr[COT*7168];
    __shared__ float red[4*COT*32];

    int tid = threadIdx.x;
    int n = blockIdx.y;
    int bx = blockIdx.x;
    int xb = bx % XT, yb = (bx/XT) % YT, zb = bx/(XT*YT);
    int w = tid >> 6, l = tid & 63;
    int col = l & 15, kg = l >> 4;

    int laneoff[14];
    #pragma unroll
    for (int ks = 0; ks < 14; ++ks) {
        int nbr = ks*2 + (l >> 5);
        if (nbr >= 27) nbr = 0;
        int dz = nbr/9, r9 = nbr - dz*9, dy = r9/3, dx = r9 - dy*3;
        laneoff[ks] = dz*1728 + dy*432 + (col + dx)*24 + ((l>>4)&1)*8;
    }
    int Mbase[4];
    #pragma unroll
    for (int mt = 0; mt < 4; ++mt)
        Mbase[mt] = (2*w + (mt>>1))*1728 + (mt&1)*432;

    f32x4 acc[4][COT];
    #pragma unroll
    for (int mt = 0; mt < 4; ++mt)
        #pragma unroll
        for (int ct = 0; ct < COT; ++ct)
            acc[mt][ct] = (f32x4){0.f,0.f,0.f,0.f};

    for (int h = 0; h < CIHALVES; ++h) {
        __syncthreads();
        for (int i = tid; i < 1440; i += 256) {
            int vec = i >> 1, hi8 = (i & 1) << 3;
            int z = vec/72, r = vec - z*72, y = r/18, x = r - y*18;
            int gz = zb*8 - 1 + z, gy = yb*2 - 1 + y, gx = xb*16 - 1 + x;
            ushort8v val = {0,0,0,0,0,0,0,0};
            if ((unsigned)gz < (unsigned)D && (unsigned)gy < (unsigned)D && (unsigned)gx < (unsigned)D) {
                size_t gi = (((size_t)n*D*D*D) + ((size_t)gz*D + gy)*D + gx)*CIN + h*16 + hi8;
                val = *(const ushort8v*)(Xcl + gi);
            }
            *(ushort8v*)(Ast + (vec)*24 + hi8) = val;
        }
        for (int i = tid; i < COT*896; i += 256)
            *(ushort8v*)(Bfr + i*8) = *(const ushort8v*)(WfragG + (size_t)h*COT*7168 + i*8);
        __syncthreads();

        #pragma unroll
        for (int ks = 0; ks < 14; ++ks) {
            short8v a[4];
            #pragma unroll
            for (int mt = 0; mt < 4; ++mt)
                a[mt] = *(const short8v*)(Ast + Mbase[mt] + laneoff[ks]);
            short8v bb[COT];
            #pragma unroll
            for (int ct = 0; ct < COT; ++ct)
                bb[ct] = *(const short8v*)(Bfr + ct*7168 + ks*512 + kg*128 + col*8);
            #pragma unroll
            for (int mt = 0; mt < 4; ++mt)
                #pragma unroll
                for (int ct = 0; ct < COT; ++ct)
                    acc[mt][ct] = __builtin_amdgcn_mfma_f32_16x16x32_bf16(a[mt], bb[ct], acc[mt][ct], 0, 0, 0);
        }
    }

    int zp = zb*4 + w, yp = yb;
    #pragma unroll
    for (int ct = 0; ct < COT; ++ct) {
        float bl = bias[ct*16 + col];
        float s = 0.f, q = 0.f;
        float mx0 = -1e30f, mx1 = -1e30f, mn0 = 1e30f, mn1 = 1e30f;
        #pragma unroll
        for (int mt = 0; mt < 4; ++mt) {
            #pragma unroll
            for (int j = 0; j < 4; ++j) {
                float v = acc[mt][ct][j] + bl;
                s += v; q = fmaf(v, v, q);
                if (j < 2) { mx0 = fmaxf(mx0, v); mn0 = fminf(mn0, v); }
                else       { mx1 = fmaxf(mx1, v); mn1 = fminf(mn1, v); }
            }
        }
        s += __shfl_xor(s, 16); s += __shfl_xor(s, 32);
        q += __shfl_xor(q, 16); q += __shfl_xor(q, 32);
        if (kg == 0) {
            red[((w*COT + ct)*16 + col)*2]     = s;
            red[((w*COT + ct)*16 + col)*2 + 1] = q;
        }
        size_t ob = (((size_t)((n*PD + zp)*PD + yp))*PD + xb*8 + kg*2)*COUT + ct*16 + col;
        outmax[ob]        = f2b(mx0);
        outmin[ob]        = f2b(mn0);
        outmax[ob + COUT] = f2b(mx1);
        outmin[ob + COUT] = f2b(mn1);
    }
    __syncthreads();
    if (tid < COT*32) {
        float t = red[tid] + red[COT*32 + tid] + red[2*COT*32 + tid] + red[3*COT*32 + tid];
        unsafeAtomicAdd(&stats_part[(bx & pmask)*(COT*32) + tid], t);
    }
}

// channels-last bf16 pooled max/min -> BN+ReLU -> bf16
__global__ __launch_bounds__(256) void bn_select_cl23_k(
    const ushort* __restrict__ mx, const ushort* __restrict__ mn,
    const float* __restrict__ sc, const float* __restrict__ sh,
    ushort* __restrict__ out, int cmask, int total)
{
    int idx = blockIdx.x*256 + threadIdx.x;
    if (idx >= total) return;
    int ci = idx & cmask;
    float s = sc[ci];
    float v = b2f((s >= 0.f) ? mx[idx] : mn[idx]);
    out[idx] = f2b(fmaxf(fmaf(v, s, sh[ci]), 0.f));
}

// fc: X channels-last bf16 [16][512][64]; W k-index = c*512 + sp
__global__ __launch_bounds__(128) void fc_acc_k(
    const ushort* __restrict__ X, const float* __restrict__ W, float* __restrict__ featv)
{
    int t = threadIdx.x;
    int k0 = blockIdx.x*256;
    float acc[16];
    #pragma unroll
    for (int b = 0; b < 16; ++b) acc[b] = 0.f;
    for (int k = k0; k < k0 + 256; ++k) {
        float w = W[(size_t)k*128 + t];
        int c = k >> 9, sp = k & 511;
        #pragma unroll
        for (int b = 0; b < 16; ++b)
            acc[b] = fmaf(b2f(X[(size_t)((b*512 + sp))*64 + c]), w, acc[b]);
    }
    for (int b = 0; b < 16; ++b) unsafeAtomicAdd(featv + b*512 + t, acc[b]);
}

// ---------------- small dense layers ----------------
__global__ __launch_bounds__(256) void head_k(
    const float* __restrict__ X, const float* __restrict__ W, const float* __restrict__ b,
    float* __restrict__ O, int K, int Ncol, int relu)
{
    int t = blockIdx.x*256 + threadIdx.x;
    if (t >= 16*Ncol) return;
    int bi = t / Ncol, c = t % Ncol;
    float acc = b[c];
    for (int k = 0; k < K; ++k) acc = fmaf(X[bi*K + k], W[k*Ncol + c], acc);
    if (relu) acc = fmaxf(acc, 0.f);
    O[bi*Ncol + c] = acc;
}

__global__ void gebn_k(const float* __restrict__ g2, const float* __restrict__ g,
                       const float* __restrict__ b, float* __restrict__ featg)
{
    int c = threadIdx.x;
    float m = 0.f;
    for (int i = 0; i < 16; ++i) m += g2[i*128 + c];
    m *= (1.f/16.f);
    float v = 0.f;
    for (int i = 0; i < 16; ++i) { float d = g2[i*128 + c] - m; v += d*d; }
    v *= (1.f/16.f);
    float s = g[c] * rsqrtf(v + 1e-5f);
    for (int i = 0; i < 16; ++i)
        featg[i*512 + c] = fmaxf((g2[i*128 + c] - m)*s + b[c], 0.f);
}

__global__ void finalize_feat_k(float* __restrict__ feat, const float* __restrict__ cntm,
                                const float* __restrict__ cntz, const float* __restrict__ fcb)
{
    int t = blockIdx.x*256 + threadIdx.x;
    if (t >= 8192) return;
    int bi = t >> 9, c = t & 511;
    float v = feat[t];
    if      (c < 128) v /= fmaxf(cntm[bi], 1.f);
    else if (c < 256) v /= fmaxf(cntz[bi], 1.f);
    else if (c >= 384) v = fmaxf(v + fcb[c - 384], 0.f);
    feat[t] = v;
}

// =====================================================================================
extern "C" void kernel_launch(void* const* d_in, const int* in_sizes, int n_in,
                              void* d_out, int out_size, void* d_ws, size_t ws_size,
                              hipStream_t stream)
{
    const int*   mol_x  = (const int*)  d_in[0];
    const float* mol_q  = (const float*)d_in[1];
    const int*   mol_ei = (const int*)  d_in[2];
    const float* mol_ew = (const float*)d_in[3];
    const int*   mol_bv = (const int*)  d_in[4];
    const int*   zeo_x  = (const int*)  d_in[5];
    const int*   zeo_ei = (const int*)  d_in[6];
    const int*   zeo_bv = (const int*)  d_in[7];
    const float* voxel  = (const float*)d_in[8];
    const float* gattr  = (const float*)d_in[9];
    const float* ea  = (const float*)d_in[10];
    const float* ed  = (const float*)d_in[11];
    const float* ec  = (const float*)d_in[12];
    const float* eh  = (const float*)d_in[13];
    const float* ear = (const float*)d_in[14];
    const float* ech = (const float*)d_in[15];
    const float* mc1w=(const float*)d_in[16]; const float* mc1b=(const float*)d_in[17];
    const float* mc2w=(const float*)d_in[18]; const float* mc2b=(const float*)d_in[19];
    const float* zc1w=(const float*)d_in[20]; const float* zc1b=(const float*)d_in[21];
    const float* zc2w=(const float*)d_in[22]; const float* zc2b=(const float*)d_in[23];
    const float* cv1w=(const float*)d_in[24]; const float* cv1b=(const float*)d_in[25];
    const float* bn1g=(const float*)d_in[26]; const float* bn1b=(const float*)d_in[27];
    const float* cv2w=(const float*)d_in[28]; const float* cv2b=(const float*)d_in[29];
    const float* bn2g=(const float*)d_in[30]; const float* bn2b=(const float*)d_in[31];
    const float* cv3w=(const float*)d_in[32]; const float* cv3b=(const float*)d_in[33];
    const float* bn3g=(const float*)d_in[34]; const float* bn3b=(const float*)d_in[35];
    const float* fcw =(const float*)d_in[36]; const float* fcb =(const float*)d_in[37];
    const float* ge1w=(const float*)d_in[38]; const float* ge1b=(const float*)d_in[39];
    const float* ge2w=(const float*)d_in[40]; const float* ge2b=(const float*)d_in[41];
    const float* gbng=(const float*)d_in[42]; const float* gbnb=(const float*)d_in[43];
    const float* h1w =(const float*)d_in[44]; const float* h1b =(const float*)d_in[45];
    const float* h2w =(const float*)d_in[46]; const float* h2b =(const float*)d_in[47];
    const float* h3w =(const float*)d_in[48]; const float* h3b =(const float*)d_in[49];

    const int Nm = in_sizes[0]/6, Em = in_sizes[2]/2;
    const int Nz = in_sizes[5]/6, Ez = in_sizes[6]/2;
    const int NBm = (Nm + 1023)/1024, NBz = (Nz + 1023)/1024;

    float* WS = (float*)d_ws;
    float* A  = WS;
    float* Bb = WS + 16777216;
    float* S  = WS + 33554432;
    ushort* X0 = (ushort*)A;
    ushort* X1 = (ushort*)A + 16777216;
    ushort* X2 = (ushort*)Bb;
    ushort* X3 = (ushort*)Bb + 16777216;
    // conv-phase channels-last bf16 buffers (GNN buffers dead by then)
    ushort* Au   = (ushort*)A;
    ushort* pm1  = Au;                      // [16][32^3][16]
    ushort* pn1  = Au + 8388608;
    ushort* Xcl0 = Au + 16777216;           // [16][64^3][2]
    ushort* Xcl1 = (ushort*)Bb;             // [16][32^3][16]
    ushort* pm2  = Au;                      // [16][16^3][32]
    ushort* pn2  = Au + 2097152;
    ushort* Xcl2 = Au + 4194304;
    ushort* pm3  = (ushort*)Bb;             // [16][8^3][64]
    ushort* pn3  = (ushort*)Bb + 524288;
    ushort* Xcl3 = (ushort*)Bb + 1048576;
    float* deg  = S;
    float* dis  = S + 131072;
    float* csr_nrm = S + 262144;
    float* T    = S + 786432;
    float* cntm = S + 807040;
    float* cntz = S + 807056;
    float* feat = S + 807072;
    float* st1  = S + 815264; float* st2 = st1 + 32; float* st3 = st1 + 96;
    float* sc1  = S + 815488; float* sh1 = sc1 + 16;
    float* sc2  = sc1 + 32;   float* sh2 = sc1 + 64;
    float* sc3  = sc1 + 96;   float* sh3 = sc1 + 160;
    float* g1   = S + 815712;
    float* g2   = S + 816736;
    float* H1   = S + 818784;
    float* H2   = S + 826976;
    int* rowptr  = (int*)(S + 831072);          // 131073
    int* cursor  = (int*)(S + 962176);          // 131072
    int* csr_src = (int*)(S + 1093248);         // 524288 (ends S+1617536)
    ushort* wf2 = (ushort*)(S + 1617536);       // 14336 ush
    ushort* wf3 = (ushort*)(S + 1624704);       // 57344 ush
    int* bsum   = (int*)(S + 1653376);          // 256 ints
    ushort* wf1 = (ushort*)(S + 1653632);       // 2560 ush (ends S+1654912 floats)
    float* stp1 = S + 1655040;                  // 128*32 = 4096
    float* stp2 = S + 1659136;                  // 32*64  = 2048
    float* stp3 = S + 1661184;                  // 8*128  = 1024 (ends S+1662208)

    hipMemsetAsync(S, 0, (size_t)831072*sizeof(float), stream);
    hipMemsetAsync(stp1, 0, (size_t)7168*sizeof(float), stream);   // stp1..stp3 contiguous

    // weight prepacks for MFMA convs
    wfrag1_k<<<10,256,0,stream>>>(cv1w, wf1);
    wfrag_k<<<56,256,0,stream>>>(cv2w, wf2, 16, 2, 14336);
    wfrag_k<<<224,256,0,stream>>>(cv3w, wf3, 32, 4, 57344);

    // ---------------- molecule branch ----------------
    build_tables_k<<<161,128,0,stream>>>(ea,ed,ec,eh,ear,ech, mc1w, T);
    init_deg_k   <<<Nm/256,256,0,stream>>>(deg, Nm);
    deg_scatter_k<<<Em/256,256,0,stream>>>(mol_ei+Em, mol_ew, deg, Em);
    dis_k        <<<Nm/256,256,0,stream>>>(deg, dis, Nm);
    hipMemsetAsync(cursor, 0, (size_t)Nm*sizeof(int), stream);
    count_in_k   <<<Em/256,256,0,stream>>>(mol_ei+Em, cursor, Em);
    blocksum_k   <<<NBm,256,0,stream>>>(cursor, bsum, Nm);
    scan_bsum_k  <<<1,256,0,stream>>>(bsum, NBm);
    scan_apply_k <<<NBm,256,0,stream>>>(cursor, bsum, rowptr, Nm, Em);
    fill_csr_k   <<<Em/256,256,0,stream>>>(mol_ei, mol_ei+Em, mol_ew, dis, cursor, csr_src, csr_nrm, Em);
    embed_lookup_k<<<Nm/8,256,0,stream>>>(mol_x, mol_q, T, mc1w + 112*128, X0, Nm);
    gcn_gather_k <<<Nm/8,256,0,stream>>>(X0, rowptr, csr_src, csr_nrm, dis, mc1b, X1, Nm);
    gemm_mfma_k  <<<Nm/64,256,0,stream>>>(X1, mc2w, X2, Nm);
    gcn_gather_k <<<Nm/8,256,0,stream>>>(X2, rowptr, csr_src, csr_nrm, dis, mc2b, X3, Nm);
    count_batch_k<<<Nm/256,256,0,stream>>>(mol_bv, cntm, Nm);
    mean_pool_sum_k<<<256,128,0,stream>>>(X3, mol_bv, feat + 0, (Nm+255)/256, Nm);

    // ---------------- zeolite branch ----------------
    build_tables_k<<<161,128,0,stream>>>(ea,ed,ec,eh,ear,ech, zc1w, T);
    init_deg_k   <<<Nz/256,256,0,stream>>>(deg, Nz);
    deg_scatter_k<<<Ez/256,256,0,stream>>>(zeo_ei+Ez, nullptr, deg, Ez);
    dis_k        <<<Nz/256,256,0,stream>>>(deg, dis, Nz);
    hipMemsetAsync(cursor, 0, (size_t)Nz*sizeof(int), stream);
    count_in_k   <<<Ez/256,256,0,stream>>>(zeo_ei+Ez, cursor, Ez);
    blocksum_k   <<<NBz,256,0,stream>>>(cursor, bsum, Nz);
    scan_bsum_k  <<<1,256,0,stream>>>(bsum, NBz);
    scan_apply_k <<<NBz,256,0,stream>>>(cursor, bsum, rowptr, Nz, Ez);
    fill_csr_k   <<<Ez/256,256,0,stream>>>(zeo_ei, zeo_ei+Ez, nullptr, dis, cursor, csr_src, csr_nrm, Ez);
    embed_lookup_k<<<Nz/8,256,0,stream>>>(zeo_x, nullptr, T, nullptr, X0, Nz);
    gcn_gather_k <<<Nz/8,256,0,stream>>>(X0, rowptr, csr_src, csr_nrm, dis, zc1b, X1, Nz);
    gemm_mfma_k  <<<Nz/64,256,0,stream>>>(X1, zc2w, X2, Nz);
    gcn_gather_k <<<Nz/8,256,0,stream>>>(X2, rowptr, csr_src, csr_nrm, dis, zc2b, X3, Nz);
    count_batch_k<<<Nz/256,256,0,stream>>>(zeo_bv, cntz, Nz);
    mean_pool_sum_k<<<256,128,0,stream>>>(X3, zeo_bv, feat + 128, (Nz+255)/256, Nz);

    // ---------------- voxel CNN (all layers MFMA implicit-GEMM) ----------------
    cvt_cl0_k<<<16384,256,0,stream>>>(voxel, (unsigned*)Xcl0);
    conv1_mfma_k<<<dim3(1024,16),256,0,stream>>>(Xcl0, wf1, cv1b, pm1, pn1, stp1);
    stats_reduce_k<<<1,64,0,stream>>>(stp1, st1, 128, 32);
    bn_final_k<<<1,64,0,stream>>>(st1, bn1g, bn1b, sc1, sh1, 16, 1.f/(16.f*262144.f));
    bn_select_cl23_k<<<32768,256,0,stream>>>(pm1, pn1, sc1, sh1, Xcl1, 15, 8388608);

    conv_mfma_k<1,2,32,16,32><<<dim3(128,16),256,0,stream>>>(Xcl1, wf2, cv2b, pm2, pn2, stp2, 31);
    stats_reduce_k<<<1,64,0,stream>>>(stp2, st2, 32, 64);
    bn_final_k<<<1,64,0,stream>>>(st2, bn2g, bn2b, sc2, sh2, 32, 1.f/(16.f*32768.f));
    bn_select_cl23_k<<<8192,256,0,stream>>>(pm2, pn2, sc2, sh2, Xcl2, 31, 2097152);

    conv_mfma_k<2,4,16,32,64><<<dim3(16,16),256,0,stream>>>(Xcl2, wf3, cv3b, pm3, pn3, stp3, 7);
    stats_reduce_k<<<2,64,0,stream>>>(stp3, st3, 8, 128);
    bn_final_k<<<1,64,0,stream>>>(st3, bn3g, bn3b, sc3, sh3, 64, 1.f/(16.f*4096.f));
    bn_select_cl23_k<<<2048,256,0,stream>>>(pm3, pn3, sc3, sh3, Xcl3, 63, 524288);

    fc_acc_k<<<128,128,0,stream>>>(Xcl3, fcw, feat + 384);

    // ---------------- global encoder ----------------
    head_k<<<4,256,0,stream>>>(gattr, ge1w, ge1b, g1, 17, 64, 1);
    head_k<<<8,256,0,stream>>>(g1, ge2w, ge2b, g2, 64, 128, 0);
    gebn_k<<<1,128,0,stream>>>(g2, gbng, gbnb, feat + 256);

    // ---------------- fusion head ----------------
    finalize_feat_k<<<32,256,0,stream>>>(feat, cntm, cntz, fcb);
    head_k<<<32,256,0,stream>>>(feat, h1w, h1b, H1, 512, 512, 1);
    head_k<<<16,256,0,stream>>>(H1, h2w, h2b, H2, 512, 256, 1);
    head_k<<<1,256,0,stream>>>(H2, h3w, h3b, (float*)d_out, 256, 3, 0);
}

// Round 14
// 1183.469 us; speedup vs baseline: 1.2970x; 1.1583x over previous
//
#include <hip/hip_runtime.h>
#include <math.h>

#define DEV static __device__ __forceinline__

DEV float4 ld4(const float* p){ return *(const float4*)p; }
DEV float2 ld2(const float* p){ return *(const float2*)p; }
DEV void   st4(float* p, float4 v){ *(float4*)p = v; }
DEV float4 f4add(float4 a, float4 b){ return make_float4(a.x+b.x,a.y+b.y,a.z+b.z,a.w+b.w); }
DEV float4 f4fma(float s, float4 a, float4 c){ return make_float4(fmaf(s,a.x,c.x),fmaf(s,a.y,c.y),fmaf(s,a.z,c.z),fmaf(s,a.w,c.w)); }

// bf16 helpers (RNE pack, exact unpack)
DEV float  b2f(ushort u){ return __uint_as_float(((unsigned)u) << 16); }
DEV ushort f2b(float f){
    unsigned u = __float_as_uint(f);
    return (ushort)((u + 0x7FFFu + ((u >> 16) & 1u)) >> 16);
}
DEV float4 b2f4(ushort4 v){ return make_float4(b2f(v.x), b2f(v.y), b2f(v.z), b2f(v.w)); }
DEV ushort4 f2b4(float4 v){ ushort4 o; o.x=f2b(v.x); o.y=f2b(v.y); o.z=f2b(v.z); o.w=f2b(v.w); return o; }

typedef __attribute__((ext_vector_type(8))) short short8v;            // 8 bf16 = 4 VGPR
typedef __attribute__((ext_vector_type(8))) unsigned short ushort8v;
typedef __attribute__((ext_vector_type(4))) float f32x4;

DEV short8v ld_a8(const ushort* p){   // 8B-aligned 16B LDS read as 2x b64
    ushort4 a = *(const ushort4*)p;
    ushort4 b = *(const ushort4*)(p+4);
    short8v r;
    r[0]=a.x; r[1]=a.y; r[2]=a.z; r[3]=a.w;
    r[4]=b.x; r[5]=b.y; r[6]=b.z; r[7]=b.w;
    return r;
}

// ---------------- GNN: embedding tables  T[161][128] = emb_f @ W_slice ----------------
__global__ __launch_bounds__(128) void build_tables_k(
    const float* __restrict__ ea, const float* __restrict__ ed, const float* __restrict__ ec,
    const float* __restrict__ eh, const float* __restrict__ ear, const float* __restrict__ ech,
    const float* __restrict__ Wm, float* __restrict__ T)
{
    int r = blockIdx.x, c = threadIdx.x;
    const float* e; int dim, woff, rl;
    if      (r < 120) { e=ea;  dim=64; woff=0;   rl=r; }
    else if (r < 132) { e=ed;  dim=16; woff=64;  rl=r-120; }
    else if (r < 147) { e=ec;  dim=16; woff=80;  rl=r-132; }
    else if (r < 155) { e=eh;  dim=8;  woff=96;  rl=r-147; }
    else if (r < 157) { e=ear; dim=4;  woff=104; rl=r-155; }
    else              { e=ech; dim=4;  woff=108; rl=r-157; }
    float acc = 0.f;
    for (int k = 0; k < dim; ++k) acc += e[rl*dim + k] * Wm[(woff + k)*128 + c];
    T[r*128 + c] = acc;
}

__global__ __launch_bounds__(256) void embed_lookup_k(
    const int* __restrict__ xi, const float* __restrict__ charge,
    const float* __restrict__ T, const float* __restrict__ wq,
    ushort* __restrict__ H, int N)
{
    int t = threadIdx.x;
    int node = blockIdx.x*8 + (t >> 5);
    if (node >= N) return;
    int c = (t & 31)*4;
    const int* xp = xi + node*6;
    float4 acc = ld4(T + (       xp[0])*128 + c);
    acc = f4add(acc, ld4(T + (120+xp[1])*128 + c));
    acc = f4add(acc, ld4(T + (132+xp[2])*128 + c));
    acc = f4add(acc, ld4(T + (147+xp[3])*128 + c));
    acc = f4add(acc, ld4(T + (155+xp[4])*128 + c));
    acc = f4add(acc, ld4(T + (157+xp[5])*128 + c));
    if (charge) acc = f4fma(charge[node], ld4(wq + c), acc);
    *(ushort4*)(H + (size_t)node*128 + c) = f2b4(acc);
}

// ---------------- GCN degree / norm / CSR build ----------------
__global__ void init_deg_k(float* deg, int N){ int i = blockIdx.x*256+threadIdx.x; if (i<N) deg[i]=1.f; }

__global__ void deg_scatter_k(const int* __restrict__ col, const float* __restrict__ ew, float* deg, int E){
    int e = blockIdx.x*256+threadIdx.x; if (e>=E) return;
    unsafeAtomicAdd(deg + col[e], ew ? ew[e] : 1.f);
}

__global__ void dis_k(const float* __restrict__ deg, float* __restrict__ dis, int N){
    int i = blockIdx.x*256+threadIdx.x; if (i<N) dis[i] = 1.f/sqrtf(deg[i]);
}

__global__ void count_in_k(const int* __restrict__ col, int* __restrict__ cnt, int E){
    int e = blockIdx.x*256+threadIdx.x; if (e>=E) return;
    atomicAdd(&cnt[col[e]], 1);
}

// ---- multi-block exclusive scan (3 phases; 1024 elems / block) ----
__global__ __launch_bounds__(256) void blocksum_k(const int* __restrict__ cnt, int* __restrict__ bsum, int N){
    int b = blockIdx.x, t = threadIdx.x;
    int base = b*1024 + t*4;
    int s = 0;
    if (base + 3 < N) { int4 v = *(const int4*)(cnt + base); s = v.x + v.y + v.z + v.w; }
    else { for (int i = 0; i < 4; ++i) { int idx = base + i; if (idx < N) s += cnt[idx]; } }
    __shared__ int red[256];
    red[t] = s; __syncthreads();
    for (int off = 128; off; off >>= 1) { if (t < off) red[t] += red[t+off]; __syncthreads(); }
    if (!t) bsum[b] = red[0];
}

__global__ __launch_bounds__(256) void scan_bsum_k(int* __restrict__ bsum, int NB){
    int t = threadIdx.x;
    __shared__ int sh[256];
    sh[t] = (t < NB) ? bsum[t] : 0;
    __syncthreads();
    for (int off = 1; off < 256; off <<= 1) {
        int v = (t >= off) ? sh[t-off] : 0;
        __syncthreads();
        sh[t] += v;
        __syncthreads();
    }
    if (t < NB) bsum[t] = (t == 0) ? 0 : sh[t-1];
}

__global__ __launch_bounds__(256) void scan_apply_k(int* cur, const int* __restrict__ bsum,
                                                    int* __restrict__ rowptr, int N, int E){
    int b = blockIdx.x, t = threadIdx.x;
    int base = b*1024 + t*4;
    int c[4]; int s = 0;
    #pragma unroll
    for (int i = 0; i < 4; ++i) { int idx = base + i; c[i] = (idx < N) ? cur[idx] : 0; s += c[i]; }
    __shared__ int sh[256];
    sh[t] = s; __syncthreads();
    for (int off = 1; off < 256; off <<= 1) {
        int v = (t >= off) ? sh[t-off] : 0;
        __syncthreads();
        sh[t] += v;
        __syncthreads();
    }
    int run = bsum[b] + ((t == 0) ? 0 : sh[t-1]);
    #pragma unroll
    for (int i = 0; i < 4; ++i) {
        int idx = base + i;
        if (idx < N) { rowptr[idx] = run; cur[idx] = run; run += c[i]; }
    }
    if (b == 0 && t == 0) rowptr[N] = E;
}

__global__ void fill_csr_k(const int* __restrict__ row, const int* __restrict__ col,
                           const float* __restrict__ ew, const float* __restrict__ dis,
                           int* __restrict__ cursor, int* __restrict__ csr_src,
                           float* __restrict__ csr_nrm, int E)
{
    int e = blockIdx.x*256+threadIdx.x; if (e>=E) return;
    int r = row[e], c = col[e];
    int pos = atomicAdd(&cursor[c], 1);
    csr_src[pos] = r;
    csr_nrm[pos] = dis[r] * (ew ? ew[e] : 1.f) * dis[c];
}

// O[i] = bias + dis[i]^2 * H[i] + sum_j nrm_j * H[src_j]   -- bf16 in/out, fp32 math
__global__ __launch_bounds__(256) void gcn_gather_k(
    const ushort* __restrict__ H, const int* __restrict__ rowptr,
    const int* __restrict__ csr_src, const float* __restrict__ csr_nrm,
    const float* __restrict__ dis, const float* __restrict__ bias,
    ushort* __restrict__ O, int N)
{
    int node = blockIdx.x*8 + (threadIdx.x >> 5);
    if (node >= N) return;
    int lane = (threadIdx.x & 31)*4;
    float s = dis[node]; s *= s;
    float4 h = b2f4(*(const ushort4*)(H + (size_t)node*128 + lane));
    float4 b = ld4(bias + lane);
    float4 acc = f4fma(s, h, b);
    int j = rowptr[node], end = rowptr[node+1];
    for (; j + 4 <= end; j += 4) {
        int   s0 = csr_src[j],   s1 = csr_src[j+1], s2 = csr_src[j+2], s3 = csr_src[j+3];
        float n0 = csr_nrm[j],   n1 = csr_nrm[j+1], n2 = csr_nrm[j+2], n3 = csr_nrm[j+3];
        float4 h0 = b2f4(*(const ushort4*)(H + (size_t)s0*128 + lane));
        float4 h1 = b2f4(*(const ushort4*)(H + (size_t)s1*128 + lane));
        float4 h2 = b2f4(*(const ushort4*)(H + (size_t)s2*128 + lane));
        float4 h3 = b2f4(*(const ushort4*)(H + (size_t)s3*128 + lane));
        acc = f4fma(n0, h0, acc);
        acc = f4fma(n1, h1, acc);
        acc = f4fma(n2, h2, acc);
        acc = f4fma(n3, h3, acc);
    }
    for (; j < end; ++j) {
        float4 h0 = b2f4(*(const ushort4*)(H + (size_t)csr_src[j]*128 + lane));
        acc = f4fma(csr_nrm[j], h0, acc);
    }
    *(ushort4*)(O + (size_t)node*128 + lane) = f2b4(acc);
}

// O = relu(A) @ W via bf16 MFMA; A:[N,128] bf16, W:[128,128] f32, O bf16
__global__ __launch_bounds__(256) void gemm_mfma_k(
    const ushort* __restrict__ A, const float* __restrict__ W,
    ushort* __restrict__ O, int N)
{
    __shared__ ushort WsF[16384];
    __shared__ ushort As[64*136];
    int t = threadIdx.x;
    for (int i = t; i < 16384; i += 256) {
        int j = i & 7, col = (i >> 3) & 15, kg = (i >> 7) & 3, ks = (i >> 9) & 3, ct = i >> 11;
        WsF[i] = f2b(W[(ks*32 + kg*8 + j)*128 + ct*16 + col]);
    }
    int row0 = blockIdx.x*64;
    for (int i = t; i < 64*32; i += 256) {
        int r = i >> 5, c4 = (i & 31)*4;
        ushort4 v = *(const ushort4*)(A + (size_t)(row0 + r)*128 + c4);
        v.x = (v.x & 0x8000) ? 0 : v.x;
        v.y = (v.y & 0x8000) ? 0 : v.y;
        v.z = (v.z & 0x8000) ? 0 : v.z;
        v.w = (v.w & 0x8000) ? 0 : v.w;
        *(ushort4*)(As + r*136 + c4) = v;
    }
    __syncthreads();
    int w = t >> 6, l = t & 63;
    int m16 = l & 15, kg = l >> 4;
    short8v af[4];
    #pragma unroll
    for (int ks = 0; ks < 4; ++ks)
        af[ks] = *(const short8v*)(As + (w*16 + m16)*136 + ks*32 + kg*8);
    #pragma unroll
    for (int ct = 0; ct < 8; ++ct) {
        f32x4 acc = {0.f, 0.f, 0.f, 0.f};
        #pragma unroll
        for (int ks = 0; ks < 4; ++ks) {
            short8v bf = *(const short8v*)(WsF + ((ct*4 + ks)*4 + kg)*128 + m16*8);
            acc = __builtin_amdgcn_mfma_f32_16x16x32_bf16(af[ks], bf, acc, 0, 0, 0);
        }
        int col = ct*16 + m16;
        int rbase = row0 + w*16 + kg*4;
        #pragma unroll
        for (int j = 0; j < 4; ++j)
            O[(size_t)(rbase + j)*128 + col] = f2b(acc[j]);
    }
}

// ---------------- mean pool (bf16 input) ----------------
__global__ __launch_bounds__(128) void mean_pool_sum_k(
    const ushort* __restrict__ X, const int* __restrict__ bv,
    float* __restrict__ featp, int chunk, int N)
{
    __shared__ float acc[16*128];
    int t = threadIdx.x;
    for (int b = 0; b < 16; ++b) acc[b*128 + t] = 0.f;
    int i0 = blockIdx.x * chunk;
    int iend = min(i0 + chunk, N);
    int bcur = bv[i0];
    float r = 0.f;
    for (int i = i0; i < iend; ++i) {
        int b = bv[i];
        if (b != bcur) { acc[bcur*128 + t] += r; r = 0.f; bcur = b; }
        r += fmaxf(b2f(X[(size_t)i*128 + t]), 0.f);
    }
    acc[bcur*128 + t] += r;
    for (int b = 0; b < 16; ++b) {
        float v = acc[b*128 + t];
        if (v != 0.f) unsafeAtomicAdd(featp + b*512 + t, v);
    }
}

__global__ void count_batch_k(const int* __restrict__ bv, float* __restrict__ cnt, int N){
    __shared__ int h[16];
    int t = threadIdx.x;
    if (t < 16) h[t] = 0;
    __syncthreads();
    int i = blockIdx.x*256 + t;
    if (i < N) atomicAdd(&h[bv[i]], 1);
    __syncthreads();
    if (t < 16 && h[t]) unsafeAtomicAdd(&cnt[t], (float)h[t]);
}

// ---------------- voxel fp32 NCDHW -> bf16 channels-last [n][64^3][2] ----------------
__global__ __launch_bounds__(256) void cvt_cl0_k(const float* __restrict__ vox, unsigned* __restrict__ out){
    int idx = blockIdx.x*256 + threadIdx.x;       // 16 * 262144
    int n = idx >> 18, v = idx & 262143;
    float a = vox[((size_t)n*2    )*262144 + v];
    float b = vox[((size_t)n*2 + 1)*262144 + v];
    out[idx] = (unsigned)f2b(a) | ((unsigned)f2b(b) << 16);
}

// conv1 weight prepack: k = rowIdx*16 + dx*4 + ci (ci padded 2->4, rows padded 9->10)
__global__ void wfrag1_k(const float* __restrict__ wt, ushort* __restrict__ out){
    int i = blockIdx.x*256 + threadIdx.x;
    if (i >= 2560) return;
    int j = i & 7, col = (i >> 3) & 15, kg = (i >> 7) & 3, ks = i >> 9;
    int rowIdx = ks*2 + (kg >> 1);
    int dx = (kg & 1)*2 + (j >> 2), ci = j & 3;
    ushort v = 0;
    if (rowIdx < 9 && dx < 3 && ci < 2)
        v = f2b(wt[(col*2 + ci)*27 + (rowIdx/3)*9 + (rowIdx%3)*3 + dx]);
    out[i] = v;
}

// conv1 implicit-GEMM MFMA: CL bf16 [n][64^3][2] -> pooled max/min CL [n][32^3][16]
__global__ __launch_bounds__(256) void conv1_mfma_k(
    const ushort* __restrict__ Xcl0, const ushort* __restrict__ wf,
    const float* __restrict__ bias,
    ushort* __restrict__ outmax, ushort* __restrict__ outmin, float* __restrict__ stats_part)
{
    __shared__ __align__(16) ushort Ast[2896];    // [10z][4y][18x][4ci-pad] (2880) + guard
    __shared__ __align__(16) ushort Bfr[2560];
    __shared__ float red[128];

    int tid = threadIdx.x;
    int n = blockIdx.y;
    int bx = blockIdx.x;
    int xb = bx & 3, yb = (bx >> 2) & 31, zb = bx >> 7;
    int w = tid >> 6, l = tid & 63;
    int col = l & 15, kg = l >> 4;

    for (int i = tid; i < 320; i += 256)
        *(ushort8v*)(Bfr + i*8) = *(const ushort8v*)(wf + i*8);
    for (int i = tid; i < 720; i += 256) {
        int z = i/72, r = i - z*72, y = r/18, x = r - y*18;
        int gz = zb*8 - 1 + z, gy = yb*2 - 1 + y, gx = xb*16 - 1 + x;
        unsigned packed = 0;
        if ((unsigned)gz < 64u && (unsigned)gy < 64u && (unsigned)gx < 64u)
            packed = *(const unsigned*)(Xcl0 + ((((size_t)n << 18) + ((gz*64 + gy)*64 + gx)) << 1));
        *(uint2*)(Ast + i*4) = make_uint2(packed, 0u);
    }
    if (tid < 2) *(uint2*)(Ast + 2880 + tid*4) = make_uint2(0u, 0u);
    __syncthreads();

    int halfoff = (kg & 1)*2;
    f32x4 acc[4];
    #pragma unroll
    for (int mt = 0; mt < 4; ++mt) acc[mt] = (f32x4){0.f,0.f,0.f,0.f};

    #pragma unroll
    for (int ks = 0; ks < 5; ++ks) {
        int rowIdx = ks*2 + (kg >> 1); if (rowIdx >= 9) rowIdx = 0;
        int kd = rowIdx/3, kh = rowIdx - kd*3;
        int off = kd*288 + kh*72 + (col + halfoff)*4;
        short8v bb = *(const short8v*)(Bfr + (ks*4 + kg)*128 + col*8);
        #pragma unroll
        for (int mt = 0; mt < 4; ++mt) {
            const ushort* p = Ast + (2*w + (mt>>1))*288 + (mt&1)*72 + off;
            short8v a = ld_a8(p);
            acc[mt] = __builtin_amdgcn_mfma_f32_16x16x32_bf16(a, bb, acc[mt], 0, 0, 0);
        }
    }

    int zp = zb*4 + w, yp = yb;
    float bl = bias[col];
    float s = 0.f, q = 0.f;
    float mx0=-1e30f, mx1=-1e30f, mn0=1e30f, mn1=1e30f;
    #pragma unroll
    for (int mt = 0; mt < 4; ++mt)
        #pragma unroll
        for (int j = 0; j < 4; ++j) {
            float v = acc[mt][j] + bl;
            s += v; q = fmaf(v, v, q);
            if (j < 2) { mx0 = fmaxf(mx0, v); mn0 = fminf(mn0, v); }
            else       { mx1 = fmaxf(mx1, v); mn1 = fminf(mn1, v); }
        }
    s += __shfl_xor(s, 16); s += __shfl_xor(s, 32);
    q += __shfl_xor(q, 16); q += __shfl_xor(q, 32);
    if (kg == 0) { red[(w*16 + col)*2] = s; red[(w*16 + col)*2 + 1] = q; }
    size_t ob = ((((size_t)(n*32 + zp))*32 + yp)*32 + xb*8 + kg*2)*16 + col;
    outmax[ob]      = f2b(mx0); outmin[ob]      = f2b(mn0);
    outmax[ob + 16] = f2b(mx1); outmin[ob + 16] = f2b(mn1);
    __syncthreads();
    if (tid < 32) {
        float t = red[tid] + red[32 + tid] + red[64 + tid] + red[96 + tid];
        unsafeAtomicAdd(&stats_part[((bx & 127) << 5) + tid], t);
    }
}

// sum partial stats -> final stats
__global__ void stats_reduce_k(const float* __restrict__ part, float* __restrict__ out,
                               int npart, int n)
{
    int c = blockIdx.x*64 + threadIdx.x;
    if (c >= n) return;
    float s = 0.f;
    for (int p = 0; p < npart; ++p) s += part[p*n + c];
    out[c] = s;
}

__global__ void bn_final_k(const float* __restrict__ stats, const float* __restrict__ g,
                           const float* __restrict__ b, float* __restrict__ sc, float* __restrict__ sh,
                           int C, float invN)
{
    int c = threadIdx.x; if (c >= C) return;
    float m = stats[c*2] * invN;
    float v = stats[c*2+1] * invN - m*m;
    float s = g[c] * rsqrtf(v + 1e-5f);
    sc[c] = s; sh[c] = b[c] - m*s;
}

// prepack conv weights into MFMA B-fragment order (bf16), K padded to 448 per ci-half
__global__ void wfrag_k(const float* __restrict__ wt, ushort* __restrict__ out,
                        int CIN, int COT, int total)
{
    int i = blockIdx.x*256 + threadIdx.x;
    if (i >= total) return;
    int per_h = COT*7168;
    int h  = i / per_h;
    int r0 = i - h*per_h;
    int ct = r0 / 7168;
    int r  = r0 - ct*7168;
    int ks = r >> 9;
    int r2 = r & 511;
    int kg = r2 >> 7, col = (r2 >> 3) & 15, j = r2 & 7;
    int k = ks*32 + kg*8 + j;
    int nbr = k >> 4, ci = (k & 15) + h*16;
    out[i] = (nbr < 27) ? f2b(wt[((size_t)(ct*16 + col)*CIN + ci)*27 + nbr]) : (ushort)0;
}

// ---------------- implicit-GEMM MFMA conv + bias + BN-stats(partial) + max/min pool ----
template<int CIHALVES, int COT, int D, int CIN, int COUT>
__global__ __launch_bounds__(256) void conv_mfma_k(
    const ushort* __restrict__ Xcl, const ushort* __restrict__ WfragG,
    const float* __restrict__ bias,
    ushort* __restrict__ outmax, ushort* __restrict__ outmin,
    float* __restrict__ stats_part, int pmask)
{
    constexpr int PD = D/2;
    constexpr int XT = D/16, YT = D/2;
    __shared__ __align__(16) ushort Ast[17280];
    __shared__ __align__(16) ushort Bfr[COT*7168];
    __shared__ float red[4*COT*32];

    int tid = threadIdx.x;
    int n = blockIdx.y;
    int bx = blockIdx.x;
    int xb = bx % XT, yb = (bx/XT) % YT, zb = bx/(XT*YT);
    int w = tid >> 6, l = tid & 63;
    int col = l & 15, kg = l >> 4;

    int laneoff[14];
    #pragma unroll
    for (int ks = 0; ks < 14; ++ks) {
        int nbr = ks*2 + (l >> 5);
        if (nbr >= 27) nbr = 0;
        int dz = nbr/9, r9 = nbr - dz*9, dy = r9/3, dx = r9 - dy*3;
        laneoff[ks] = dz*1728 + dy*432 + (col + dx)*24 + ((l>>4)&1)*8;
    }
    int Mbase[4];
    #pragma unroll
    for (int mt = 0; mt < 4; ++mt)
        Mbase[mt] = (2*w + (mt>>1))*1728 + (mt&1)*432;

    f32x4 acc[4][COT];
    #pragma unroll
    for (int mt = 0; mt < 4; ++mt)
        #pragma unroll
        for (int ct = 0; ct < COT; ++ct)
            acc[mt][ct] = (f32x4){0.f,0.f,0.f,0.f};

    for (int h = 0; h < CIHALVES; ++h) {
        __syncthreads();
        for (int i = tid; i < 1440; i += 256) {
            int vec = i >> 1, hi8 = (i & 1) << 3;
            int z = vec/72, r = vec - z*72, y = r/18, x = r - y*18;
            int gz = zb*8 - 1 + z, gy = yb*2 - 1 + y, gx = xb*16 - 1 + x;
            ushort8v val = {0,0,0,0,0,0,0,0};
            if ((unsigned)gz < (unsigned)D && (unsigned)gy < (unsigned)D && (unsigned)gx < (unsigned)D) {
                size_t gi = (((size_t)n*D*D*D) + ((size_t)gz*D + gy)*D + gx)*CIN + h*16 + hi8;
                val = *(const ushort8v*)(Xcl + gi);
            }
            *(ushort8v*)(Ast + (vec)*24 + hi8) = val;
        }
        for (int i = tid; i < COT*896; i += 256)
            *(ushort8v*)(Bfr + i*8) = *(const ushort8v*)(WfragG + (size_t)h*COT*7168 + i*8);
        __syncthreads();

        #pragma unroll
        for (int ks = 0; ks < 14; ++ks) {
            short8v a[4];
            #pragma unroll
            for (int mt = 0; mt < 4; ++mt)
                a[mt] = *(const short8v*)(Ast + Mbase[mt] + laneoff[ks]);
            short8v bb[COT];
            #pragma unroll
            for (int ct = 0; ct < COT; ++ct)
                bb[ct] = *(const short8v*)(Bfr + ct*7168 + ks*512 + kg*128 + col*8);
            #pragma unroll
            for (int mt = 0; mt < 4; ++mt)
                #pragma unroll
                for (int ct = 0; ct < COT; ++ct)
                    acc[mt][ct] = __builtin_amdgcn_mfma_f32_16x16x32_bf16(a[mt], bb[ct], acc[mt][ct], 0, 0, 0);
        }
    }

    int zp = zb*4 + w, yp = yb;
    #pragma unroll
    for (int ct = 0; ct < COT; ++ct) {
        float bl = bias[ct*16 + col];
        float s = 0.f, q = 0.f;
        float mx0 = -1e30f, mx1 = -1e30f, mn0 = 1e30f, mn1 = 1e30f;
        #pragma unroll
        for (int mt = 0; mt < 4; ++mt) {
            #pragma unroll
            for (int j = 0; j < 4; ++j) {
                float v = acc[mt][ct][j] + bl;
                s += v; q = fmaf(v, v, q);
                if (j < 2) { mx0 = fmaxf(mx0, v); mn0 = fminf(mn0, v); }
                else       { mx1 = fmaxf(mx1, v); mn1 = fminf(mn1, v); }
            }
        }
        s += __shfl_xor(s, 16); s += __shfl_xor(s, 32);
        q += __shfl_xor(q, 16); q += __shfl_xor(q, 32);
        if (kg == 0) {
            red[((w*COT + ct)*16 + col)*2]     = s;
            red[((w*COT + ct)*16 + col)*2 + 1] = q;
        }
        size_t ob = (((size_t)((n*PD + zp)*PD + yp))*PD + xb*8 + kg*2)*COUT + ct*16 + col;
        outmax[ob]        = f2b(mx0);
        outmin[ob]        = f2b(mn0);
        outmax[ob + COUT] = f2b(mx1);
        outmin[ob + COUT] = f2b(mn1);
    }
    __syncthreads();
    if (tid < COT*32) {
        float t = red[tid] + red[COT*32 + tid] + red[2*COT*32 + tid] + red[3*COT*32 + tid];
        unsafeAtomicAdd(&stats_part[(bx & pmask)*(COT*32) + tid], t);
    }
}

// channels-last bf16 pooled max/min -> BN+ReLU -> bf16
__global__ __launch_bounds__(256) void bn_select_cl23_k(
    const ushort* __restrict__ mx, const ushort* __restrict__ mn,
    const float* __restrict__ sc, const float* __restrict__ sh,
    ushort* __restrict__ out, int cmask, int total)
{
    int idx = blockIdx.x*256 + threadIdx.x;
    if (idx >= total) return;
    int ci = idx & cmask;
    float s = sc[ci];
    float v = b2f((s >= 0.f) ? mx[idx] : mn[idx]);
    out[idx] = f2b(fmaxf(fmaf(v, s, sh[ci]), 0.f));
}

// fc: X channels-last bf16 [16][512][64]; W k-index = c*512 + sp
__global__ __launch_bounds__(128) void fc_acc_k(
    const ushort* __restrict__ X, const float* __restrict__ W, float* __restrict__ featv)
{
    int t = threadIdx.x;
    int k0 = blockIdx.x*256;
    float acc[16];
    #pragma unroll
    for (int b = 0; b < 16; ++b) acc[b] = 0.f;
    for (int k = k0; k < k0 + 256; ++k) {
        float w = W[(size_t)k*128 + t];
        int c = k >> 9, sp = k & 511;
        #pragma unroll
        for (int b = 0; b < 16; ++b)
            acc[b] = fmaf(b2f(X[(size_t)((b*512 + sp))*64 + c]), w, acc[b]);
    }
    for (int b = 0; b < 16; ++b) unsafeAtomicAdd(featv + b*512 + t, acc[b]);
}

// ---------------- dense head layers: K-parallel (4 kgroups x 64 cols), X in LDS ------
// O[16][Ncol] = relu?(X[16][K] @ W[K][Ncol] + b);  K <= 512
__global__ __launch_bounds__(256) void head2_k(
    const float* __restrict__ X, const float* __restrict__ W, const float* __restrict__ b,
    float* __restrict__ O, int K, int Ncol, int relu)
{
    __shared__ float Xs[512*16];      // transposed: [k][bi]
    __shared__ float red[3*16*64];
    int t = threadIdx.x;
    int kg = t >> 6, lane = t & 63;
    int c = blockIdx.x*64 + lane;
    bool valid = (c < Ncol);
    for (int i = t; i < 16*K; i += 256) {
        int bi = i & 15, k = i >> 4;
        Xs[k*16 + bi] = X[bi*K + k];
    }
    __syncthreads();
    float acc[16];
    #pragma unroll
    for (int bi = 0; bi < 16; ++bi) acc[bi] = 0.f;
    for (int k = kg; k < K; k += 4) {
        float w = valid ? W[(size_t)k*Ncol + c] : 0.f;
        const float* xp = Xs + k*16;
        float4 x0 = ld4(xp), x1 = ld4(xp+4), x2 = ld4(xp+8), x3 = ld4(xp+12);
        acc[0]  = fmaf(x0.x, w, acc[0]);  acc[1]  = fmaf(x0.y, w, acc[1]);
        acc[2]  = fmaf(x0.z, w, acc[2]);  acc[3]  = fmaf(x0.w, w, acc[3]);
        acc[4]  = fmaf(x1.x, w, acc[4]);  acc[5]  = fmaf(x1.y, w, acc[5]);
        acc[6]  = fmaf(x1.z, w, acc[6]);  acc[7]  = fmaf(x1.w, w, acc[7]);
        acc[8]  = fmaf(x2.x, w, acc[8]);  acc[9]  = fmaf(x2.y, w, acc[9]);
        acc[10] = fmaf(x2.z, w, acc[10]); acc[11] = fmaf(x2.w, w, acc[11]);
        acc[12] = fmaf(x3.x, w, acc[12]); acc[13] = fmaf(x3.y, w, acc[13]);
        acc[14] = fmaf(x3.z, w, acc[14]); acc[15] = fmaf(x3.w, w, acc[15]);
    }
    if (kg) {
        #pragma unroll
        for (int bi = 0; bi < 16; ++bi) red[((kg-1)*16 + bi)*64 + lane] = acc[bi];
    }
    __syncthreads();
    if (kg == 0 && valid) {
        float bias = b[c];
        #pragma unroll
        for (int bi = 0; bi < 16; ++bi) {
            float v = acc[bi] + red[bi*64 + lane] + red[(16 + bi)*64 + lane]
                    + red[(32 + bi)*64 + lane] + bias;
            if (relu) v = fmaxf(v, 0.f);
            O[bi*Ncol + c] = v;
        }
    }
}

__global__ void gebn_k(const float* __restrict__ g2, const float* __restrict__ g,
                       const float* __restrict__ b, float* __restrict__ featg)
{
    int c = threadIdx.x;
    float m = 0.f;
    for (int i = 0; i < 16; ++i) m += g2[i*128 + c];
    m *= (1.f/16.f);
    float v = 0.f;
    for (int i = 0; i < 16; ++i) { float d = g2[i*128 + c] - m; v += d*d; }
    v *= (1.f/16.f);
    float s = g[c] * rsqrtf(v + 1e-5f);
    for (int i = 0; i < 16; ++i)
        featg[i*512 + c] = fmaxf((g2[i*128 + c] - m)*s + b[c], 0.f);
}

__global__ void finalize_feat_k(float* __restrict__ feat, const float* __restrict__ cntm,
                                const float* __restrict__ cntz, const float* __restrict__ fcb)
{
    int t = blockIdx.x*256 + threadIdx.x;
    if (t >= 8192) return;
    int bi = t >> 9, c = t & 511;
    float v = feat[t];
    if      (c < 128) v /= fmaxf(cntm[bi], 1.f);
    else if (c < 256) v /= fmaxf(cntz[bi], 1.f);
    else if (c >= 384) v = fmaxf(v + fcb[c - 384], 0.f);
    feat[t] = v;
}

// =====================================================================================
extern "C" void kernel_launch(void* const* d_in, const int* in_sizes, int n_in,
                              void* d_out, int out_size, void* d_ws, size_t ws_size,
                              hipStream_t stream)
{
    const int*   mol_x  = (const int*)  d_in[0];
    const float* mol_q  = (const float*)d_in[1];
    const int*   mol_ei = (const int*)  d_in[2];
    const float* mol_ew = (const float*)d_in[3];
    const int*   mol_bv = (const int*)  d_in[4];
    const int*   zeo_x  = (const int*)  d_in[5];
    const int*   zeo_ei = (const int*)  d_in[6];
    const int*   zeo_bv = (const int*)  d_in[7];
    const float* voxel  = (const float*)d_in[8];
    const float* gattr  = (const float*)d_in[9];
    const float* ea  = (const float*)d_in[10];
    const float* ed  = (const float*)d_in[11];
    const float* ec  = (const float*)d_in[12];
    const float* eh  = (const float*)d_in[13];
    const float* ear = (const float*)d_in[14];
    const float* ech = (const float*)d_in[15];
    const float* mc1w=(const float*)d_in[16]; const float* mc1b=(const float*)d_in[17];
    const float* mc2w=(const float*)d_in[18]; const float* mc2b=(const float*)d_in[19];
    const float* zc1w=(const float*)d_in[20]; const float* zc1b=(const float*)d_in[21];
    const float* zc2w=(const float*)d_in[22]; const float* zc2b=(const float*)d_in[23];
    const float* cv1w=(const float*)d_in[24]; const float* cv1b=(const float*)d_in[25];
    const float* bn1g=(const float*)d_in[26]; const float* bn1b=(const float*)d_in[27];
    const float* cv2w=(const float*)d_in[28]; const float* cv2b=(const float*)d_in[29];
    const float* bn2g=(const float*)d_in[30]; const float* bn2b=(const float*)d_in[31];
    const float* cv3w=(const float*)d_in[32]; const float* cv3b=(const float*)d_in[33];
    const float* bn3g=(const float*)d_in[34]; const float* bn3b=(const float*)d_in[35];
    const float* fcw =(const float*)d_in[36]; const float* fcb =(const float*)d_in[37];
    const float* ge1w=(const float*)d_in[38]; const float* ge1b=(const float*)d_in[39];
    const float* ge2w=(const float*)d_in[40]; const float* ge2b=(const float*)d_in[41];
    const float* gbng=(const float*)d_in[42]; const float* gbnb=(const float*)d_in[43];
    const float* h1w =(const float*)d_in[44]; const float* h1b =(const float*)d_in[45];
    const float* h2w =(const float*)d_in[46]; const float* h2b =(const float*)d_in[47];
    const float* h3w =(const float*)d_in[48]; const float* h3b =(const float*)d_in[49];

    const int Nm = in_sizes[0]/6, Em = in_sizes[2]/2;
    const int Nz = in_sizes[5]/6, Ez = in_sizes[6]/2;
    const int NBm = (Nm + 1023)/1024, NBz = (Nz + 1023)/1024;

    float* WS = (float*)d_ws;
    float* A  = WS;
    float* Bb = WS + 16777216;
    float* S  = WS + 33554432;
    ushort* X0 = (ushort*)A;
    ushort* X1 = (ushort*)A + 16777216;
    ushort* X2 = (ushort*)Bb;
    ushort* X3 = (ushort*)Bb + 16777216;
    // conv-phase channels-last bf16 buffers (GNN buffers dead by then)
    ushort* Au   = (ushort*)A;
    ushort* pm1  = Au;                      // [16][32^3][16]
    ushort* pn1  = Au + 8388608;
    ushort* Xcl0 = Au + 16777216;           // [16][64^3][2]
    ushort* Xcl1 = (ushort*)Bb;             // [16][32^3][16]
    ushort* pm2  = Au;                      // [16][16^3][32]
    ushort* pn2  = Au + 2097152;
    ushort* Xcl2 = Au + 4194304;
    ushort* pm3  = (ushort*)Bb;             // [16][8^3][64]
    ushort* pn3  = (ushort*)Bb + 524288;
    ushort* Xcl3 = (ushort*)Bb + 1048576;
    float* deg  = S;
    float* dis  = S + 131072;
    float* csr_nrm = S + 262144;
    float* T    = S + 786432;
    float* cntm = S + 807040;
    float* cntz = S + 807056;
    float* feat = S + 807072;
    float* st1  = S + 815264; float* st2 = st1 + 32; float* st3 = st1 + 96;
    float* sc1  = S + 815488; float* sh1 = sc1 + 16;
    float* sc2  = sc1 + 32;   float* sh2 = sc1 + 64;
    float* sc3  = sc1 + 96;   float* sh3 = sc1 + 160;
    float* g1   = S + 815712;
    float* g2   = S + 816736;
    float* H1   = S + 818784;
    float* H2   = S + 826976;
    int* rowptr  = (int*)(S + 831072);          // 131073
    int* cursor  = (int*)(S + 962176);          // 131072
    int* csr_src = (int*)(S + 1093248);         // 524288 (ends S+1617536)
    ushort* wf2 = (ushort*)(S + 1617536);       // 14336 ush
    ushort* wf3 = (ushort*)(S + 1624704);       // 57344 ush
    int* bsum   = (int*)(S + 1653376);          // 256 ints
    ushort* wf1 = (ushort*)(S + 1653632);       // 2560 ush
    float* stp1 = S + 1655040;                  // 128*32
    float* stp2 = S + 1659136;                  // 32*64
    float* stp3 = S + 1661184;                  // 8*128 (ends S+1662208)

    hipMemsetAsync(S, 0, (size_t)831072*sizeof(float), stream);
    hipMemsetAsync(stp1, 0, (size_t)7168*sizeof(float), stream);

    // weight prepacks for MFMA convs
    wfrag1_k<<<10,256,0,stream>>>(cv1w, wf1);
    wfrag_k<<<56,256,0,stream>>>(cv2w, wf2, 16, 2, 14336);
    wfrag_k<<<224,256,0,stream>>>(cv3w, wf3, 32, 4, 57344);

    // ---------------- molecule branch ----------------
    build_tables_k<<<161,128,0,stream>>>(ea,ed,ec,eh,ear,ech, mc1w, T);
    init_deg_k   <<<Nm/256,256,0,stream>>>(deg, Nm);
    deg_scatter_k<<<Em/256,256,0,stream>>>(mol_ei+Em, mol_ew, deg, Em);
    dis_k        <<<Nm/256,256,0,stream>>>(deg, dis, Nm);
    hipMemsetAsync(cursor, 0, (size_t)Nm*sizeof(int), stream);
    count_in_k   <<<Em/256,256,0,stream>>>(mol_ei+Em, cursor, Em);
    blocksum_k   <<<NBm,256,0,stream>>>(cursor, bsum, Nm);
    scan_bsum_k  <<<1,256,0,stream>>>(bsum, NBm);
    scan_apply_k <<<NBm,256,0,stream>>>(cursor, bsum, rowptr, Nm, Em);
    fill_csr_k   <<<Em/256,256,0,stream>>>(mol_ei, mol_ei+Em, mol_ew, dis, cursor, csr_src, csr_nrm, Em);
    embed_lookup_k<<<Nm/8,256,0,stream>>>(mol_x, mol_q, T, mc1w + 112*128, X0, Nm);
    gcn_gather_k <<<Nm/8,256,0,stream>>>(X0, rowptr, csr_src, csr_nrm, dis, mc1b, X1, Nm);
    gemm_mfma_k  <<<Nm/64,256,0,stream>>>(X1, mc2w, X2, Nm);
    gcn_gather_k <<<Nm/8,256,0,stream>>>(X2, rowptr, csr_src, csr_nrm, dis, mc2b, X3, Nm);
    count_batch_k<<<Nm/256,256,0,stream>>>(mol_bv, cntm, Nm);
    mean_pool_sum_k<<<256,128,0,stream>>>(X3, mol_bv, feat + 0, (Nm+255)/256, Nm);

    // ---------------- zeolite branch ----------------
    build_tables_k<<<161,128,0,stream>>>(ea,ed,ec,eh,ear,ech, zc1w, T);
    init_deg_k   <<<Nz/256,256,0,stream>>>(deg, Nz);
    deg_scatter_k<<<Ez/256,256,0,stream>>>(zeo_ei+Ez, nullptr, deg, Ez);
    dis_k        <<<Nz/256,256,0,stream>>>(deg, dis, Nz);
    hipMemsetAsync(cursor, 0, (size_t)Nz*sizeof(int), stream);
    count_in_k   <<<Ez/256,256,0,stream>>>(zeo_ei+Ez, cursor, Ez);
    blocksum_k   <<<NBz,256,0,stream>>>(cursor, bsum, Nz);
    scan_bsum_k  <<<1,256,0,stream>>>(bsum, NBz);
    scan_apply_k <<<NBz,256,0,stream>>>(cursor, bsum, rowptr, Nz, Ez);
    fill_csr_k   <<<Ez/256,256,0,stream>>>(zeo_ei, zeo_ei+Ez, nullptr, dis, cursor, csr_src, csr_nrm, Ez);
    embed_lookup_k<<<Nz/8,256,0,stream>>>(zeo_x, nullptr, T, nullptr, X0, Nz);
    gcn_gather_k <<<Nz/8,256,0,stream>>>(X0, rowptr, csr_src, csr_nrm, dis, zc1b, X1, Nz);
    gemm_mfma_k  <<<Nz/64,256,0,stream>>>(X1, zc2w, X2, Nz);
    gcn_gather_k <<<Nz/8,256,0,stream>>>(X2, rowptr, csr_src, csr_nrm, dis, zc2b, X3, Nz);
    count_batch_k<<<Nz/256,256,0,stream>>>(zeo_bv, cntz, Nz);
    mean_pool_sum_k<<<256,128,0,stream>>>(X3, zeo_bv, feat + 128, (Nz+255)/256, Nz);

    // ---------------- voxel CNN (all layers MFMA implicit-GEMM) ----------------
    cvt_cl0_k<<<16384,256,0,stream>>>(voxel, (unsigned*)Xcl0);
    conv1_mfma_k<<<dim3(1024,16),256,0,stream>>>(Xcl0, wf1, cv1b, pm1, pn1, stp1);
    stats_reduce_k<<<1,64,0,stream>>>(stp1, st1, 128, 32);
    bn_final_k<<<1,64,0,stream>>>(st1, bn1g, bn1b, sc1, sh1, 16, 1.f/(16.f*262144.f));
    bn_select_cl23_k<<<32768,256,0,stream>>>(pm1, pn1, sc1, sh1, Xcl1, 15, 8388608);

    conv_mfma_k<1,2,32,16,32><<<dim3(128,16),256,0,stream>>>(Xcl1, wf2, cv2b, pm2, pn2, stp2, 31);
    stats_reduce_k<<<1,64,0,stream>>>(stp2, st2, 32, 64);
    bn_final_k<<<1,64,0,stream>>>(st2, bn2g, bn2b, sc2, sh2, 32, 1.f/(16.f*32768.f));
    bn_select_cl23_k<<<8192,256,0,stream>>>(pm2, pn2, sc2, sh2, Xcl2, 31, 2097152);

    conv_mfma_k<2,4,16,32,64><<<dim3(16,16),256,0,stream>>>(Xcl2, wf3, cv3b, pm3, pn3, stp3, 7);
    stats_reduce_k<<<2,64,0,stream>>>(stp3, st3, 8, 128);
    bn_final_k<<<1,64,0,stream>>>(st3, bn3g, bn3b, sc3, sh3, 64, 1.f/(16.f*4096.f));
    bn_select_cl23_k<<<2048,256,0,stream>>>(pm3, pn3, sc3, sh3, Xcl3, 63, 524288);

    fc_acc_k<<<128,128,0,stream>>>(Xcl3, fcw, feat + 384);

    // ---------------- global encoder ----------------
    head2_k<<<1,256,0,stream>>>(gattr, ge1w, ge1b, g1, 17, 64, 1);
    head2_k<<<2,256,0,stream>>>(g1, ge2w, ge2b, g2, 64, 128, 0);
    gebn_k<<<1,128,0,stream>>>(g2, gbng, gbnb, feat + 256);

    // ---------------- fusion head ----------------
    finalize_feat_k<<<32,256,0,stream>>>(feat, cntm, cntz, fcb);
    head2_k<<<8,256,0,stream>>>(feat, h1w, h1b, H1, 512, 512, 1);
    head2_k<<<4,256,0,stream>>>(H1, h2w, h2b, H2, 512, 256, 1);
    head2_k<<<1,256,0,stream>>>(H2, h3w, h3b, (float*)d_out, 256, 3, 0);
}

// Round 15
// 922.616 us; speedup vs baseline: 1.6637x; 1.2827x over previous
//
#include <hip/hip_runtime.h>
#include <math.h>

#define DEV static __device__ __forceinline__

DEV float4 ld4(const float* p){ return *(const float4*)p; }
DEV float2 ld2(const float* p){ return *(const float2*)p; }
DEV void   st4(float* p, float4 v){ *(float4*)p = v; }
DEV float4 f4add(float4 a, float4 b){ return make_float4(a.x+b.x,a.y+b.y,a.z+b.z,a.w+b.w); }
DEV float4 f4fma(float s, float4 a, float4 c){ return make_float4(fmaf(s,a.x,c.x),fmaf(s,a.y,c.y),fmaf(s,a.z,c.z),fmaf(s,a.w,c.w)); }

// bf16 helpers (RNE pack, exact unpack)
DEV float  b2f(ushort u){ return __uint_as_float(((unsigned)u) << 16); }
DEV ushort f2b(float f){
    unsigned u = __float_as_uint(f);
    return (ushort)((u + 0x7FFFu + ((u >> 16) & 1u)) >> 16);
}
DEV float4 b2f4(ushort4 v){ return make_float4(b2f(v.x), b2f(v.y), b2f(v.z), b2f(v.w)); }
DEV ushort4 f2b4(float4 v){ ushort4 o; o.x=f2b(v.x); o.y=f2b(v.y); o.z=f2b(v.z); o.w=f2b(v.w); return o; }

typedef __attribute__((ext_vector_type(8))) short short8v;            // 8 bf16 = 4 VGPR
typedef __attribute__((ext_vector_type(8))) unsigned short ushort8v;
typedef __attribute__((ext_vector_type(4))) float f32x4;

DEV short8v ld_a8(const ushort* p){   // 8B-aligned 16B LDS read as 2x b64
    ushort4 a = *(const ushort4*)p;
    ushort4 b = *(const ushort4*)(p+4);
    short8v r;
    r[0]=a.x; r[1]=a.y; r[2]=a.z; r[3]=a.w;
    r[4]=b.x; r[5]=b.y; r[6]=b.z; r[7]=b.w;
    return r;
}

// ---------------- GNN: embedding tables  T[161][128] = emb_f @ W_slice ----------------
__global__ __launch_bounds__(128) void build_tables_k(
    const float* __restrict__ ea, const float* __restrict__ ed, const float* __restrict__ ec,
    const float* __restrict__ eh, const float* __restrict__ ear, const float* __restrict__ ech,
    const float* __restrict__ Wm, float* __restrict__ T)
{
    int r = blockIdx.x, c = threadIdx.x;
    const float* e; int dim, woff, rl;
    if      (r < 120) { e=ea;  dim=64; woff=0;   rl=r; }
    else if (r < 132) { e=ed;  dim=16; woff=64;  rl=r-120; }
    else if (r < 147) { e=ec;  dim=16; woff=80;  rl=r-132; }
    else if (r < 155) { e=eh;  dim=8;  woff=96;  rl=r-147; }
    else if (r < 157) { e=ear; dim=4;  woff=104; rl=r-155; }
    else              { e=ech; dim=4;  woff=108; rl=r-157; }
    float acc = 0.f;
    for (int k = 0; k < dim; ++k) acc += e[rl*dim + k] * Wm[(woff + k)*128 + c];
    T[r*128 + c] = acc;
}

__global__ __launch_bounds__(256) void embed_lookup_k(
    const int* __restrict__ xi, const float* __restrict__ charge,
    const float* __restrict__ T, const float* __restrict__ wq,
    ushort* __restrict__ H, int N)
{
    int t = threadIdx.x;
    int node = blockIdx.x*8 + (t >> 5);
    if (node >= N) return;
    int c = (t & 31)*4;
    const int* xp = xi + node*6;
    float4 acc = ld4(T + (       xp[0])*128 + c);
    acc = f4add(acc, ld4(T + (120+xp[1])*128 + c));
    acc = f4add(acc, ld4(T + (132+xp[2])*128 + c));
    acc = f4add(acc, ld4(T + (147+xp[3])*128 + c));
    acc = f4add(acc, ld4(T + (155+xp[4])*128 + c));
    acc = f4add(acc, ld4(T + (157+xp[5])*128 + c));
    if (charge) acc = f4fma(charge[node], ld4(wq + c), acc);
    *(ushort4*)(H + (size_t)node*128 + c) = f2b4(acc);
}

// ---------------- GCN degree / norm / CSR build ----------------
__global__ void init_deg_k(float* deg, int N){ int i = blockIdx.x*256+threadIdx.x; if (i<N) deg[i]=1.f; }

__global__ void deg_scatter_k(const int* __restrict__ col, const float* __restrict__ ew, float* deg, int E){
    int e = blockIdx.x*256+threadIdx.x; if (e>=E) return;
    unsafeAtomicAdd(deg + col[e], ew ? ew[e] : 1.f);
}

__global__ void dis_k(const float* __restrict__ deg, float* __restrict__ dis, int N){
    int i = blockIdx.x*256+threadIdx.x; if (i<N) dis[i] = 1.f/sqrtf(deg[i]);
}

__global__ void count_in_k(const int* __restrict__ col, int* __restrict__ cnt, int E){
    int e = blockIdx.x*256+threadIdx.x; if (e>=E) return;
    atomicAdd(&cnt[col[e]], 1);
}

// ---- multi-block exclusive scan (3 phases; 1024 elems / block) ----
__global__ __launch_bounds__(256) void blocksum_k(const int* __restrict__ cnt, int* __restrict__ bsum, int N){
    int b = blockIdx.x, t = threadIdx.x;
    int base = b*1024 + t*4;
    int s = 0;
    if (base + 3 < N) { int4 v = *(const int4*)(cnt + base); s = v.x + v.y + v.z + v.w; }
    else { for (int i = 0; i < 4; ++i) { int idx = base + i; if (idx < N) s += cnt[idx]; } }
    __shared__ int red[256];
    red[t] = s; __syncthreads();
    for (int off = 128; off; off >>= 1) { if (t < off) red[t] += red[t+off]; __syncthreads(); }
    if (!t) bsum[b] = red[0];
}

__global__ __launch_bounds__(256) void scan_bsum_k(int* __restrict__ bsum, int NB){
    int t = threadIdx.x;
    __shared__ int sh[256];
    sh[t] = (t < NB) ? bsum[t] : 0;
    __syncthreads();
    for (int off = 1; off < 256; off <<= 1) {
        int v = (t >= off) ? sh[t-off] : 0;
        __syncthreads();
        sh[t] += v;
        __syncthreads();
    }
    if (t < NB) bsum[t] = (t == 0) ? 0 : sh[t-1];
}

__global__ __launch_bounds__(256) void scan_apply_k(int* cur, const int* __restrict__ bsum,
                                                    int* __restrict__ rowptr, int N, int E){
    int b = blockIdx.x, t = threadIdx.x;
    int base = b*1024 + t*4;
    int c[4]; int s = 0;
    #pragma unroll
    for (int i = 0; i < 4; ++i) { int idx = base + i; c[i] = (idx < N) ? cur[idx] : 0; s += c[i]; }
    __shared__ int sh[256];
    sh[t] = s; __syncthreads();
    for (int off = 1; off < 256; off <<= 1) {
        int v = (t >= off) ? sh[t-off] : 0;
        __syncthreads();
        sh[t] += v;
        __syncthreads();
    }
    int run = bsum[b] + ((t == 0) ? 0 : sh[t-1]);
    #pragma unroll
    for (int i = 0; i < 4; ++i) {
        int idx = base + i;
        if (idx < N) { rowptr[idx] = run; cur[idx] = run; run += c[i]; }
    }
    if (b == 0 && t == 0) rowptr[N] = E;
}

__global__ void fill_csr_k(const int* __restrict__ row, const int* __restrict__ col,
                           const float* __restrict__ ew, const float* __restrict__ dis,
                           int* __restrict__ cursor, int* __restrict__ csr_src,
                           float* __restrict__ csr_nrm, int E)
{
    int e = blockIdx.x*256+threadIdx.x; if (e>=E) return;
    int r = row[e], c = col[e];
    int pos = atomicAdd(&cursor[c], 1);
    csr_src[pos] = r;
    csr_nrm[pos] = dis[r] * (ew ? ew[e] : 1.f) * dis[c];
}

// O[i] = bias + dis[i]^2 * H[i] + sum_j nrm_j * H[src_j]   -- bf16 in/out, fp32 math
__global__ __launch_bounds__(256) void gcn_gather_k(
    const ushort* __restrict__ H, const int* __restrict__ rowptr,
    const int* __restrict__ csr_src, const float* __restrict__ csr_nrm,
    const float* __restrict__ dis, const float* __restrict__ bias,
    ushort* __restrict__ O, int N)
{
    int node = blockIdx.x*8 + (threadIdx.x >> 5);
    if (node >= N) return;
    int lane = (threadIdx.x & 31)*4;
    float s = dis[node]; s *= s;
    float4 h = b2f4(*(const ushort4*)(H + (size_t)node*128 + lane));
    float4 b = ld4(bias + lane);
    float4 acc = f4fma(s, h, b);
    int j = rowptr[node], end = rowptr[node+1];
    for (; j + 4 <= end; j += 4) {
        int   s0 = csr_src[j],   s1 = csr_src[j+1], s2 = csr_src[j+2], s3 = csr_src[j+3];
        float n0 = csr_nrm[j],   n1 = csr_nrm[j+1], n2 = csr_nrm[j+2], n3 = csr_nrm[j+3];
        float4 h0 = b2f4(*(const ushort4*)(H + (size_t)s0*128 + lane));
        float4 h1 = b2f4(*(const ushort4*)(H + (size_t)s1*128 + lane));
        float4 h2 = b2f4(*(const ushort4*)(H + (size_t)s2*128 + lane));
        float4 h3 = b2f4(*(const ushort4*)(H + (size_t)s3*128 + lane));
        acc = f4fma(n0, h0, acc);
        acc = f4fma(n1, h1, acc);
        acc = f4fma(n2, h2, acc);
        acc = f4fma(n3, h3, acc);
    }
    for (; j < end; ++j) {
        float4 h0 = b2f4(*(const ushort4*)(H + (size_t)csr_src[j]*128 + lane));
        acc = f4fma(csr_nrm[j], h0, acc);
    }
    *(ushort4*)(O + (size_t)node*128 + lane) = f2b4(acc);
}

// O = relu(A) @ W via bf16 MFMA; A:[N,128] bf16, W:[128,128] f32, O bf16
__global__ __launch_bounds__(256) void gemm_mfma_k(
    const ushort* __restrict__ A, const float* __restrict__ W,
    ushort* __restrict__ O, int N)
{
    __shared__ ushort WsF[16384];
    __shared__ ushort As[64*136];
    int t = threadIdx.x;
    for (int i = t; i < 16384; i += 256) {
        int j = i & 7, col = (i >> 3) & 15, kg = (i >> 7) & 3, ks = (i >> 9) & 3, ct = i >> 11;
        WsF[i] = f2b(W[(ks*32 + kg*8 + j)*128 + ct*16 + col]);
    }
    int row0 = blockIdx.x*64;
    for (int i = t; i < 64*32; i += 256) {
        int r = i >> 5, c4 = (i & 31)*4;
        ushort4 v = *(const ushort4*)(A + (size_t)(row0 + r)*128 + c4);
        v.x = (v.x & 0x8000) ? 0 : v.x;
        v.y = (v.y & 0x8000) ? 0 : v.y;
        v.z = (v.z & 0x8000) ? 0 : v.z;
        v.w = (v.w & 0x8000) ? 0 : v.w;
        *(ushort4*)(As + r*136 + c4) = v;
    }
    __syncthreads();
    int w = t >> 6, l = t & 63;
    int m16 = l & 15, kg = l >> 4;
    short8v af[4];
    #pragma unroll
    for (int ks = 0; ks < 4; ++ks)
        af[ks] = *(const short8v*)(As + (w*16 + m16)*136 + ks*32 + kg*8);
    #pragma unroll
    for (int ct = 0; ct < 8; ++ct) {
        f32x4 acc = {0.f, 0.f, 0.f, 0.f};
        #pragma unroll
        for (int ks = 0; ks < 4; ++ks) {
            short8v bf = *(const short8v*)(WsF + ((ct*4 + ks)*4 + kg)*128 + m16*8);
            acc = __builtin_amdgcn_mfma_f32_16x16x32_bf16(af[ks], bf, acc, 0, 0, 0);
        }
        int col = ct*16 + m16;
        int rbase = row0 + w*16 + kg*4;
        #pragma unroll
        for (int j = 0; j < 4; ++j)
            O[(size_t)(rbase + j)*128 + col] = f2b(acc[j]);
    }
}

// ---------------- mean pool (bf16 input): 4-way pipelined, LDS-direct accumulation ----
__global__ __launch_bounds__(128) void mean_pool_sum_k(
    const ushort* __restrict__ X, const int* __restrict__ bv,
    float* __restrict__ featp, int chunk, int N)
{
    __shared__ float acc[16*128];
    int t = threadIdx.x;
    #pragma unroll
    for (int b = 0; b < 16; ++b) acc[b*128 + t] = 0.f;
    int i0 = blockIdx.x * chunk;
    int iend = min(i0 + chunk, N);
    int i = i0;
    for (; i + 4 <= iend; i += 4) {
        int b0 = bv[i], b1 = bv[i+1], b2 = bv[i+2], b3 = bv[i+3];
        float v0 = fmaxf(b2f(X[(size_t)i*128 + t]),     0.f);
        float v1 = fmaxf(b2f(X[(size_t)(i+1)*128 + t]), 0.f);
        float v2 = fmaxf(b2f(X[(size_t)(i+2)*128 + t]), 0.f);
        float v3 = fmaxf(b2f(X[(size_t)(i+3)*128 + t]), 0.f);
        acc[b0*128 + t] += v0;
        acc[b1*128 + t] += v1;
        acc[b2*128 + t] += v2;
        acc[b3*128 + t] += v3;
    }
    for (; i < iend; ++i) {
        int b = bv[i];
        acc[b*128 + t] += fmaxf(b2f(X[(size_t)i*128 + t]), 0.f);
    }
    #pragma unroll
    for (int b = 0; b < 16; ++b) {
        float v = acc[b*128 + t];
        if (v != 0.f) unsafeAtomicAdd(featp + b*512 + t, v);
    }
}

__global__ void count_batch_k(const int* __restrict__ bv, float* __restrict__ cnt, int N){
    __shared__ int h[16];
    int t = threadIdx.x;
    if (t < 16) h[t] = 0;
    __syncthreads();
    int i = blockIdx.x*256 + t;
    if (i < N) atomicAdd(&h[bv[i]], 1);
    __syncthreads();
    if (t < 16 && h[t]) unsafeAtomicAdd(&cnt[t], (float)h[t]);
}

// ---------------- voxel fp32 NCDHW -> bf16 channels-last [n][64^3][2] ----------------
__global__ __launch_bounds__(256) void cvt_cl0_k(const float* __restrict__ vox, unsigned* __restrict__ out){
    int idx = blockIdx.x*256 + threadIdx.x;       // 16 * 262144
    int n = idx >> 18, v = idx & 262143;
    float a = vox[((size_t)n*2    )*262144 + v];
    float b = vox[((size_t)n*2 + 1)*262144 + v];
    out[idx] = (unsigned)f2b(a) | ((unsigned)f2b(b) << 16);
}

// conv1 weight prepack: k = rowIdx*16 + dx*4 + ci (ci padded 2->4, rows padded 9->10)
__global__ void wfrag1_k(const float* __restrict__ wt, ushort* __restrict__ out){
    int i = blockIdx.x*256 + threadIdx.x;
    if (i >= 2560) return;
    int j = i & 7, col = (i >> 3) & 15, kg = (i >> 7) & 3, ks = i >> 9;
    int rowIdx = ks*2 + (kg >> 1);
    int dx = (kg & 1)*2 + (j >> 2), ci = j & 3;
    ushort v = 0;
    if (rowIdx < 9 && dx < 3 && ci < 2)
        v = f2b(wt[(col*2 + ci)*27 + (rowIdx/3)*9 + (rowIdx%3)*3 + dx]);
    out[i] = v;
}

// conv1 implicit-GEMM MFMA: CL bf16 [n][64^3][2] -> pooled max/min CL [n][32^3][16]
__global__ __launch_bounds__(256) void conv1_mfma_k(
    const ushort* __restrict__ Xcl0, const ushort* __restrict__ wf,
    const float* __restrict__ bias,
    ushort* __restrict__ outmax, ushort* __restrict__ outmin, float* __restrict__ stats_part)
{
    __shared__ __align__(16) ushort Ast[2896];    // [10z][4y][18x][4ci-pad] (2880) + guard
    __shared__ __align__(16) ushort Bfr[2560];
    __shared__ float red[128];

    int tid = threadIdx.x;
    int n = blockIdx.y;
    int bx = blockIdx.x;
    int xb = bx & 3, yb = (bx >> 2) & 31, zb = bx >> 7;
    int w = tid >> 6, l = tid & 63;
    int col = l & 15, kg = l >> 4;

    for (int i = tid; i < 320; i += 256)
        *(ushort8v*)(Bfr + i*8) = *(const ushort8v*)(wf + i*8);
    for (int i = tid; i < 720; i += 256) {
        int z = i/72, r = i - z*72, y = r/18, x = r - y*18;
        int gz = zb*8 - 1 + z, gy = yb*2 - 1 + y, gx = xb*16 - 1 + x;
        unsigned packed = 0;
        if ((unsigned)gz < 64u && (unsigned)gy < 64u && (unsigned)gx < 64u)
            packed = *(const unsigned*)(Xcl0 + ((((size_t)n << 18) + ((gz*64 + gy)*64 + gx)) << 1));
        *(uint2*)(Ast + i*4) = make_uint2(packed, 0u);
    }
    if (tid < 2) *(uint2*)(Ast + 2880 + tid*4) = make_uint2(0u, 0u);
    __syncthreads();

    int halfoff = (kg & 1)*2;
    f32x4 acc[4];
    #pragma unroll
    for (int mt = 0; mt < 4; ++mt) acc[mt] = (f32x4){0.f,0.f,0.f,0.f};

    #pragma unroll
    for (int ks = 0; ks < 5; ++ks) {
        int rowIdx = ks*2 + (kg >> 1); if (rowIdx >= 9) rowIdx = 0;
        int kd = rowIdx/3, kh = rowIdx - kd*3;
        int off = kd*288 + kh*72 + (col + halfoff)*4;
        short8v bb = *(const short8v*)(Bfr + (ks*4 + kg)*128 + col*8);
        #pragma unroll
        for (int mt = 0; mt < 4; ++mt) {
            const ushort* p = Ast + (2*w + (mt>>1))*288 + (mt&1)*72 + off;
            short8v a = ld_a8(p);
            acc[mt] = __builtin_amdgcn_mfma_f32_16x16x32_bf16(a, bb, acc[mt], 0, 0, 0);
        }
    }

    int zp = zb*4 + w, yp = yb;
    float bl = bias[col];
    float s = 0.f, q = 0.f;
    float mx0=-1e30f, mx1=-1e30f, mn0=1e30f, mn1=1e30f;
    #pragma unroll
    for (int mt = 0; mt < 4; ++mt)
        #pragma unroll
        for (int j = 0; j < 4; ++j) {
            float v = acc[mt][j] + bl;
            s += v; q = fmaf(v, v, q);
            if (j < 2) { mx0 = fmaxf(mx0, v); mn0 = fminf(mn0, v); }
            else       { mx1 = fmaxf(mx1, v); mn1 = fminf(mn1, v); }
        }
    s += __shfl_xor(s, 16); s += __shfl_xor(s, 32);
    q += __shfl_xor(q, 16); q += __shfl_xor(q, 32);
    if (kg == 0) { red[(w*16 + col)*2] = s; red[(w*16 + col)*2 + 1] = q; }
    size_t ob = ((((size_t)(n*32 + zp))*32 + yp)*32 + xb*8 + kg*2)*16 + col;
    outmax[ob]      = f2b(mx0); outmin[ob]      = f2b(mn0);
    outmax[ob + 16] = f2b(mx1); outmin[ob + 16] = f2b(mn1);
    __syncthreads();
    if (tid < 32) {
        float t = red[tid] + red[32 + tid] + red[64 + tid] + red[96 + tid];
        unsafeAtomicAdd(&stats_part[((bx & 127) << 5) + tid], t);
    }
}

// sum partial stats -> final stats
__global__ void stats_reduce_k(const float* __restrict__ part, float* __restrict__ out,
                               int npart, int n)
{
    int c = blockIdx.x*64 + threadIdx.x;
    if (c >= n) return;
    float s = 0.f;
    for (int p = 0; p < npart; ++p) s += part[p*n + c];
    out[c] = s;
}

__global__ void bn_final_k(const float* __restrict__ stats, const float* __restrict__ g,
                           const float* __restrict__ b, float* __restrict__ sc, float* __restrict__ sh,
                           int C, float invN)
{
    int c = threadIdx.x; if (c >= C) return;
    float m = stats[c*2] * invN;
    float v = stats[c*2+1] * invN - m*m;
    float s = g[c] * rsqrtf(v + 1e-5f);
    sc[c] = s; sh[c] = b[c] - m*s;
}

// prepack conv weights into MFMA B-fragment order (bf16), K padded to 448 per ci-half
__global__ void wfrag_k(const float* __restrict__ wt, ushort* __restrict__ out,
                        int CIN, int COT, int total)
{
    int i = blockIdx.x*256 + threadIdx.x;
    if (i >= total) return;
    int per_h = COT*7168;
    int h  = i / per_h;
    int r0 = i - h*per_h;
    int ct = r0 / 7168;
    int r  = r0 - ct*7168;
    int ks = r >> 9;
    int r2 = r & 511;
    int kg = r2 >> 7, col = (r2 >> 3) & 15, j = r2 & 7;
    int k = ks*32 + kg*8 + j;
    int nbr = k >> 4, ci = (k & 15) + h*16;
    out[i] = (nbr < 27) ? f2b(wt[((size_t)(ct*16 + col)*CIN + ci)*27 + nbr]) : (ushort)0;
}

// ---------------- implicit-GEMM MFMA conv + bias + BN-stats(partial) + max/min pool ----
template<int CIHALVES, int COT, int D, int CIN, int COUT>
__global__ __launch_bounds__(256) void conv_mfma_k(
    const ushort* __restrict__ Xcl, const ushort* __restrict__ WfragG,
    const float* __restrict__ bias,
    ushort* __restrict__ outmax, ushort* __restrict__ outmin,
    float* __restrict__ stats_part, int pmask)
{
    constexpr int PD = D/2;
    constexpr int XT = D/16, YT = D/2;
    __shared__ __align__(16) ushort Ast[17280];
    __shared__ __align__(16) ushort Bfr[COT*7168];
    __shared__ float red[4*COT*32];

    int tid = threadIdx.x;
    int n = blockIdx.y;
    int bx = blockIdx.x;
    int xb = bx % XT, yb = (bx/XT) % YT, zb = bx/(XT*YT);
    int w = tid >> 6, l = tid & 63;
    int col = l & 15, kg = l >> 4;

    int laneoff[14];
    #pragma unroll
    for (int ks = 0; ks < 14; ++ks) {
        int nbr = ks*2 + (l >> 5);
        if (nbr >= 27) nbr = 0;
        int dz = nbr/9, r9 = nbr - dz*9, dy = r9/3, dx = r9 - dy*3;
        laneoff[ks] = dz*1728 + dy*432 + (col + dx)*24 + ((l>>4)&1)*8;
    }
    int Mbase[4];
    #pragma unroll
    for (int mt = 0; mt < 4; ++mt)
        Mbase[mt] = (2*w + (mt>>1))*1728 + (mt&1)*432;

    f32x4 acc[4][COT];
    #pragma unroll
    for (int mt = 0; mt < 4; ++mt)
        #pragma unroll
        for (int ct = 0; ct < COT; ++ct)
            acc[mt][ct] = (f32x4){0.f,0.f,0.f,0.f};

    for (int h = 0; h < CIHALVES; ++h) {
        __syncthreads();
        for (int i = tid; i < 1440; i += 256) {
            int vec = i >> 1, hi8 = (i & 1) << 3;
            int z = vec/72, r = vec - z*72, y = r/18, x = r - y*18;
            int gz = zb*8 - 1 + z, gy = yb*2 - 1 + y, gx = xb*16 - 1 + x;
            ushort8v val = {0,0,0,0,0,0,0,0};
            if ((unsigned)gz < (unsigned)D && (unsigned)gy < (unsigned)D && (unsigned)gx < (unsigned)D) {
                size_t gi = (((size_t)n*D*D*D) + ((size_t)gz*D + gy)*D + gx)*CIN + h*16 + hi8;
                val = *(const ushort8v*)(Xcl + gi);
            }
            *(ushort8v*)(Ast + (vec)*24 + hi8) = val;
        }
        for (int i = tid; i < COT*896; i += 256)
            *(ushort8v*)(Bfr + i*8) = *(const ushort8v*)(WfragG + (size_t)h*COT*7168 + i*8);
        __syncthreads();

        #pragma unroll
        for (int ks = 0; ks < 14; ++ks) {
            short8v a[4];
            #pragma unroll
            for (int mt = 0; mt < 4; ++mt)
                a[mt] = *(const short8v*)(Ast + Mbase[mt] + laneoff[ks]);
            short8v bb[COT];
            #pragma unroll
            for (int ct = 0; ct < COT; ++ct)
                bb[ct] = *(const short8v*)(Bfr + ct*7168 + ks*512 + kg*128 + col*8);
            #pragma unroll
            for (int mt = 0; mt < 4; ++mt)
                #pragma unroll
                for (int ct = 0; ct < COT; ++ct)
                    acc[mt][ct] = __builtin_amdgcn_mfma_f32_16x16x32_bf16(a[mt], bb[ct], acc[mt][ct], 0, 0, 0);
        }
    }

    int zp = zb*4 + w, yp = yb;
    #pragma unroll
    for (int ct = 0; ct < COT; ++ct) {
        float bl = bias[ct*16 + col];
        float s = 0.f, q = 0.f;
        float mx0 = -1e30f, mx1 = -1e30f, mn0 = 1e30f, mn1 = 1e30f;
        #pragma unroll
        for (int mt = 0; mt < 4; ++mt) {
            #pragma unroll
            for (int j = 0; j < 4; ++j) {
                float v = acc[mt][ct][j] + bl;
                s += v; q = fmaf(v, v, q);
                if (j < 2) { mx0 = fmaxf(mx0, v); mn0 = fminf(mn0, v); }
                else       { mx1 = fmaxf(mx1, v); mn1 = fminf(mn1, v); }
            }
        }
        s += __shfl_xor(s, 16); s += __shfl_xor(s, 32);
        q += __shfl_xor(q, 16); q += __shfl_xor(q, 32);
        if (kg == 0) {
            red[((w*COT + ct)*16 + col)*2]     = s;
            red[((w*COT + ct)*16 + col)*2 + 1] = q;
        }
        size_t ob = (((size_t)((n*PD + zp)*PD + yp))*PD + xb*8 + kg*2)*COUT + ct*16 + col;
        outmax[ob]        = f2b(mx0);
        outmin[ob]        = f2b(mn0);
        outmax[ob + COUT] = f2b(mx1);
        outmin[ob + COUT] = f2b(mn1);
    }
    __syncthreads();
    if (tid < COT*32) {
        float t = red[tid] + red[COT*32 + tid] + red[2*COT*32 + tid] + red[3*COT*32 + tid];
        unsafeAtomicAdd(&stats_part[(bx & pmask)*(COT*32) + tid], t);
    }
}

// channels-last bf16 pooled max/min -> BN+ReLU -> bf16
__global__ __launch_bounds__(256) void bn_select_cl23_k(
    const ushort* __restrict__ mx, const ushort* __restrict__ mn,
    const float* __restrict__ sc, const float* __restrict__ sh,
    ushort* __restrict__ out, int cmask, int total)
{
    int idx = blockIdx.x*256 + threadIdx.x;
    if (idx >= total) return;
    int ci = idx & cmask;
    float s = sc[ci];
    float v = b2f((s >= 0.f) ? mx[idx] : mn[idx]);
    out[idx] = f2b(fmaxf(fmaf(v, s, sh[ci]), 0.f));
}

// fc: X channels-last bf16 [16][512][64]; W k-index = c*512 + sp
__global__ __launch_bounds__(128) void fc_acc_k(
    const ushort* __restrict__ X, const float* __restrict__ W, float* __restrict__ featv)
{
    int t = threadIdx.x;
    int k0 = blockIdx.x*256;
    float acc[16];
    #pragma unroll
    for (int b = 0; b < 16; ++b) acc[b] = 0.f;
    for (int k = k0; k < k0 + 256; ++k) {
        float w = W[(size_t)k*128 + t];
        int c = k >> 9, sp = k & 511;
        #pragma unroll
        for (int b = 0; b < 16; ++b)
            acc[b] = fmaf(b2f(X[(size_t)((b*512 + sp))*64 + c]), w, acc[b]);
    }
    for (int b = 0; b < 16; ++b) unsafeAtomicAdd(featv + b*512 + t, acc[b]);
}

// ---------------- dense head layers: K-parallel (4 kgroups x 64 cols), X in LDS ------
__global__ __launch_bounds__(256) void head2_k(
    const float* __restrict__ X, const float* __restrict__ W, const float* __restrict__ b,
    float* __restrict__ O, int K, int Ncol, int relu)
{
    __shared__ float Xs[512*16];      // transposed: [k][bi]
    __shared__ float red[3*16*64];
    int t = threadIdx.x;
    int kg = t >> 6, lane = t & 63;
    int c = blockIdx.x*64 + lane;
    bool valid = (c < Ncol);
    for (int i = t; i < 16*K; i += 256) {
        int bi = i & 15, k = i >> 4;
        Xs[k*16 + bi] = X[bi*K + k];
    }
    __syncthreads();
    float acc[16];
    #pragma unroll
    for (int bi = 0; bi < 16; ++bi) acc[bi] = 0.f;
    for (int k = kg; k < K; k += 4) {
        float w = valid ? W[(size_t)k*Ncol + c] : 0.f;
        const float* xp = Xs + k*16;
        float4 x0 = ld4(xp), x1 = ld4(xp+4), x2 = ld4(xp+8), x3 = ld4(xp+12);
        acc[0]  = fmaf(x0.x, w, acc[0]);  acc[1]  = fmaf(x0.y, w, acc[1]);
        acc[2]  = fmaf(x0.z, w, acc[2]);  acc[3]  = fmaf(x0.w, w, acc[3]);
        acc[4]  = fmaf(x1.x, w, acc[4]);  acc[5]  = fmaf(x1.y, w, acc[5]);
        acc[6]  = fmaf(x1.z, w, acc[6]);  acc[7]  = fmaf(x1.w, w, acc[7]);
        acc[8]  = fmaf(x2.x, w, acc[8]);  acc[9]  = fmaf(x2.y, w, acc[9]);
        acc[10] = fmaf(x2.z, w, acc[10]); acc[11] = fmaf(x2.w, w, acc[11]);
        acc[12] = fmaf(x3.x, w, acc[12]); acc[13] = fmaf(x3.y, w, acc[13]);
        acc[14] = fmaf(x3.z, w, acc[14]); acc[15] = fmaf(x3.w, w, acc[15]);
    }
    if (kg) {
        #pragma unroll
        for (int bi = 0; bi < 16; ++bi) red[((kg-1)*16 + bi)*64 + lane] = acc[bi];
    }
    __syncthreads();
    if (kg == 0 && valid) {
        float bias = b[c];
        #pragma unroll
        for (int bi = 0; bi < 16; ++bi) {
            float v = acc[bi] + red[bi*64 + lane] + red[(16 + bi)*64 + lane]
                    + red[(32 + bi)*64 + lane] + bias;
            if (relu) v = fmaxf(v, 0.f);
            O[bi*Ncol + c] = v;
        }
    }
}

__global__ void gebn_k(const float* __restrict__ g2, const float* __restrict__ g,
                       const float* __restrict__ b, float* __restrict__ featg)
{
    int c = threadIdx.x;
    float m = 0.f;
    for (int i = 0; i < 16; ++i) m += g2[i*128 + c];
    m *= (1.f/16.f);
    float v = 0.f;
    for (int i = 0; i < 16; ++i) { float d = g2[i*128 + c] - m; v += d*d; }
    v *= (1.f/16.f);
    float s = g[c] * rsqrtf(v + 1e-5f);
    for (int i = 0; i < 16; ++i)
        featg[i*512 + c] = fmaxf((g2[i*128 + c] - m)*s + b[c], 0.f);
}

__global__ void finalize_feat_k(float* __restrict__ feat, const float* __restrict__ cntm,
                                const float* __restrict__ cntz, const float* __restrict__ fcb)
{
    int t = blockIdx.x*256 + threadIdx.x;
    if (t >= 8192) return;
    int bi = t >> 9, c = t & 511;
    float v = feat[t];
    if      (c < 128) v /= fmaxf(cntm[bi], 1.f);
    else if (c < 256) v /= fmaxf(cntz[bi], 1.f);
    else if (c >= 384) v = fmaxf(v + fcb[c - 384], 0.f);
    feat[t] = v;
}

// =====================================================================================
extern "C" void kernel_launch(void* const* d_in, const int* in_sizes, int n_in,
                              void* d_out, int out_size, void* d_ws, size_t ws_size,
                              hipStream_t stream)
{
    const int*   mol_x  = (const int*)  d_in[0];
    const float* mol_q  = (const float*)d_in[1];
    const int*   mol_ei = (const int*)  d_in[2];
    const float* mol_ew = (const float*)d_in[3];
    const int*   mol_bv = (const int*)  d_in[4];
    const int*   zeo_x  = (const int*)  d_in[5];
    const int*   zeo_ei = (const int*)  d_in[6];
    const int*   zeo_bv = (const int*)  d_in[7];
    const float* voxel  = (const float*)d_in[8];
    const float* gattr  = (const float*)d_in[9];
    const float* ea  = (const float*)d_in[10];
    const float* ed  = (const float*)d_in[11];
    const float* ec  = (const float*)d_in[12];
    const float* eh  = (const float*)d_in[13];
    const float* ear = (const float*)d_in[14];
    const float* ech = (const float*)d_in[15];
    const float* mc1w=(const float*)d_in[16]; const float* mc1b=(const float*)d_in[17];
    const float* mc2w=(const float*)d_in[18]; const float* mc2b=(const float*)d_in[19];
    const float* zc1w=(const float*)d_in[20]; const float* zc1b=(const float*)d_in[21];
    const float* zc2w=(const float*)d_in[22]; const float* zc2b=(const float*)d_in[23];
    const float* cv1w=(const float*)d_in[24]; const float* cv1b=(const float*)d_in[25];
    const float* bn1g=(const float*)d_in[26]; const float* bn1b=(const float*)d_in[27];
    const float* cv2w=(const float*)d_in[28]; const float* cv2b=(const float*)d_in[29];
    const float* bn2g=(const float*)d_in[30]; const float* bn2b=(const float*)d_in[31];
    const float* cv3w=(const float*)d_in[32]; const float* cv3b=(const float*)d_in[33];
    const float* bn3g=(const float*)d_in[34]; const float* bn3b=(const float*)d_in[35];
    const float* fcw =(const float*)d_in[36]; const float* fcb =(const float*)d_in[37];
    const float* ge1w=(const float*)d_in[38]; const float* ge1b=(const float*)d_in[39];
    const float* ge2w=(const float*)d_in[40]; const float* ge2b=(const float*)d_in[41];
    const float* gbng=(const float*)d_in[42]; const float* gbnb=(const float*)d_in[43];
    const float* h1w =(const float*)d_in[44]; const float* h1b =(const float*)d_in[45];
    const float* h2w =(const float*)d_in[46]; const float* h2b =(const float*)d_in[47];
    const float* h3w =(const float*)d_in[48]; const float* h3b =(const float*)d_in[49];

    const int Nm = in_sizes[0]/6, Em = in_sizes[2]/2;
    const int Nz = in_sizes[5]/6, Ez = in_sizes[6]/2;
    const int NBm = (Nm + 1023)/1024, NBz = (Nz + 1023)/1024;

    float* WS = (float*)d_ws;
    float* A  = WS;
    float* Bb = WS + 16777216;
    float* S  = WS + 33554432;
    ushort* X0 = (ushort*)A;
    ushort* X1 = (ushort*)A + 16777216;
    ushort* X2 = (ushort*)Bb;
    ushort* X3 = (ushort*)Bb + 16777216;
    // conv-phase channels-last bf16 buffers (GNN buffers dead by then)
    ushort* Au   = (ushort*)A;
    ushort* pm1  = Au;                      // [16][32^3][16]
    ushort* pn1  = Au + 8388608;
    ushort* Xcl0 = Au + 16777216;           // [16][64^3][2]
    ushort* Xcl1 = (ushort*)Bb;             // [16][32^3][16]
    ushort* pm2  = Au;                      // [16][16^3][32]
    ushort* pn2  = Au + 2097152;
    ushort* Xcl2 = Au + 4194304;
    ushort* pm3  = (ushort*)Bb;             // [16][8^3][64]
    ushort* pn3  = (ushort*)Bb + 524288;
    ushort* Xcl3 = (ushort*)Bb + 1048576;
    float* deg  = S;
    float* dis  = S + 131072;
    float* csr_nrm = S + 262144;
    float* T    = S + 786432;
    float* cntm = S + 807040;
    float* cntz = S + 807056;
    float* feat = S + 807072;
    float* st1  = S + 815264; float* st2 = st1 + 32; float* st3 = st1 + 96;
    float* sc1  = S + 815488; float* sh1 = sc1 + 16;
    float* sc2  = sc1 + 32;   float* sh2 = sc1 + 64;
    float* sc3  = sc1 + 96;   float* sh3 = sc1 + 160;
    float* g1   = S + 815712;
    float* g2   = S + 816736;
    float* H1   = S + 818784;
    float* H2   = S + 826976;
    int* rowptr  = (int*)(S + 831072);          // 131073
    int* cursor  = (int*)(S + 962176);          // 131072
    int* csr_src = (int*)(S + 1093248);         // 524288 (ends S+1617536)
    ushort* wf2 = (ushort*)(S + 1617536);       // 14336 ush
    ushort* wf3 = (ushort*)(S + 1624704);       // 57344 ush
    int* bsum   = (int*)(S + 1653376);          // 256 ints
    ushort* wf1 = (ushort*)(S + 1653632);       // 2560 ush
    float* stp1 = S + 1655040;                  // 128*32
    float* stp2 = S + 1659136;                  // 32*64
    float* stp3 = S + 1661184;                  // 8*128 (ends S+1662208)

    hipMemsetAsync(S, 0, (size_t)831072*sizeof(float), stream);
    hipMemsetAsync(stp1, 0, (size_t)7168*sizeof(float), stream);

    // weight prepacks for MFMA convs
    wfrag1_k<<<10,256,0,stream>>>(cv1w, wf1);
    wfrag_k<<<56,256,0,stream>>>(cv2w, wf2, 16, 2, 14336);
    wfrag_k<<<224,256,0,stream>>>(cv3w, wf3, 32, 4, 57344);

    // ---------------- molecule branch ----------------
    build_tables_k<<<161,128,0,stream>>>(ea,ed,ec,eh,ear,ech, mc1w, T);
    init_deg_k   <<<Nm/256,256,0,stream>>>(deg, Nm);
    deg_scatter_k<<<Em/256,256,0,stream>>>(mol_ei+Em, mol_ew, deg, Em);
    dis_k        <<<Nm/256,256,0,stream>>>(deg, dis, Nm);
    hipMemsetAsync(cursor, 0, (size_t)Nm*sizeof(int), stream);
    count_in_k   <<<Em/256,256,0,stream>>>(mol_ei+Em, cursor, Em);
    blocksum_k   <<<NBm,256,0,stream>>>(cursor, bsum, Nm);
    scan_bsum_k  <<<1,256,0,stream>>>(bsum, NBm);
    scan_apply_k <<<NBm,256,0,stream>>>(cursor, bsum, rowptr, Nm, Em);
    fill_csr_k   <<<Em/256,256,0,stream>>>(mol_ei, mol_ei+Em, mol_ew, dis, cursor, csr_src, csr_nrm, Em);
    embed_lookup_k<<<Nm/8,256,0,stream>>>(mol_x, mol_q, T, mc1w + 112*128, X0, Nm);
    gcn_gather_k <<<Nm/8,256,0,stream>>>(X0, rowptr, csr_src, csr_nrm, dis, mc1b, X1, Nm);
    gemm_mfma_k  <<<Nm/64,256,0,stream>>>(X1, mc2w, X2, Nm);
    gcn_gather_k <<<Nm/8,256,0,stream>>>(X2, rowptr, csr_src, csr_nrm, dis, mc2b, X3, Nm);
    count_batch_k<<<Nm/256,256,0,stream>>>(mol_bv, cntm, Nm);
    mean_pool_sum_k<<<2048,128,0,stream>>>(X3, mol_bv, feat + 0, (Nm+2047)/2048, Nm);

    // ---------------- zeolite branch ----------------
    build_tables_k<<<161,128,0,stream>>>(ea,ed,ec,eh,ear,ech, zc1w, T);
    init_deg_k   <<<Nz/256,256,0,stream>>>(deg, Nz);
    deg_scatter_k<<<Ez/256,256,0,stream>>>(zeo_ei+Ez, nullptr, deg, Ez);
    dis_k        <<<Nz/256,256,0,stream>>>(deg, dis, Nz);
    hipMemsetAsync(cursor, 0, (size_t)Nz*sizeof(int), stream);
    count_in_k   <<<Ez/256,256,0,stream>>>(zeo_ei+Ez, cursor, Ez);
    blocksum_k   <<<NBz,256,0,stream>>>(cursor, bsum, Nz);
    scan_bsum_k  <<<1,256,0,stream>>>(bsum, NBz);
    scan_apply_k <<<NBz,256,0,stream>>>(cursor, bsum, rowptr, Nz, Ez);
    fill_csr_k   <<<Ez/256,256,0,stream>>>(zeo_ei, zeo_ei+Ez, nullptr, dis, cursor, csr_src, csr_nrm, Ez);
    embed_lookup_k<<<Nz/8,256,0,stream>>>(zeo_x, nullptr, T, nullptr, X0, Nz);
    gcn_gather_k <<<Nz/8,256,0,stream>>>(X0, rowptr, csr_src, csr_nrm, dis, zc1b, X1, Nz);
    gemm_mfma_k  <<<Nz/64,256,0,stream>>>(X1, zc2w, X2, Nz);
    gcn_gather_k <<<Nz/8,256,0,stream>>>(X2, rowptr, csr_src, csr_nrm, dis, zc2b, X3, Nz);
    count_batch_k<<<Nz/256,256,0,stream>>>(zeo_bv, cntz, Nz);
    mean_pool_sum_k<<<2048,128,0,stream>>>(X3, zeo_bv, feat + 128, (Nz+2047)/2048, Nz);

    // ---------------- voxel CNN (all layers MFMA implicit-GEMM) ----------------
    cvt_cl0_k<<<16384,256,0,stream>>>(voxel, (unsigned*)Xcl0);
    conv1_mfma_k<<<dim3(1024,16),256,0,stream>>>(Xcl0, wf1, cv1b, pm1, pn1, stp1);
    stats_reduce_k<<<1,64,0,stream>>>(stp1, st1, 128, 32);
    bn_final_k<<<1,64,0,stream>>>(st1, bn1g, bn1b, sc1, sh1, 16, 1.f/(16.f*262144.f));
    bn_select_cl23_k<<<32768,256,0,stream>>>(pm1, pn1, sc1, sh1, Xcl1, 15, 8388608);

    conv_mfma_k<1,2,32,16,32><<<dim3(128,16),256,0,stream>>>(Xcl1, wf2, cv2b, pm2, pn2, stp2, 31);
    stats_reduce_k<<<1,64,0,stream>>>(stp2, st2, 32, 64);
    bn_final_k<<<1,64,0,stream>>>(st2, bn2g, bn2b, sc2, sh2, 32, 1.f/(16.f*32768.f));
    bn_select_cl23_k<<<8192,256,0,stream>>>(pm2, pn2, sc2, sh2, Xcl2, 31, 2097152);

    conv_mfma_k<2,4,16,32,64><<<dim3(16,16),256,0,stream>>>(Xcl2, wf3, cv3b, pm3, pn3, stp3, 7);
    stats_reduce_k<<<2,64,0,stream>>>(stp3, st3, 8, 128);
    bn_final_k<<<1,64,0,stream>>>(st3, bn3g, bn3b, sc3, sh3, 64, 1.f/(16.f*4096.f));
    bn_select_cl23_k<<<2048,256,0,stream>>>(pm3, pn3, sc3, sh3, Xcl3, 63, 524288);

    fc_acc_k<<<128,128,0,stream>>>(Xcl3, fcw, feat + 384);

    // ---------------- global encoder ----------------
    head2_k<<<1,256,0,stream>>>(gattr, ge1w, ge1b, g1, 17, 64, 1);
    head2_k<<<2,256,0,stream>>>(g1, ge2w, ge2b, g2, 64, 128, 0);
    gebn_k<<<1,128,0,stream>>>(g2, gbng, gbnb, feat + 256);

    // ---------------- fusion head ----------------
    finalize_feat_k<<<32,256,0,stream>>>(feat, cntm, cntz, fcb);
    head2_k<<<8,256,0,stream>>>(feat, h1w, h1b, H1, 512, 512, 1);
    head2_k<<<4,256,0,stream>>>(H1, h2w, h2b, H2, 512, 256, 1);
    head2_k<<<1,256,0,stream>>>(H2, h3w, h3b, (float*)d_out, 256, 3, 0);
}

// Round 16
// 851.002 us; speedup vs baseline: 1.8037x; 1.0842x over previous
//
#include <hip/hip_runtime.h>
#include <math.h>

#define DEV static __device__ __forceinline__

DEV float4 ld4(const float* p){ return *(const float4*)p; }
DEV float2 ld2(const float* p){ return *(const float2*)p; }
DEV void   st4(float* p, float4 v){ *(float4*)p = v; }
DEV float4 f4add(float4 a, float4 b){ return make_float4(a.x+b.x,a.y+b.y,a.z+b.z,a.w+b.w); }
DEV float4 f4fma(float s, float4 a, float4 c){ return make_float4(fmaf(s,a.x,c.x),fmaf(s,a.y,c.y),fmaf(s,a.z,c.z),fmaf(s,a.w,c.w)); }

// bf16 helpers (RNE pack, exact unpack)
DEV float  b2f(ushort u){ return __uint_as_float(((unsigned)u) << 16); }
DEV ushort f2b(float f){
    unsigned u = __float_as_uint(f);
    return (ushort)((u + 0x7FFFu + ((u >> 16) & 1u)) >> 16);
}
DEV float4 b2f4(ushort4 v){ return make_float4(b2f(v.x), b2f(v.y), b2f(v.z), b2f(v.w)); }
DEV ushort4 f2b4(float4 v){ ushort4 o; o.x=f2b(v.x); o.y=f2b(v.y); o.z=f2b(v.z); o.w=f2b(v.w); return o; }

typedef __attribute__((ext_vector_type(8))) short short8v;            // 8 bf16 = 4 VGPR
typedef __attribute__((ext_vector_type(8))) unsigned short ushort8v;
typedef __attribute__((ext_vector_type(4))) float f32x4;

DEV short8v ld_a8(const ushort* p){   // 8B-aligned 16B LDS read as 2x b64
    ushort4 a = *(const ushort4*)p;
    ushort4 b = *(const ushort4*)(p+4);
    short8v r;
    r[0]=a.x; r[1]=a.y; r[2]=a.z; r[3]=a.w;
    r[4]=b.x; r[5]=b.y; r[6]=b.z; r[7]=b.w;
    return r;
}

// ---------------- GNN: embedding tables  T[161][128] = emb_f @ W_slice ----------------
__global__ __launch_bounds__(128) void build_tables_k(
    const float* __restrict__ ea, const float* __restrict__ ed, const float* __restrict__ ec,
    const float* __restrict__ eh, const float* __restrict__ ear, const float* __restrict__ ech,
    const float* __restrict__ Wm, float* __restrict__ T)
{
    int r = blockIdx.x, c = threadIdx.x;
    const float* e; int dim, woff, rl;
    if      (r < 120) { e=ea;  dim=64; woff=0;   rl=r; }
    else if (r < 132) { e=ed;  dim=16; woff=64;  rl=r-120; }
    else if (r < 147) { e=ec;  dim=16; woff=80;  rl=r-132; }
    else if (r < 155) { e=eh;  dim=8;  woff=96;  rl=r-147; }
    else if (r < 157) { e=ear; dim=4;  woff=104; rl=r-155; }
    else              { e=ech; dim=4;  woff=108; rl=r-157; }
    float acc = 0.f;
    for (int k = 0; k < dim; ++k) acc += e[rl*dim + k] * Wm[(woff + k)*128 + c];
    T[r*128 + c] = acc;
}

__global__ __launch_bounds__(256) void embed_lookup_k(
    const int* __restrict__ xi, const float* __restrict__ charge,
    const float* __restrict__ T, const float* __restrict__ wq,
    ushort* __restrict__ H, int N)
{
    int t = threadIdx.x;
    int node = blockIdx.x*8 + (t >> 5);
    if (node >= N) return;
    int c = (t & 31)*4;
    const int* xp = xi + node*6;
    float4 acc = ld4(T + (       xp[0])*128 + c);
    acc = f4add(acc, ld4(T + (120+xp[1])*128 + c));
    acc = f4add(acc, ld4(T + (132+xp[2])*128 + c));
    acc = f4add(acc, ld4(T + (147+xp[3])*128 + c));
    acc = f4add(acc, ld4(T + (155+xp[4])*128 + c));
    acc = f4add(acc, ld4(T + (157+xp[5])*128 + c));
    if (charge) acc = f4fma(charge[node], ld4(wq + c), acc);
    *(ushort4*)(H + (size_t)node*128 + c) = f2b4(acc);
}

// ---------------- GCN degree / norm / CSR build ----------------
__global__ void init_deg_k(float* deg, int N){ int i = blockIdx.x*256+threadIdx.x; if (i<N) deg[i]=1.f; }

__global__ void deg_scatter_k(const int* __restrict__ col, const float* __restrict__ ew, float* deg, int E){
    int e = blockIdx.x*256+threadIdx.x; if (e>=E) return;
    unsafeAtomicAdd(deg + col[e], ew ? ew[e] : 1.f);
}

__global__ void dis_k(const float* __restrict__ deg, float* __restrict__ dis, int N){
    int i = blockIdx.x*256+threadIdx.x; if (i<N) dis[i] = 1.f/sqrtf(deg[i]);
}

__global__ void count_in_k(const int* __restrict__ col, int* __restrict__ cnt, int E){
    int e = blockIdx.x*256+threadIdx.x; if (e>=E) return;
    atomicAdd(&cnt[col[e]], 1);
}

// ---- multi-block exclusive scan (3 phases; 1024 elems / block) ----
__global__ __launch_bounds__(256) void blocksum_k(const int* __restrict__ cnt, int* __restrict__ bsum, int N){
    int b = blockIdx.x, t = threadIdx.x;
    int base = b*1024 + t*4;
    int s = 0;
    if (base + 3 < N) { int4 v = *(const int4*)(cnt + base); s = v.x + v.y + v.z + v.w; }
    else { for (int i = 0; i < 4; ++i) { int idx = base + i; if (idx < N) s += cnt[idx]; } }
    __shared__ int red[256];
    red[t] = s; __syncthreads();
    for (int off = 128; off; off >>= 1) { if (t < off) red[t] += red[t+off]; __syncthreads(); }
    if (!t) bsum[b] = red[0];
}

__global__ __launch_bounds__(256) void scan_bsum_k(int* __restrict__ bsum, int NB){
    int t = threadIdx.x;
    __shared__ int sh[256];
    sh[t] = (t < NB) ? bsum[t] : 0;
    __syncthreads();
    for (int off = 1; off < 256; off <<= 1) {
        int v = (t >= off) ? sh[t-off] : 0;
        __syncthreads();
        sh[t] += v;
        __syncthreads();
    }
    if (t < NB) bsum[t] = (t == 0) ? 0 : sh[t-1];
}

__global__ __launch_bounds__(256) void scan_apply_k(int* cur, const int* __restrict__ bsum,
                                                    int* __restrict__ rowptr, int N, int E){
    int b = blockIdx.x, t = threadIdx.x;
    int base = b*1024 + t*4;
    int c[4]; int s = 0;
    #pragma unroll
    for (int i = 0; i < 4; ++i) { int idx = base + i; c[i] = (idx < N) ? cur[idx] : 0; s += c[i]; }
    __shared__ int sh[256];
    sh[t] = s; __syncthreads();
    for (int off = 1; off < 256; off <<= 1) {
        int v = (t >= off) ? sh[t-off] : 0;
        __syncthreads();
        sh[t] += v;
        __syncthreads();
    }
    int run = bsum[b] + ((t == 0) ? 0 : sh[t-1]);
    #pragma unroll
    for (int i = 0; i < 4; ++i) {
        int idx = base + i;
        if (idx < N) { rowptr[idx] = run; cur[idx] = run; run += c[i]; }
    }
    if (b == 0 && t == 0) rowptr[N] = E;
}

__global__ void fill_csr_k(const int* __restrict__ row, const int* __restrict__ col,
                           const float* __restrict__ ew, const float* __restrict__ dis,
                           int* __restrict__ cursor, int* __restrict__ csr_src,
                           float* __restrict__ csr_nrm, int E)
{
    int e = blockIdx.x*256+threadIdx.x; if (e>=E) return;
    int r = row[e], c = col[e];
    int pos = atomicAdd(&cursor[c], 1);
    csr_src[pos] = r;
    csr_nrm[pos] = dis[r] * (ew ? ew[e] : 1.f) * dis[c];
}

// O[i] = bias + dis[i]^2 * H[i] + sum_j nrm_j * H[src_j]   -- bf16 in/out, fp32 math
__global__ __launch_bounds__(256) void gcn_gather_k(
    const ushort* __restrict__ H, const int* __restrict__ rowptr,
    const int* __restrict__ csr_src, const float* __restrict__ csr_nrm,
    const float* __restrict__ dis, const float* __restrict__ bias,
    ushort* __restrict__ O, int N)
{
    int node = blockIdx.x*8 + (threadIdx.x >> 5);
    if (node >= N) return;
    int lane = (threadIdx.x & 31)*4;
    float s = dis[node]; s *= s;
    float4 h = b2f4(*(const ushort4*)(H + (size_t)node*128 + lane));
    float4 b = ld4(bias + lane);
    float4 acc = f4fma(s, h, b);
    int j = rowptr[node], end = rowptr[node+1];
    for (; j + 4 <= end; j += 4) {
        int   s0 = csr_src[j],   s1 = csr_src[j+1], s2 = csr_src[j+2], s3 = csr_src[j+3];
        float n0 = csr_nrm[j],   n1 = csr_nrm[j+1], n2 = csr_nrm[j+2], n3 = csr_nrm[j+3];
        float4 h0 = b2f4(*(const ushort4*)(H + (size_t)s0*128 + lane));
        float4 h1 = b2f4(*(const ushort4*)(H + (size_t)s1*128 + lane));
        float4 h2 = b2f4(*(const ushort4*)(H + (size_t)s2*128 + lane));
        float4 h3 = b2f4(*(const ushort4*)(H + (size_t)s3*128 + lane));
        acc = f4fma(n0, h0, acc);
        acc = f4fma(n1, h1, acc);
        acc = f4fma(n2, h2, acc);
        acc = f4fma(n3, h3, acc);
    }
    for (; j < end; ++j) {
        float4 h0 = b2f4(*(const ushort4*)(H + (size_t)csr_src[j]*128 + lane));
        acc = f4fma(csr_nrm[j], h0, acc);
    }
    *(ushort4*)(O + (size_t)node*128 + lane) = f2b4(acc);
}

// O = relu(A) @ W via bf16 MFMA; A:[N,128] bf16, W:[128,128] f32, O bf16
__global__ __launch_bounds__(256) void gemm_mfma_k(
    const ushort* __restrict__ A, const float* __restrict__ W,
    ushort* __restrict__ O, int N)
{
    __shared__ ushort WsF[16384];
    __shared__ ushort As[64*136];
    int t = threadIdx.x;
    for (int i = t; i < 16384; i += 256) {
        int j = i & 7, col = (i >> 3) & 15, kg = (i >> 7) & 3, ks = (i >> 9) & 3, ct = i >> 11;
        WsF[i] = f2b(W[(ks*32 + kg*8 + j)*128 + ct*16 + col]);
    }
    int row0 = blockIdx.x*64;
    for (int i = t; i < 64*32; i += 256) {
        int r = i >> 5, c4 = (i & 31)*4;
        ushort4 v = *(const ushort4*)(A + (size_t)(row0 + r)*128 + c4);
        v.x = (v.x & 0x8000) ? 0 : v.x;
        v.y = (v.y & 0x8000) ? 0 : v.y;
        v.z = (v.z & 0x8000) ? 0 : v.z;
        v.w = (v.w & 0x8000) ? 0 : v.w;
        *(ushort4*)(As + r*136 + c4) = v;
    }
    __syncthreads();
    int w = t >> 6, l = t & 63;
    int m16 = l & 15, kg = l >> 4;
    short8v af[4];
    #pragma unroll
    for (int ks = 0; ks < 4; ++ks)
        af[ks] = *(const short8v*)(As + (w*16 + m16)*136 + ks*32 + kg*8);
    #pragma unroll
    for (int ct = 0; ct < 8; ++ct) {
        f32x4 acc = {0.f, 0.f, 0.f, 0.f};
        #pragma unroll
        for (int ks = 0; ks < 4; ++ks) {
            short8v bf = *(const short8v*)(WsF + ((ct*4 + ks)*4 + kg)*128 + m16*8);
            acc = __builtin_amdgcn_mfma_f32_16x16x32_bf16(af[ks], bf, acc, 0, 0, 0);
        }
        int col = ct*16 + m16;
        int rbase = row0 + w*16 + kg*4;
        #pragma unroll
        for (int j = 0; j < 4; ++j)
            O[(size_t)(rbase + j)*128 + col] = f2b(acc[j]);
    }
}

// ---------------- mean pool (bf16 input): 4-way pipelined, LDS-direct accumulation ----
__global__ __launch_bounds__(128) void mean_pool_sum_k(
    const ushort* __restrict__ X, const int* __restrict__ bv,
    float* __restrict__ featp, int chunk, int N)
{
    __shared__ float acc[16*128];
    int t = threadIdx.x;
    #pragma unroll
    for (int b = 0; b < 16; ++b) acc[b*128 + t] = 0.f;
    int i0 = blockIdx.x * chunk;
    int iend = min(i0 + chunk, N);
    int i = i0;
    for (; i + 4 <= iend; i += 4) {
        int b0 = bv[i], b1 = bv[i+1], b2 = bv[i+2], b3 = bv[i+3];
        float v0 = fmaxf(b2f(X[(size_t)i*128 + t]),     0.f);
        float v1 = fmaxf(b2f(X[(size_t)(i+1)*128 + t]), 0.f);
        float v2 = fmaxf(b2f(X[(size_t)(i+2)*128 + t]), 0.f);
        float v3 = fmaxf(b2f(X[(size_t)(i+3)*128 + t]), 0.f);
        acc[b0*128 + t] += v0;
        acc[b1*128 + t] += v1;
        acc[b2*128 + t] += v2;
        acc[b3*128 + t] += v3;
    }
    for (; i < iend; ++i) {
        int b = bv[i];
        acc[b*128 + t] += fmaxf(b2f(X[(size_t)i*128 + t]), 0.f);
    }
    #pragma unroll
    for (int b = 0; b < 16; ++b) {
        float v = acc[b*128 + t];
        if (v != 0.f) unsafeAtomicAdd(featp + b*512 + t, v);
    }
}

__global__ void count_batch_k(const int* __restrict__ bv, float* __restrict__ cnt, int N){
    __shared__ int h[16];
    int t = threadIdx.x;
    if (t < 16) h[t] = 0;
    __syncthreads();
    int i = blockIdx.x*256 + t;
    if (i < N) atomicAdd(&h[bv[i]], 1);
    __syncthreads();
    if (t < 16 && h[t]) unsafeAtomicAdd(&cnt[t], (float)h[t]);
}

// ---------------- voxel fp32 NCDHW -> bf16 channels-last [n][64^3][2] ----------------
__global__ __launch_bounds__(256) void cvt_cl0_k(const float* __restrict__ vox, unsigned* __restrict__ out){
    int idx = blockIdx.x*256 + threadIdx.x;       // 16 * 262144
    int n = idx >> 18, v = idx & 262143;
    float a = vox[((size_t)n*2    )*262144 + v];
    float b = vox[((size_t)n*2 + 1)*262144 + v];
    out[idx] = (unsigned)f2b(a) | ((unsigned)f2b(b) << 16);
}

// conv1 weight prepack: k = rowIdx*16 + dx*4 + ci (ci padded 2->4, rows padded 9->10)
__global__ void wfrag1_k(const float* __restrict__ wt, ushort* __restrict__ out){
    int i = blockIdx.x*256 + threadIdx.x;
    if (i >= 2560) return;
    int j = i & 7, col = (i >> 3) & 15, kg = (i >> 7) & 3, ks = i >> 9;
    int rowIdx = ks*2 + (kg >> 1);
    int dx = (kg & 1)*2 + (j >> 2), ci = j & 3;
    ushort v = 0;
    if (rowIdx < 9 && dx < 3 && ci < 2)
        v = f2b(wt[(col*2 + ci)*27 + (rowIdx/3)*9 + (rowIdx%3)*3 + dx]);
    out[i] = v;
}

// conv1 implicit-GEMM MFMA: CL bf16 [n][64^3][2] -> pooled max/min CL [n][32^3][16]
__global__ __launch_bounds__(256) void conv1_mfma_k(
    const ushort* __restrict__ Xcl0, const ushort* __restrict__ wf,
    const float* __restrict__ bias,
    ushort* __restrict__ outmax, ushort* __restrict__ outmin, float* __restrict__ stats_part)
{
    __shared__ __align__(16) ushort Ast[2896];    // [10z][4y][18x][4ci-pad] (2880) + guard
    __shared__ __align__(16) ushort Bfr[2560];
    __shared__ float red[128];

    int tid = threadIdx.x;
    int n = blockIdx.y;
    int bx = blockIdx.x;
    int xb = bx & 3, yb = (bx >> 2) & 31, zb = bx >> 7;
    int w = tid >> 6, l = tid & 63;
    int col = l & 15, kg = l >> 4;

    for (int i = tid; i < 320; i += 256)
        *(ushort8v*)(Bfr + i*8) = *(const ushort8v*)(wf + i*8);
    for (int i = tid; i < 720; i += 256) {
        int z = i/72, r = i - z*72, y = r/18, x = r - y*18;
        int gz = zb*8 - 1 + z, gy = yb*2 - 1 + y, gx = xb*16 - 1 + x;
        unsigned packed = 0;
        if ((unsigned)gz < 64u && (unsigned)gy < 64u && (unsigned)gx < 64u)
            packed = *(const unsigned*)(Xcl0 + ((((size_t)n << 18) + ((gz*64 + gy)*64 + gx)) << 1));
        *(uint2*)(Ast + i*4) = make_uint2(packed, 0u);
    }
    if (tid < 2) *(uint2*)(Ast + 2880 + tid*4) = make_uint2(0u, 0u);
    __syncthreads();

    int halfoff = (kg & 1)*2;
    f32x4 acc[4];
    #pragma unroll
    for (int mt = 0; mt < 4; ++mt) acc[mt] = (f32x4){0.f,0.f,0.f,0.f};

    #pragma unroll
    for (int ks = 0; ks < 5; ++ks) {
        int rowIdx = ks*2 + (kg >> 1); if (rowIdx >= 9) rowIdx = 0;
        int kd = rowIdx/3, kh = rowIdx - kd*3;
        int off = kd*288 + kh*72 + (col + halfoff)*4;
        short8v bb = *(const short8v*)(Bfr + (ks*4 + kg)*128 + col*8);
        #pragma unroll
        for (int mt = 0; mt < 4; ++mt) {
            const ushort* p = Ast + (2*w + (mt>>1))*288 + (mt&1)*72 + off;
            short8v a = ld_a8(p);
            acc[mt] = __builtin_amdgcn_mfma_f32_16x16x32_bf16(a, bb, acc[mt], 0, 0, 0);
        }
    }

    int zp = zb*4 + w, yp = yb;
    float bl = bias[col];
    float s = 0.f, q = 0.f;
    float mx0=-1e30f, mx1=-1e30f, mn0=1e30f, mn1=1e30f;
    #pragma unroll
    for (int mt = 0; mt < 4; ++mt)
        #pragma unroll
        for (int j = 0; j < 4; ++j) {
            float v = acc[mt][j] + bl;
            s += v; q = fmaf(v, v, q);
            if (j < 2) { mx0 = fmaxf(mx0, v); mn0 = fminf(mn0, v); }
            else       { mx1 = fmaxf(mx1, v); mn1 = fminf(mn1, v); }
        }
    s += __shfl_xor(s, 16); s += __shfl_xor(s, 32);
    q += __shfl_xor(q, 16); q += __shfl_xor(q, 32);
    if (kg == 0) { red[(w*16 + col)*2] = s; red[(w*16 + col)*2 + 1] = q; }
    size_t ob = ((((size_t)(n*32 + zp))*32 + yp)*32 + xb*8 + kg*2)*16 + col;
    outmax[ob]      = f2b(mx0); outmin[ob]      = f2b(mn0);
    outmax[ob + 16] = f2b(mx1); outmin[ob + 16] = f2b(mn1);
    __syncthreads();
    if (tid < 32) {
        float t = red[tid] + red[32 + tid] + red[64 + tid] + red[96 + tid];
        unsafeAtomicAdd(&stats_part[((bx & 127) << 5) + tid], t);
    }
}

// sum partial stats -> final stats
__global__ void stats_reduce_k(const float* __restrict__ part, float* __restrict__ out,
                               int npart, int n)
{
    int c = blockIdx.x*64 + threadIdx.x;
    if (c >= n) return;
    float s = 0.f;
    for (int p = 0; p < npart; ++p) s += part[p*n + c];
    out[c] = s;
}

__global__ void bn_final_k(const float* __restrict__ stats, const float* __restrict__ g,
                           const float* __restrict__ b, float* __restrict__ sc, float* __restrict__ sh,
                           int C, float invN)
{
    int c = threadIdx.x; if (c >= C) return;
    float m = stats[c*2] * invN;
    float v = stats[c*2+1] * invN - m*m;
    float s = g[c] * rsqrtf(v + 1e-5f);
    sc[c] = s; sh[c] = b[c] - m*s;
}

// prepack conv weights into MFMA B-fragment order (bf16), K padded to 448 per ci-half
__global__ void wfrag_k(const float* __restrict__ wt, ushort* __restrict__ out,
                        int CIN, int COT, int total)
{
    int i = blockIdx.x*256 + threadIdx.x;
    if (i >= total) return;
    int per_h = COT*7168;
    int h  = i / per_h;
    int r0 = i - h*per_h;
    int ct = r0 / 7168;
    int r  = r0 - ct*7168;
    int ks = r >> 9;
    int r2 = r & 511;
    int kg = r2 >> 7, col = (r2 >> 3) & 15, j = r2 & 7;
    int k = ks*32 + kg*8 + j;
    int nbr = k >> 4, ci = (k & 15) + h*16;
    out[i] = (nbr < 27) ? f2b(wt[((size_t)(ct*16 + col)*CIN + ci)*27 + nbr]) : (ushort)0;
}

// ---------------- implicit-GEMM MFMA conv + bias + BN-stats(partial) + max/min pool ----
template<int CIHALVES, int COT, int D, int CIN, int COUT>
__global__ __launch_bounds__(256) void conv_mfma_k(
    const ushort* __restrict__ Xcl, const ushort* __restrict__ WfragG,
    const float* __restrict__ bias,
    ushort* __restrict__ outmax, ushort* __restrict__ outmin,
    float* __restrict__ stats_part, int pmask)
{
    constexpr int PD = D/2;
    constexpr int XT = D/16, YT = D/2;
    __shared__ __align__(16) ushort Ast[17280];
    __shared__ __align__(16) ushort Bfr[COT*7168];
    __shared__ float red[4*COT*32];

    int tid = threadIdx.x;
    int n = blockIdx.y;
    int bx = blockIdx.x;
    int xb = bx % XT, yb = (bx/XT) % YT, zb = bx/(XT*YT);
    int w = tid >> 6, l = tid & 63;
    int col = l & 15, kg = l >> 4;

    int laneoff[14];
    #pragma unroll
    for (int ks = 0; ks < 14; ++ks) {
        int nbr = ks*2 + (l >> 5);
        if (nbr >= 27) nbr = 0;
        int dz = nbr/9, r9 = nbr - dz*9, dy = r9/3, dx = r9 - dy*3;
        laneoff[ks] = dz*1728 + dy*432 + (col + dx)*24 + ((l>>4)&1)*8;
    }
    int Mbase[4];
    #pragma unroll
    for (int mt = 0; mt < 4; ++mt)
        Mbase[mt] = (2*w + (mt>>1))*1728 + (mt&1)*432;

    f32x4 acc[4][COT];
    #pragma unroll
    for (int mt = 0; mt < 4; ++mt)
        #pragma unroll
        for (int ct = 0; ct < COT; ++ct)
            acc[mt][ct] = (f32x4){0.f,0.f,0.f,0.f};

    for (int h = 0; h < CIHALVES; ++h) {
        __syncthreads();
        for (int i = tid; i < 1440; i += 256) {
            int vec = i >> 1, hi8 = (i & 1) << 3;
            int z = vec/72, r = vec - z*72, y = r/18, x = r - y*18;
            int gz = zb*8 - 1 + z, gy = yb*2 - 1 + y, gx = xb*16 - 1 + x;
            ushort8v val = {0,0,0,0,0,0,0,0};
            if ((unsigned)gz < (unsigned)D && (unsigned)gy < (unsigned)D && (unsigned)gx < (unsigned)D) {
                size_t gi = (((size_t)n*D*D*D) + ((size_t)gz*D + gy)*D + gx)*CIN + h*16 + hi8;
                val = *(const ushort8v*)(Xcl + gi);
            }
            *(ushort8v*)(Ast + (vec)*24 + hi8) = val;
        }
        for (int i = tid; i < COT*896; i += 256)
            *(ushort8v*)(Bfr + i*8) = *(const ushort8v*)(WfragG + (size_t)h*COT*7168 + i*8);
        __syncthreads();

        #pragma unroll
        for (int ks = 0; ks < 14; ++ks) {
            short8v a[4];
            #pragma unroll
            for (int mt = 0; mt < 4; ++mt)
                a[mt] = *(const short8v*)(Ast + Mbase[mt] + laneoff[ks]);
            short8v bb[COT];
            #pragma unroll
            for (int ct = 0; ct < COT; ++ct)
                bb[ct] = *(const short8v*)(Bfr + ct*7168 + ks*512 + kg*128 + col*8);
            #pragma unroll
            for (int mt = 0; mt < 4; ++mt)
                #pragma unroll
                for (int ct = 0; ct < COT; ++ct)
                    acc[mt][ct] = __builtin_amdgcn_mfma_f32_16x16x32_bf16(a[mt], bb[ct], acc[mt][ct], 0, 0, 0);
        }
    }

    int zp = zb*4 + w, yp = yb;
    #pragma unroll
    for (int ct = 0; ct < COT; ++ct) {
        float bl = bias[ct*16 + col];
        float s = 0.f, q = 0.f;
        float mx0 = -1e30f, mx1 = -1e30f, mn0 = 1e30f, mn1 = 1e30f;
        #pragma unroll
        for (int mt = 0; mt < 4; ++mt) {
            #pragma unroll
            for (int j = 0; j < 4; ++j) {
                float v = acc[mt][ct][j] + bl;
                s += v; q = fmaf(v, v, q);
                if (j < 2) { mx0 = fmaxf(mx0, v); mn0 = fminf(mn0, v); }
                else       { mx1 = fmaxf(mx1, v); mn1 = fminf(mn1, v); }
            }
        }
        s += __shfl_xor(s, 16); s += __shfl_xor(s, 32);
        q += __shfl_xor(q, 16); q += __shfl_xor(q, 32);
        if (kg == 0) {
            red[((w*COT + ct)*16 + col)*2]     = s;
            red[((w*COT + ct)*16 + col)*2 + 1] = q;
        }
        size_t ob = (((size_t)((n*PD + zp)*PD + yp))*PD + xb*8 + kg*2)*COUT + ct*16 + col;
        outmax[ob]        = f2b(mx0);
        outmin[ob]        = f2b(mn0);
        outmax[ob + COUT] = f2b(mx1);
        outmin[ob + COUT] = f2b(mn1);
    }
    __syncthreads();
    if (tid < COT*32) {
        float t = red[tid] + red[COT*32 + tid] + red[2*COT*32 + tid] + red[3*COT*32 + tid];
        unsafeAtomicAdd(&stats_part[(bx & pmask)*(COT*32) + tid], t);
    }
}

// channels-last bf16 pooled max/min -> BN+ReLU -> bf16
__global__ __launch_bounds__(256) void bn_select_cl23_k(
    const ushort* __restrict__ mx, const ushort* __restrict__ mn,
    const float* __restrict__ sc, const float* __restrict__ sh,
    ushort* __restrict__ out, int cmask, int total)
{
    int idx = blockIdx.x*256 + threadIdx.x;
    if (idx >= total) return;
    int ci = idx & cmask;
    float s = sc[ci];
    float v = b2f((s >= 0.f) ? mx[idx] : mn[idx]);
    out[idx] = f2b(fmaxf(fmaf(v, s, sh[ci]), 0.f));
}

// fc: X channels-last bf16 [16][512][64] @ W[32768,128] -> 8 partial slices
// block: 64 consecutive k (one c0 channel); X tile staged in LDS; 512 blocks.
__global__ __launch_bounds__(128) void fc_acc2_k(
    const ushort* __restrict__ X, const float* __restrict__ W, float* __restrict__ part)
{
    __shared__ float Xs[16*64];
    int t = threadIdx.x;
    int bx = blockIdx.x;
    int k0 = bx*64;
    int c0 = k0 >> 9, sp0 = k0 & 511;
    for (int i = t; i < 1024; i += 128) {
        int b = i >> 6, spo = i & 63;
        Xs[b*64 + spo] = b2f(X[(size_t)(b*512 + sp0 + spo)*64 + c0]);
    }
    __syncthreads();
    float acc[16];
    #pragma unroll
    for (int b = 0; b < 16; ++b) acc[b] = 0.f;
    #pragma unroll 4
    for (int kk = 0; kk < 64; ++kk) {
        float w = W[(size_t)(k0 + kk)*128 + t];
        #pragma unroll
        for (int b = 0; b < 16; ++b) acc[b] = fmaf(Xs[b*64 + kk], w, acc[b]);
    }
    float* pp = part + (bx & 7)*2048;
    #pragma unroll
    for (int b = 0; b < 16; ++b) unsafeAtomicAdd(pp + b*128 + t, acc[b]);
}

// sum fc partials -> feat[:,384:512] (plain store; region otherwise untouched)
__global__ void fc_reduce_k(const float* __restrict__ part, float* __restrict__ feat)
{
    int i = blockIdx.x*256 + threadIdx.x;    // 2048
    if (i >= 2048) return;
    int b = i >> 7, t = i & 127;
    float s = 0.f;
    #pragma unroll
    for (int p = 0; p < 8; ++p) s += part[p*2048 + b*128 + t];
    feat[b*512 + 384 + t] = s;
}

// ---------------- dense head layers: K-parallel (4 kgroups x 64 cols), X in LDS ------
__global__ __launch_bounds__(256) void head2_k(
    const float* __restrict__ X, const float* __restrict__ W, const float* __restrict__ b,
    float* __restrict__ O, int K, int Ncol, int relu)
{
    __shared__ float Xs[512*16];      // transposed: [k][bi]
    __shared__ float red[3*16*64];
    int t = threadIdx.x;
    int kg = t >> 6, lane = t & 63;
    int c = blockIdx.x*64 + lane;
    bool valid = (c < Ncol);
    for (int i = t; i < 16*K; i += 256) {
        int bi = i & 15, k = i >> 4;
        Xs[k*16 + bi] = X[bi*K + k];
    }
    __syncthreads();
    float acc[16];
    #pragma unroll
    for (int bi = 0; bi < 16; ++bi) acc[bi] = 0.f;
    for (int k = kg; k < K; k += 4) {
        float w = valid ? W[(size_t)k*Ncol + c] : 0.f;
        const float* xp = Xs + k*16;
        float4 x0 = ld4(xp), x1 = ld4(xp+4), x2 = ld4(xp+8), x3 = ld4(xp+12);
        acc[0]  = fmaf(x0.x, w, acc[0]);  acc[1]  = fmaf(x0.y, w, acc[1]);
        acc[2]  = fmaf(x0.z, w, acc[2]);  acc[3]  = fmaf(x0.w, w, acc[3]);
        acc[4]  = fmaf(x1.x, w, acc[4]);  acc[5]  = fmaf(x1.y, w, acc[5]);
        acc[6]  = fmaf(x1.z, w, acc[6]);  acc[7]  = fmaf(x1.w, w, acc[7]);
        acc[8]  = fmaf(x2.x, w, acc[8]);  acc[9]  = fmaf(x2.y, w, acc[9]);
        acc[10] = fmaf(x2.z, w, acc[10]); acc[11] = fmaf(x2.w, w, acc[11]);
        acc[12] = fmaf(x3.x, w, acc[12]); acc[13] = fmaf(x3.y, w, acc[13]);
        acc[14] = fmaf(x3.z, w, acc[14]); acc[15] = fmaf(x3.w, w, acc[15]);
    }
    if (kg) {
        #pragma unroll
        for (int bi = 0; bi < 16; ++bi) red[((kg-1)*16 + bi)*64 + lane] = acc[bi];
    }
    __syncthreads();
    if (kg == 0 && valid) {
        float bias = b[c];
        #pragma unroll
        for (int bi = 0; bi < 16; ++bi) {
            float v = acc[bi] + red[bi*64 + lane] + red[(16 + bi)*64 + lane]
                    + red[(32 + bi)*64 + lane] + bias;
            if (relu) v = fmaxf(v, 0.f);
            O[bi*Ncol + c] = v;
        }
    }
}

__global__ void gebn_k(const float* __restrict__ g2, const float* __restrict__ g,
                       const float* __restrict__ b, float* __restrict__ featg)
{
    int c = threadIdx.x;
    float m = 0.f;
    for (int i = 0; i < 16; ++i) m += g2[i*128 + c];
    m *= (1.f/16.f);
    float v = 0.f;
    for (int i = 0; i < 16; ++i) { float d = g2[i*128 + c] - m; v += d*d; }
    v *= (1.f/16.f);
    float s = g[c] * rsqrtf(v + 1e-5f);
    for (int i = 0; i < 16; ++i)
        featg[i*512 + c] = fmaxf((g2[i*128 + c] - m)*s + b[c], 0.f);
}

__global__ void finalize_feat_k(float* __restrict__ feat, const float* __restrict__ cntm,
                                const float* __restrict__ cntz, const float* __restrict__ fcb)
{
    int t = blockIdx.x*256 + threadIdx.x;
    if (t >= 8192) return;
    int bi = t >> 9, c = t & 511;
    float v = feat[t];
    if      (c < 128) v /= fmaxf(cntm[bi], 1.f);
    else if (c < 256) v /= fmaxf(cntz[bi], 1.f);
    else if (c >= 384) v = fmaxf(v + fcb[c - 384], 0.f);
    feat[t] = v;
}

// =====================================================================================
extern "C" void kernel_launch(void* const* d_in, const int* in_sizes, int n_in,
                              void* d_out, int out_size, void* d_ws, size_t ws_size,
                              hipStream_t stream)
{
    const int*   mol_x  = (const int*)  d_in[0];
    const float* mol_q  = (const float*)d_in[1];
    const int*   mol_ei = (const int*)  d_in[2];
    const float* mol_ew = (const float*)d_in[3];
    const int*   mol_bv = (const int*)  d_in[4];
    const int*   zeo_x  = (const int*)  d_in[5];
    const int*   zeo_ei = (const int*)  d_in[6];
    const int*   zeo_bv = (const int*)  d_in[7];
    const float* voxel  = (const float*)d_in[8];
    const float* gattr  = (const float*)d_in[9];
    const float* ea  = (const float*)d_in[10];
    const float* ed  = (const float*)d_in[11];
    const float* ec  = (const float*)d_in[12];
    const float* eh  = (const float*)d_in[13];
    const float* ear = (const float*)d_in[14];
    const float* ech = (const float*)d_in[15];
    const float* mc1w=(const float*)d_in[16]; const float* mc1b=(const float*)d_in[17];
    const float* mc2w=(const float*)d_in[18]; const float* mc2b=(const float*)d_in[19];
    const float* zc1w=(const float*)d_in[20]; const float* zc1b=(const float*)d_in[21];
    const float* zc2w=(const float*)d_in[22]; const float* zc2b=(const float*)d_in[23];
    const float* cv1w=(const float*)d_in[24]; const float* cv1b=(const float*)d_in[25];
    const float* bn1g=(const float*)d_in[26]; const float* bn1b=(const float*)d_in[27];
    const float* cv2w=(const float*)d_in[28]; const float* cv2b=(const float*)d_in[29];
    const float* bn2g=(const float*)d_in[30]; const float* bn2b=(const float*)d_in[31];
    const float* cv3w=(const float*)d_in[32]; const float* cv3b=(const float*)d_in[33];
    const float* bn3g=(const float*)d_in[34]; const float* bn3b=(const float*)d_in[35];
    const float* fcw =(const float*)d_in[36]; const float* fcb =(const float*)d_in[37];
    const float* ge1w=(const float*)d_in[38]; const float* ge1b=(const float*)d_in[39];
    const float* ge2w=(const float*)d_in[40]; const float* ge2b=(const float*)d_in[41];
    const float* gbng=(const float*)d_in[42]; const float* gbnb=(const float*)d_in[43];
    const float* h1w =(const float*)d_in[44]; const float* h1b =(const float*)d_in[45];
    const float* h2w =(const float*)d_in[46]; const float* h2b =(const float*)d_in[47];
    const float* h3w =(const float*)d_in[48]; const float* h3b =(const float*)d_in[49];

    const int Nm = in_sizes[0]/6, Em = in_sizes[2]/2;
    const int Nz = in_sizes[5]/6, Ez = in_sizes[6]/2;
    const int NBm = (Nm + 1023)/1024, NBz = (Nz + 1023)/1024;

    float* WS = (float*)d_ws;
    float* A  = WS;
    float* Bb = WS + 16777216;
    float* S  = WS + 33554432;
    ushort* X0 = (ushort*)A;
    ushort* X1 = (ushort*)A + 16777216;
    ushort* X2 = (ushort*)Bb;
    ushort* X3 = (ushort*)Bb + 16777216;
    // conv-phase channels-last bf16 buffers (GNN buffers dead by then)
    ushort* Au   = (ushort*)A;
    ushort* pm1  = Au;                      // [16][32^3][16]
    ushort* pn1  = Au + 8388608;
    ushort* Xcl0 = Au + 16777216;           // [16][64^3][2]
    ushort* Xcl1 = (ushort*)Bb;             // [16][32^3][16]
    ushort* pm2  = Au;                      // [16][16^3][32]
    ushort* pn2  = Au + 2097152;
    ushort* Xcl2 = Au + 4194304;
    ushort* pm3  = (ushort*)Bb;             // [16][8^3][64]
    ushort* pn3  = (ushort*)Bb + 524288;
    ushort* Xcl3 = (ushort*)Bb + 1048576;
    float* deg  = S;
    float* dis  = S + 131072;
    float* csr_nrm = S + 262144;
    float* T    = S + 786432;
    float* cntm = S + 807040;
    float* cntz = S + 807056;
    float* feat = S + 807072;
    float* st1  = S + 815264; float* st2 = st1 + 32; float* st3 = st1 + 96;
    float* sc1  = S + 815488; float* sh1 = sc1 + 16;
    float* sc2  = sc1 + 32;   float* sh2 = sc1 + 64;
    float* sc3  = sc1 + 96;   float* sh3 = sc1 + 160;
    float* g1   = S + 815712;
    float* g2   = S + 816736;
    float* H1   = S + 818784;
    float* H2   = S + 826976;
    int* rowptr  = (int*)(S + 831072);          // 131073
    int* cursor  = (int*)(S + 962176);          // 131072
    int* csr_src = (int*)(S + 1093248);         // 524288 (ends S+1617536)
    ushort* wf2 = (ushort*)(S + 1617536);       // 14336 ush
    ushort* wf3 = (ushort*)(S + 1624704);       // 57344 ush
    int* bsum   = (int*)(S + 1653376);          // 256 ints
    ushort* wf1 = (ushort*)(S + 1653632);       // 2560 ush
    float* stp1 = S + 1655040;                  // 128*32
    float* stp2 = S + 1659136;                  // 32*64
    float* stp3 = S + 1661184;                  // 8*128 (ends S+1662208)
    float* fcpart = S + 1662208;                // 8*2048 (ends S+1678592)

    hipMemsetAsync(S, 0, (size_t)831072*sizeof(float), stream);
    hipMemsetAsync(stp1, 0, (size_t)(7168 + 16384)*sizeof(float), stream);  // stp1..3 + fcpart

    // weight prepacks for MFMA convs
    wfrag1_k<<<10,256,0,stream>>>(cv1w, wf1);
    wfrag_k<<<56,256,0,stream>>>(cv2w, wf2, 16, 2, 14336);
    wfrag_k<<<224,256,0,stream>>>(cv3w, wf3, 32, 4, 57344);

    // ---------------- molecule branch ----------------
    build_tables_k<<<161,128,0,stream>>>(ea,ed,ec,eh,ear,ech, mc1w, T);
    init_deg_k   <<<Nm/256,256,0,stream>>>(deg, Nm);
    deg_scatter_k<<<Em/256,256,0,stream>>>(mol_ei+Em, mol_ew, deg, Em);
    dis_k        <<<Nm/256,256,0,stream>>>(deg, dis, Nm);
    hipMemsetAsync(cursor, 0, (size_t)Nm*sizeof(int), stream);
    count_in_k   <<<Em/256,256,0,stream>>>(mol_ei+Em, cursor, Em);
    blocksum_k   <<<NBm,256,0,stream>>>(cursor, bsum, Nm);
    scan_bsum_k  <<<1,256,0,stream>>>(bsum, NBm);
    scan_apply_k <<<NBm,256,0,stream>>>(cursor, bsum, rowptr, Nm, Em);
    fill_csr_k   <<<Em/256,256,0,stream>>>(mol_ei, mol_ei+Em, mol_ew, dis, cursor, csr_src, csr_nrm, Em);
    embed_lookup_k<<<Nm/8,256,0,stream>>>(mol_x, mol_q, T, mc1w + 112*128, X0, Nm);
    gcn_gather_k <<<Nm/8,256,0,stream>>>(X0, rowptr, csr_src, csr_nrm, dis, mc1b, X1, Nm);
    gemm_mfma_k  <<<Nm/64,256,0,stream>>>(X1, mc2w, X2, Nm);
    gcn_gather_k <<<Nm/8,256,0,stream>>>(X2, rowptr, csr_src, csr_nrm, dis, mc2b, X3, Nm);
    count_batch_k<<<Nm/256,256,0,stream>>>(mol_bv, cntm, Nm);
    mean_pool_sum_k<<<2048,128,0,stream>>>(X3, mol_bv, feat + 0, (Nm+2047)/2048, Nm);

    // ---------------- zeolite branch ----------------
    build_tables_k<<<161,128,0,stream>>>(ea,ed,ec,eh,ear,ech, zc1w, T);
    init_deg_k   <<<Nz/256,256,0,stream>>>(deg, Nz);
    deg_scatter_k<<<Ez/256,256,0,stream>>>(zeo_ei+Ez, nullptr, deg, Ez);
    dis_k        <<<Nz/256,256,0,stream>>>(deg, dis, Nz);
    hipMemsetAsync(cursor, 0, (size_t)Nz*sizeof(int), stream);
    count_in_k   <<<Ez/256,256,0,stream>>>(zeo_ei+Ez, cursor, Ez);
    blocksum_k   <<<NBz,256,0,stream>>>(cursor, bsum, Nz);
    scan_bsum_k  <<<1,256,0,stream>>>(bsum, NBz);
    scan_apply_k <<<NBz,256,0,stream>>>(cursor, bsum, rowptr, Nz, Ez);
    fill_csr_k   <<<Ez/256,256,0,stream>>>(zeo_ei, zeo_ei+Ez, nullptr, dis, cursor, csr_src, csr_nrm, Ez);
    embed_lookup_k<<<Nz/8,256,0,stream>>>(zeo_x, nullptr, T, nullptr, X0, Nz);
    gcn_gather_k <<<Nz/8,256,0,stream>>>(X0, rowptr, csr_src, csr_nrm, dis, zc1b, X1, Nz);
    gemm_mfma_k  <<<Nz/64,256,0,stream>>>(X1, zc2w, X2, Nz);
    gcn_gather_k <<<Nz/8,256,0,stream>>>(X2, rowptr, csr_src, csr_nrm, dis, zc2b, X3, Nz);
    count_batch_k<<<Nz/256,256,0,stream>>>(zeo_bv, cntz, Nz);
    mean_pool_sum_k<<<2048,128,0,stream>>>(X3, zeo_bv, feat + 128, (Nz+2047)/2048, Nz);

    // ---------------- voxel CNN (all layers MFMA implicit-GEMM) ----------------
    cvt_cl0_k<<<16384,256,0,stream>>>(voxel, (unsigned*)Xcl0);
    conv1_mfma_k<<<dim3(1024,16),256,0,stream>>>(Xcl0, wf1, cv1b, pm1, pn1, stp1);
    stats_reduce_k<<<1,64,0,stream>>>(stp1, st1, 128, 32);
    bn_final_k<<<1,64,0,stream>>>(st1, bn1g, bn1b, sc1, sh1, 16, 1.f/(16.f*262144.f));
    bn_select_cl23_k<<<32768,256,0,stream>>>(pm1, pn1, sc1, sh1, Xcl1, 15, 8388608);

    conv_mfma_k<1,2,32,16,32><<<dim3(128,16),256,0,stream>>>(Xcl1, wf2, cv2b, pm2, pn2, stp2, 31);
    stats_reduce_k<<<1,64,0,stream>>>(stp2, st2, 32, 64);
    bn_final_k<<<1,64,0,stream>>>(st2, bn2g, bn2b, sc2, sh2, 32, 1.f/(16.f*32768.f));
    bn_select_cl23_k<<<8192,256,0,stream>>>(pm2, pn2, sc2, sh2, Xcl2, 31, 2097152);

    conv_mfma_k<2,4,16,32,64><<<dim3(16,16),256,0,stream>>>(Xcl2, wf3, cv3b, pm3, pn3, stp3, 7);
    stats_reduce_k<<<2,64,0,stream>>>(stp3, st3, 8, 128);
    bn_final_k<<<1,64,0,stream>>>(st3, bn3g, bn3b, sc3, sh3, 64, 1.f/(16.f*4096.f));
    bn_select_cl23_k<<<2048,256,0,stream>>>(pm3, pn3, sc3, sh3, Xcl3, 63, 524288);

    fc_acc2_k<<<512,128,0,stream>>>(Xcl3, fcw, fcpart);
    fc_reduce_k<<<8,256,0,stream>>>(fcpart, feat);

    // ---------------- global encoder ----------------
    head2_k<<<1,256,0,stream>>>(gattr, ge1w, ge1b, g1, 17, 64, 1);
    head2_k<<<2,256,0,stream>>>(g1, ge2w, ge2b, g2, 64, 128, 0);
    gebn_k<<<1,128,0,stream>>>(g2, gbng, gbnb, feat + 256);

    // ---------------- fusion head ----------------
    finalize_feat_k<<<32,256,0,stream>>>(feat, cntm, cntz, fcb);
    head2_k<<<8,256,0,stream>>>(feat, h1w, h1b, H1, 512, 512, 1);
    head2_k<<<4,256,0,stream>>>(H1, h2w, h2b, H2, 512, 256, 1);
    head2_k<<<1,256,0,stream>>>(H2, h3w, h3b, (float*)d_out, 256, 3, 0);
}

// Round 17
// 803.139 us; speedup vs baseline: 1.9112x; 1.0596x over previous
//
#include <hip/hip_runtime.h>
#include <math.h>

#define DEV static __device__ __forceinline__

DEV float4 ld4(const float* p){ return *(const float4*)p; }
DEV float2 ld2(const float* p){ return *(const float2*)p; }
DEV void   st4(float* p, float4 v){ *(float4*)p = v; }
DEV float4 f4add(float4 a, float4 b){ return make_float4(a.x+b.x,a.y+b.y,a.z+b.z,a.w+b.w); }
DEV float4 f4fma(float s, float4 a, float4 c){ return make_float4(fmaf(s,a.x,c.x),fmaf(s,a.y,c.y),fmaf(s,a.z,c.z),fmaf(s,a.w,c.w)); }

// bf16 helpers (RNE pack, exact unpack)
DEV float  b2f(ushort u){ return __uint_as_float(((unsigned)u) << 16); }
DEV ushort f2b(float f){
    unsigned u = __float_as_uint(f);
    return (ushort)((u + 0x7FFFu + ((u >> 16) & 1u)) >> 16);
}
DEV float4 b2f4(ushort4 v){ return make_float4(b2f(v.x), b2f(v.y), b2f(v.z), b2f(v.w)); }
DEV ushort4 f2b4(float4 v){ ushort4 o; o.x=f2b(v.x); o.y=f2b(v.y); o.z=f2b(v.z); o.w=f2b(v.w); return o; }

typedef __attribute__((ext_vector_type(8))) short short8v;            // 8 bf16 = 4 VGPR
typedef __attribute__((ext_vector_type(8))) unsigned short ushort8v;
typedef __attribute__((ext_vector_type(4))) float f32x4;

DEV short8v ld_a8(const ushort* p){   // 8B-aligned 16B LDS read as 2x b64
    ushort4 a = *(const ushort4*)p;
    ushort4 b = *(const ushort4*)(p+4);
    short8v r;
    r[0]=a.x; r[1]=a.y; r[2]=a.z; r[3]=a.w;
    r[4]=b.x; r[5]=b.y; r[6]=b.z; r[7]=b.w;
    return r;
}

// ---------------- GNN: embedding tables  T[161][128] = emb_f @ W_slice ----------------
__global__ __launch_bounds__(128) void build_tables_k(
    const float* __restrict__ ea, const float* __restrict__ ed, const float* __restrict__ ec,
    const float* __restrict__ eh, const float* __restrict__ ear, const float* __restrict__ ech,
    const float* __restrict__ Wm, float* __restrict__ T)
{
    int r = blockIdx.x, c = threadIdx.x;
    const float* e; int dim, woff, rl;
    if      (r < 120) { e=ea;  dim=64; woff=0;   rl=r; }
    else if (r < 132) { e=ed;  dim=16; woff=64;  rl=r-120; }
    else if (r < 147) { e=ec;  dim=16; woff=80;  rl=r-132; }
    else if (r < 155) { e=eh;  dim=8;  woff=96;  rl=r-147; }
    else if (r < 157) { e=ear; dim=4;  woff=104; rl=r-155; }
    else              { e=ech; dim=4;  woff=108; rl=r-157; }
    float acc = 0.f;
    for (int k = 0; k < dim; ++k) acc += e[rl*dim + k] * Wm[(woff + k)*128 + c];
    T[r*128 + c] = acc;
}

__global__ __launch_bounds__(256) void embed_lookup_k(
    const int* __restrict__ xi, const float* __restrict__ charge,
    const float* __restrict__ T, const float* __restrict__ wq,
    ushort* __restrict__ H, int N)
{
    int t = threadIdx.x;
    int node = blockIdx.x*8 + (t >> 5);
    if (node >= N) return;
    int c = (t & 31)*4;
    const int* xp = xi + node*6;
    float4 acc = ld4(T + (       xp[0])*128 + c);
    acc = f4add(acc, ld4(T + (120+xp[1])*128 + c));
    acc = f4add(acc, ld4(T + (132+xp[2])*128 + c));
    acc = f4add(acc, ld4(T + (147+xp[3])*128 + c));
    acc = f4add(acc, ld4(T + (155+xp[4])*128 + c));
    acc = f4add(acc, ld4(T + (157+xp[5])*128 + c));
    if (charge) acc = f4fma(charge[node], ld4(wq + c), acc);
    *(ushort4*)(H + (size_t)node*128 + c) = f2b4(acc);
}

// ---------------- GCN degree / norm / CSR build ----------------
__global__ void init_deg_k(float* deg, int N){ int i = blockIdx.x*256+threadIdx.x; if (i<N) deg[i]=1.f; }

__global__ void deg_scatter_k(const int* __restrict__ col, const float* __restrict__ ew, float* deg, int E){
    int e = blockIdx.x*256+threadIdx.x; if (e>=E) return;
    unsafeAtomicAdd(deg + col[e], ew ? ew[e] : 1.f);
}

__global__ void dis_k(const float* __restrict__ deg, float* __restrict__ dis, int N){
    int i = blockIdx.x*256+threadIdx.x; if (i<N) dis[i] = 1.f/sqrtf(deg[i]);
}

__global__ void count_in_k(const int* __restrict__ col, int* __restrict__ cnt, int E){
    int e = blockIdx.x*256+threadIdx.x; if (e>=E) return;
    atomicAdd(&cnt[col[e]], 1);
}

// ---- multi-block exclusive scan (3 phases; 1024 elems / block) ----
__global__ __launch_bounds__(256) void blocksum_k(const int* __restrict__ cnt, int* __restrict__ bsum, int N){
    int b = blockIdx.x, t = threadIdx.x;
    int base = b*1024 + t*4;
    int s = 0;
    if (base + 3 < N) { int4 v = *(const int4*)(cnt + base); s = v.x + v.y + v.z + v.w; }
    else { for (int i = 0; i < 4; ++i) { int idx = base + i; if (idx < N) s += cnt[idx]; } }
    __shared__ int red[256];
    red[t] = s; __syncthreads();
    for (int off = 128; off; off >>= 1) { if (t < off) red[t] += red[t+off]; __syncthreads(); }
    if (!t) bsum[b] = red[0];
}

__global__ __launch_bounds__(256) void scan_bsum_k(int* __restrict__ bsum, int NB){
    int t = threadIdx.x;
    __shared__ int sh[256];
    sh[t] = (t < NB) ? bsum[t] : 0;
    __syncthreads();
    for (int off = 1; off < 256; off <<= 1) {
        int v = (t >= off) ? sh[t-off] : 0;
        __syncthreads();
        sh[t] += v;
        __syncthreads();
    }
    if (t < NB) bsum[t] = (t == 0) ? 0 : sh[t-1];
}

__global__ __launch_bounds__(256) void scan_apply_k(int* cur, const int* __restrict__ bsum,
                                                    int* __restrict__ rowptr, int N, int E){
    int b = blockIdx.x, t = threadIdx.x;
    int base = b*1024 + t*4;
    int c[4]; int s = 0;
    #pragma unroll
    for (int i = 0; i < 4; ++i) { int idx = base + i; c[i] = (idx < N) ? cur[idx] : 0; s += c[i]; }
    __shared__ int sh[256];
    sh[t] = s; __syncthreads();
    for (int off = 1; off < 256; off <<= 1) {
        int v = (t >= off) ? sh[t-off] : 0;
        __syncthreads();
        sh[t] += v;
        __syncthreads();
    }
    int run = bsum[b] + ((t == 0) ? 0 : sh[t-1]);
    #pragma unroll
    for (int i = 0; i < 4; ++i) {
        int idx = base + i;
        if (idx < N) { rowptr[idx] = run; cur[idx] = run; run += c[i]; }
    }
    if (b == 0 && t == 0) rowptr[N] = E;
}

__global__ void fill_csr_k(const int* __restrict__ row, const int* __restrict__ col,
                           const float* __restrict__ ew, const float* __restrict__ dis,
                           int* __restrict__ cursor, int* __restrict__ csr_src,
                           float* __restrict__ csr_nrm, int E)
{
    int e = blockIdx.x*256+threadIdx.x; if (e>=E) return;
    int r = row[e], c = col[e];
    int pos = atomicAdd(&cursor[c], 1);
    csr_src[pos] = r;
    csr_nrm[pos] = dis[r] * (ew ? ew[e] : 1.f) * dis[c];
}

// O[i] = bias + dis[i]^2 * H[i] + sum_j nrm_j * H[src_j]   -- bf16 in/out, fp32 math
__global__ __launch_bounds__(256) void gcn_gather_k(
    const ushort* __restrict__ H, const int* __restrict__ rowptr,
    const int* __restrict__ csr_src, const float* __restrict__ csr_nrm,
    const float* __restrict__ dis, const float* __restrict__ bias,
    ushort* __restrict__ O, int N)
{
    int node = blockIdx.x*8 + (threadIdx.x >> 5);
    if (node >= N) return;
    int lane = (threadIdx.x & 31)*4;
    float s = dis[node]; s *= s;
    float4 h = b2f4(*(const ushort4*)(H + (size_t)node*128 + lane));
    float4 b = ld4(bias + lane);
    float4 acc = f4fma(s, h, b);
    int j = rowptr[node], end = rowptr[node+1];
    for (; j + 4 <= end; j += 4) {
        int   s0 = csr_src[j],   s1 = csr_src[j+1], s2 = csr_src[j+2], s3 = csr_src[j+3];
        float n0 = csr_nrm[j],   n1 = csr_nrm[j+1], n2 = csr_nrm[j+2], n3 = csr_nrm[j+3];
        float4 h0 = b2f4(*(const ushort4*)(H + (size_t)s0*128 + lane));
        float4 h1 = b2f4(*(const ushort4*)(H + (size_t)s1*128 + lane));
        float4 h2 = b2f4(*(const ushort4*)(H + (size_t)s2*128 + lane));
        float4 h3 = b2f4(*(const ushort4*)(H + (size_t)s3*128 + lane));
        acc = f4fma(n0, h0, acc);
        acc = f4fma(n1, h1, acc);
        acc = f4fma(n2, h2, acc);
        acc = f4fma(n3, h3, acc);
    }
    for (; j < end; ++j) {
        float4 h0 = b2f4(*(const ushort4*)(H + (size_t)csr_src[j]*128 + lane));
        acc = f4fma(csr_nrm[j], h0, acc);
    }
    *(ushort4*)(O + (size_t)node*128 + lane) = f2b4(acc);
}

// O = relu(A) @ W via bf16 MFMA; A:[N,128] bf16, W:[128,128] f32, O bf16
__global__ __launch_bounds__(256) void gemm_mfma_k(
    const ushort* __restrict__ A, const float* __restrict__ W,
    ushort* __restrict__ O, int N)
{
    __shared__ ushort WsF[16384];
    __shared__ ushort As[64*136];
    int t = threadIdx.x;
    for (int i = t; i < 16384; i += 256) {
        int j = i & 7, col = (i >> 3) & 15, kg = (i >> 7) & 3, ks = (i >> 9) & 3, ct = i >> 11;
        WsF[i] = f2b(W[(ks*32 + kg*8 + j)*128 + ct*16 + col]);
    }
    int row0 = blockIdx.x*64;
    for (int i = t; i < 64*32; i += 256) {
        int r = i >> 5, c4 = (i & 31)*4;
        ushort4 v = *(const ushort4*)(A + (size_t)(row0 + r)*128 + c4);
        v.x = (v.x & 0x8000) ? 0 : v.x;
        v.y = (v.y & 0x8000) ? 0 : v.y;
        v.z = (v.z & 0x8000) ? 0 : v.z;
        v.w = (v.w & 0x8000) ? 0 : v.w;
        *(ushort4*)(As + r*136 + c4) = v;
    }
    __syncthreads();
    int w = t >> 6, l = t & 63;
    int m16 = l & 15, kg = l >> 4;
    short8v af[4];
    #pragma unroll
    for (int ks = 0; ks < 4; ++ks)
        af[ks] = *(const short8v*)(As + (w*16 + m16)*136 + ks*32 + kg*8);
    #pragma unroll
    for (int ct = 0; ct < 8; ++ct) {
        f32x4 acc = {0.f, 0.f, 0.f, 0.f};
        #pragma unroll
        for (int ks = 0; ks < 4; ++ks) {
            short8v bf = *(const short8v*)(WsF + ((ct*4 + ks)*4 + kg)*128 + m16*8);
            acc = __builtin_amdgcn_mfma_f32_16x16x32_bf16(af[ks], bf, acc, 0, 0, 0);
        }
        int col = ct*16 + m16;
        int rbase = row0 + w*16 + kg*4;
        #pragma unroll
        for (int j = 0; j < 4; ++j)
            O[(size_t)(rbase + j)*128 + col] = f2b(acc[j]);
    }
}

// ---------------- mean pool (bf16 input): 4-way pipelined, LDS-direct accumulation ----
__global__ __launch_bounds__(128) void mean_pool_sum_k(
    const ushort* __restrict__ X, const int* __restrict__ bv,
    float* __restrict__ featp, int chunk, int N)
{
    __shared__ float acc[16*128];
    int t = threadIdx.x;
    #pragma unroll
    for (int b = 0; b < 16; ++b) acc[b*128 + t] = 0.f;
    int i0 = blockIdx.x * chunk;
    int iend = min(i0 + chunk, N);
    int i = i0;
    for (; i + 4 <= iend; i += 4) {
        int b0 = bv[i], b1 = bv[i+1], b2 = bv[i+2], b3 = bv[i+3];
        float v0 = fmaxf(b2f(X[(size_t)i*128 + t]),     0.f);
        float v1 = fmaxf(b2f(X[(size_t)(i+1)*128 + t]), 0.f);
        float v2 = fmaxf(b2f(X[(size_t)(i+2)*128 + t]), 0.f);
        float v3 = fmaxf(b2f(X[(size_t)(i+3)*128 + t]), 0.f);
        acc[b0*128 + t] += v0;
        acc[b1*128 + t] += v1;
        acc[b2*128 + t] += v2;
        acc[b3*128 + t] += v3;
    }
    for (; i < iend; ++i) {
        int b = bv[i];
        acc[b*128 + t] += fmaxf(b2f(X[(size_t)i*128 + t]), 0.f);
    }
    #pragma unroll
    for (int b = 0; b < 16; ++b) {
        float v = acc[b*128 + t];
        if (v != 0.f) unsafeAtomicAdd(featp + b*512 + t, v);
    }
}

__global__ void count_batch_k(const int* __restrict__ bv, float* __restrict__ cnt, int N){
    __shared__ int h[16];
    int t = threadIdx.x;
    if (t < 16) h[t] = 0;
    __syncthreads();
    int i = blockIdx.x*256 + t;
    if (i < N) atomicAdd(&h[bv[i]], 1);
    __syncthreads();
    if (t < 16 && h[t]) unsafeAtomicAdd(&cnt[t], (float)h[t]);
}

// ---------------- voxel fp32 NCDHW -> bf16 channels-last [n][64^3][2] ----------------
__global__ __launch_bounds__(256) void cvt_cl0_k(const float* __restrict__ vox, unsigned* __restrict__ out){
    int idx = blockIdx.x*256 + threadIdx.x;       // 16 * 262144
    int n = idx >> 18, v = idx & 262143;
    float a = vox[((size_t)n*2    )*262144 + v];
    float b = vox[((size_t)n*2 + 1)*262144 + v];
    out[idx] = (unsigned)f2b(a) | ((unsigned)f2b(b) << 16);
}

// conv1 weight prepack: k = rowIdx*16 + dx*4 + ci (ci padded 2->4, rows padded 9->10)
__global__ void wfrag1_k(const float* __restrict__ wt, ushort* __restrict__ out){
    int i = blockIdx.x*256 + threadIdx.x;
    if (i >= 2560) return;
    int j = i & 7, col = (i >> 3) & 15, kg = (i >> 7) & 3, ks = i >> 9;
    int rowIdx = ks*2 + (kg >> 1);
    int dx = (kg & 1)*2 + (j >> 2), ci = j & 3;
    ushort v = 0;
    if (rowIdx < 9 && dx < 3 && ci < 2)
        v = f2b(wt[(col*2 + ci)*27 + (rowIdx/3)*9 + (rowIdx%3)*3 + dx]);
    out[i] = v;
}

// conv1 implicit-GEMM MFMA: CL bf16 [n][64^3][2] -> pooled max/min CL [n][32^3][16]
__global__ __launch_bounds__(256) void conv1_mfma_k(
    const ushort* __restrict__ Xcl0, const ushort* __restrict__ wf,
    const float* __restrict__ bias,
    ushort* __restrict__ outmax, ushort* __restrict__ outmin, float* __restrict__ stats_part)
{
    __shared__ __align__(16) ushort Ast[2896];    // [10z][4y][18x][4ci-pad] (2880) + guard
    __shared__ __align__(16) ushort Bfr[2560];
    __shared__ float red[128];

    int tid = threadIdx.x;
    int n = blockIdx.y;
    int bx = blockIdx.x;
    int xb = bx & 3, yb = (bx >> 2) & 31, zb = bx >> 7;
    int w = tid >> 6, l = tid & 63;
    int col = l & 15, kg = l >> 4;

    for (int i = tid; i < 320; i += 256)
        *(ushort8v*)(Bfr + i*8) = *(const ushort8v*)(wf + i*8);
    for (int i = tid; i < 720; i += 256) {
        int z = i/72, r = i - z*72, y = r/18, x = r - y*18;
        int gz = zb*8 - 1 + z, gy = yb*2 - 1 + y, gx = xb*16 - 1 + x;
        unsigned packed = 0;
        if ((unsigned)gz < 64u && (unsigned)gy < 64u && (unsigned)gx < 64u)
            packed = *(const unsigned*)(Xcl0 + ((((size_t)n << 18) + ((gz*64 + gy)*64 + gx)) << 1));
        *(uint2*)(Ast + i*4) = make_uint2(packed, 0u);
    }
    if (tid < 2) *(uint2*)(Ast + 2880 + tid*4) = make_uint2(0u, 0u);
    __syncthreads();

    int halfoff = (kg & 1)*2;
    f32x4 acc[4];
    #pragma unroll
    for (int mt = 0; mt < 4; ++mt) acc[mt] = (f32x4){0.f,0.f,0.f,0.f};

    #pragma unroll
    for (int ks = 0; ks < 5; ++ks) {
        int rowIdx = ks*2 + (kg >> 1); if (rowIdx >= 9) rowIdx = 0;
        int kd = rowIdx/3, kh = rowIdx - kd*3;
        int off = kd*288 + kh*72 + (col + halfoff)*4;
        short8v bb = *(const short8v*)(Bfr + (ks*4 + kg)*128 + col*8);
        #pragma unroll
        for (int mt = 0; mt < 4; ++mt) {
            const ushort* p = Ast + (2*w + (mt>>1))*288 + (mt&1)*72 + off;
            short8v a = ld_a8(p);
            acc[mt] = __builtin_amdgcn_mfma_f32_16x16x32_bf16(a, bb, acc[mt], 0, 0, 0);
        }
    }

    int zp = zb*4 + w, yp = yb;
    float bl = bias[col];
    float s = 0.f, q = 0.f;
    float mx0=-1e30f, mx1=-1e30f, mn0=1e30f, mn1=1e30f;
    #pragma unroll
    for (int mt = 0; mt < 4; ++mt)
        #pragma unroll
        for (int j = 0; j < 4; ++j) {
            float v = acc[mt][j] + bl;
            s += v; q = fmaf(v, v, q);
            if (j < 2) { mx0 = fmaxf(mx0, v); mn0 = fminf(mn0, v); }
            else       { mx1 = fmaxf(mx1, v); mn1 = fminf(mn1, v); }
        }
    s += __shfl_xor(s, 16); s += __shfl_xor(s, 32);
    q += __shfl_xor(q, 16); q += __shfl_xor(q, 32);
    if (kg == 0) { red[(w*16 + col)*2] = s; red[(w*16 + col)*2 + 1] = q; }
    size_t ob = ((((size_t)(n*32 + zp))*32 + yp)*32 + xb*8 + kg*2)*16 + col;
    outmax[ob]      = f2b(mx0); outmin[ob]      = f2b(mn0);
    outmax[ob + 16] = f2b(mx1); outmin[ob + 16] = f2b(mn1);
    __syncthreads();
    if (tid < 32) {
        float t = red[tid] + red[32 + tid] + red[64 + tid] + red[96 + tid];
        unsafeAtomicAdd(&stats_part[((bx & 127) << 5) + tid], t);
    }
}

// sum partial stats -> final stats
__global__ void stats_reduce_k(const float* __restrict__ part, float* __restrict__ out,
                               int npart, int n)
{
    int c = blockIdx.x*64 + threadIdx.x;
    if (c >= n) return;
    float s = 0.f;
    for (int p = 0; p < npart; ++p) s += part[p*n + c];
    out[c] = s;
}

__global__ void bn_final_k(const float* __restrict__ stats, const float* __restrict__ g,
                           const float* __restrict__ b, float* __restrict__ sc, float* __restrict__ sh,
                           int C, float invN)
{
    int c = threadIdx.x; if (c >= C) return;
    float m = stats[c*2] * invN;
    float v = stats[c*2+1] * invN - m*m;
    float s = g[c] * rsqrtf(v + 1e-5f);
    sc[c] = s; sh[c] = b[c] - m*s;
}

// prepack conv weights into MFMA B-fragment order (bf16), K padded to 448 per ci-half
__global__ void wfrag_k(const float* __restrict__ wt, ushort* __restrict__ out,
                        int CIN, int COT, int total)
{
    int i = blockIdx.x*256 + threadIdx.x;
    if (i >= total) return;
    int per_h = COT*7168;
    int h  = i / per_h;
    int r0 = i - h*per_h;
    int ct = r0 / 7168;
    int r  = r0 - ct*7168;
    int ks = r >> 9;
    int r2 = r & 511;
    int kg = r2 >> 7, col = (r2 >> 3) & 15, j = r2 & 7;
    int k = ks*32 + kg*8 + j;
    int nbr = k >> 4, ci = (k & 15) + h*16;
    out[i] = (nbr < 27) ? f2b(wt[((size_t)(ct*16 + col)*CIN + ci)*27 + nbr]) : (ushort)0;
}

// ---------------- implicit-GEMM MFMA conv + bias + BN-stats(partial) + max/min pool ----
template<int CIHALVES, int COT, int D, int CIN, int COUT>
__global__ __launch_bounds__(256) void conv_mfma_k(
    const ushort* __restrict__ Xcl, const ushort* __restrict__ WfragG,
    const float* __restrict__ bias,
    ushort* __restrict__ outmax, ushort* __restrict__ outmin,
    float* __restrict__ stats_part, int pmask)
{
    constexpr int PD = D/2;
    constexpr int XT = D/16, YT = D/2;
    __shared__ __align__(16) ushort Ast[17280];
    __shared__ __align__(16) ushort Bfr[COT*7168];
    __shared__ float red[4*COT*32];

    int tid = threadIdx.x;
    int n = blockIdx.y;
    int bx = blockIdx.x;
    int xb = bx % XT, yb = (bx/XT) % YT, zb = bx/(XT*YT);
    int w = tid >> 6, l = tid & 63;
    int col = l & 15, kg = l >> 4;

    int laneoff[14];
    #pragma unroll
    for (int ks = 0; ks < 14; ++ks) {
        int nbr = ks*2 + (l >> 5);
        if (nbr >= 27) nbr = 0;
        int dz = nbr/9, r9 = nbr - dz*9, dy = r9/3, dx = r9 - dy*3;
        laneoff[ks] = dz*1728 + dy*432 + (col + dx)*24 + ((l>>4)&1)*8;
    }
    int Mbase[4];
    #pragma unroll
    for (int mt = 0; mt < 4; ++mt)
        Mbase[mt] = (2*w + (mt>>1))*1728 + (mt&1)*432;

    f32x4 acc[4][COT];
    #pragma unroll
    for (int mt = 0; mt < 4; ++mt)
        #pragma unroll
        for (int ct = 0; ct < COT; ++ct)
            acc[mt][ct] = (f32x4){0.f,0.f,0.f,0.f};

    for (int h = 0; h < CIHALVES; ++h) {
        __syncthreads();
        for (int i = tid; i < 1440; i += 256) {
            int vec = i >> 1, hi8 = (i & 1) << 3;
            int z = vec/72, r = vec - z*72, y = r/18, x = r - y*18;
            int gz = zb*8 - 1 + z, gy = yb*2 - 1 + y, gx = xb*16 - 1 + x;
            ushort8v val = {0,0,0,0,0,0,0,0};
            if ((unsigned)gz < (unsigned)D && (unsigned)gy < (unsigned)D && (unsigned)gx < (unsigned)D) {
                size_t gi = (((size_t)n*D*D*D) + ((size_t)gz*D + gy)*D + gx)*CIN + h*16 + hi8;
                val = *(const ushort8v*)(Xcl + gi);
            }
            *(ushort8v*)(Ast + (vec)*24 + hi8) = val;
        }
        for (int i = tid; i < COT*896; i += 256)
            *(ushort8v*)(Bfr + i*8) = *(const ushort8v*)(WfragG + (size_t)h*COT*7168 + i*8);
        __syncthreads();

        #pragma unroll
        for (int ks = 0; ks < 14; ++ks) {
            short8v a[4];
            #pragma unroll
            for (int mt = 0; mt < 4; ++mt)
                a[mt] = *(const short8v*)(Ast + Mbase[mt] + laneoff[ks]);
            short8v bb[COT];
            #pragma unroll
            for (int ct = 0; ct < COT; ++ct)
                bb[ct] = *(const short8v*)(Bfr + ct*7168 + ks*512 + kg*128 + col*8);
            #pragma unroll
            for (int mt = 0; mt < 4; ++mt)
                #pragma unroll
                for (int ct = 0; ct < COT; ++ct)
                    acc[mt][ct] = __builtin_amdgcn_mfma_f32_16x16x32_bf16(a[mt], bb[ct], acc[mt][ct], 0, 0, 0);
        }
    }

    int zp = zb*4 + w, yp = yb;
    #pragma unroll
    for (int ct = 0; ct < COT; ++ct) {
        float bl = bias[ct*16 + col];
        float s = 0.f, q = 0.f;
        float mx0 = -1e30f, mx1 = -1e30f, mn0 = 1e30f, mn1 = 1e30f;
        #pragma unroll
        for (int mt = 0; mt < 4; ++mt) {
            #pragma unroll
            for (int j = 0; j < 4; ++j) {
                float v = acc[mt][ct][j] + bl;
                s += v; q = fmaf(v, v, q);
                if (j < 2) { mx0 = fmaxf(mx0, v); mn0 = fminf(mn0, v); }
                else       { mx1 = fmaxf(mx1, v); mn1 = fminf(mn1, v); }
            }
        }
        s += __shfl_xor(s, 16); s += __shfl_xor(s, 32);
        q += __shfl_xor(q, 16); q += __shfl_xor(q, 32);
        if (kg == 0) {
            red[((w*COT + ct)*16 + col)*2]     = s;
            red[((w*COT + ct)*16 + col)*2 + 1] = q;
        }
        size_t ob = (((size_t)((n*PD + zp)*PD + yp))*PD + xb*8 + kg*2)*COUT + ct*16 + col;
        outmax[ob]        = f2b(mx0);
        outmin[ob]        = f2b(mn0);
        outmax[ob + COUT] = f2b(mx1);
        outmin[ob + COUT] = f2b(mn1);
    }
    __syncthreads();
    if (tid < COT*32) {
        float t = red[tid] + red[COT*32 + tid] + red[2*COT*32 + tid] + red[3*COT*32 + tid];
        unsafeAtomicAdd(&stats_part[(bx & pmask)*(COT*32) + tid], t);
    }
}

// channels-last bf16 pooled max/min -> BN+ReLU -> bf16
__global__ __launch_bounds__(256) void bn_select_cl23_k(
    const ushort* __restrict__ mx, const ushort* __restrict__ mn,
    const float* __restrict__ sc, const float* __restrict__ sh,
    ushort* __restrict__ out, int cmask, int total)
{
    int idx = blockIdx.x*256 + threadIdx.x;
    if (idx >= total) return;
    int ci = idx & cmask;
    float s = sc[ci];
    float v = b2f((s >= 0.f) ? mx[idx] : mn[idx]);
    out[idx] = f2b(fmaxf(fmaf(v, s, sh[ci]), 0.f));
}

// fc: X channels-last bf16 [16][512][64] @ W[32768,128] -> 8 partial slices
__global__ __launch_bounds__(128) void fc_acc2_k(
    const ushort* __restrict__ X, const float* __restrict__ W, float* __restrict__ part)
{
    __shared__ float Xs[16*64];
    int t = threadIdx.x;
    int bx = blockIdx.x;
    int k0 = bx*64;
    int c0 = k0 >> 9, sp0 = k0 & 511;
    for (int i = t; i < 1024; i += 128) {
        int b = i >> 6, spo = i & 63;
        Xs[b*64 + spo] = b2f(X[(size_t)(b*512 + sp0 + spo)*64 + c0]);
    }
    __syncthreads();
    float acc[16];
    #pragma unroll
    for (int b = 0; b < 16; ++b) acc[b] = 0.f;
    #pragma unroll 4
    for (int kk = 0; kk < 64; ++kk) {
        float w = W[(size_t)(k0 + kk)*128 + t];
        #pragma unroll
        for (int b = 0; b < 16; ++b) acc[b] = fmaf(Xs[b*64 + kk], w, acc[b]);
    }
    float* pp = part + (bx & 7)*2048;
    #pragma unroll
    for (int b = 0; b < 16; ++b) unsafeAtomicAdd(pp + b*128 + t, acc[b]);
}

// sum fc partials -> feat[:,384:512]
__global__ void fc_reduce_k(const float* __restrict__ part, float* __restrict__ feat)
{
    int i = blockIdx.x*256 + threadIdx.x;    // 2048
    if (i >= 2048) return;
    int b = i >> 7, t = i & 127;
    float s = 0.f;
    #pragma unroll
    for (int p = 0; p < 8; ++p) s += part[p*2048 + b*128 + t];
    feat[b*512 + 384 + t] = s;
}

// ---------------- dense head layers: K-parallel (4 kgroups x 64 cols), 4-deep MLP -----
__global__ __launch_bounds__(256) void head2_k(
    const float* __restrict__ X, const float* __restrict__ W, const float* __restrict__ b,
    float* __restrict__ O, int K, int Ncol, int relu)
{
    __shared__ float Xs[512*16];      // transposed: [k][bi]
    __shared__ float red[3*16*64];
    int t = threadIdx.x;
    int kg = t >> 6, lane = t & 63;
    int c = blockIdx.x*64 + lane;
    bool valid = (c < Ncol);
    for (int i = t; i < 16*K; i += 256) {
        int bi = i & 15, k = i >> 4;
        Xs[k*16 + bi] = X[bi*K + k];
    }
    __syncthreads();
    float acc[16];
    #pragma unroll
    for (int bi = 0; bi < 16; ++bi) acc[bi] = 0.f;
    int k = kg;
    for (; k + 12 < K; k += 16) {
        float w0 = valid ? W[(size_t)k*Ncol + c] : 0.f;
        float w1 = valid ? W[(size_t)(k+4)*Ncol + c] : 0.f;
        float w2 = valid ? W[(size_t)(k+8)*Ncol + c] : 0.f;
        float w3 = valid ? W[(size_t)(k+12)*Ncol + c] : 0.f;
        const float* xp0 = Xs + k*16;
        const float* xp1 = Xs + (k+4)*16;
        const float* xp2 = Xs + (k+8)*16;
        const float* xp3 = Xs + (k+12)*16;
        #pragma unroll
        for (int bi = 0; bi < 16; ++bi) {
            acc[bi] = fmaf(xp0[bi], w0, acc[bi]);
            acc[bi] = fmaf(xp1[bi], w1, acc[bi]);
            acc[bi] = fmaf(xp2[bi], w2, acc[bi]);
            acc[bi] = fmaf(xp3[bi], w3, acc[bi]);
        }
    }
    for (; k < K; k += 4) {
        float w = valid ? W[(size_t)k*Ncol + c] : 0.f;
        const float* xp = Xs + k*16;
        #pragma unroll
        for (int bi = 0; bi < 16; ++bi) acc[bi] = fmaf(xp[bi], w, acc[bi]);
    }
    if (kg) {
        #pragma unroll
        for (int bi = 0; bi < 16; ++bi) red[((kg-1)*16 + bi)*64 + lane] = acc[bi];
    }
    __syncthreads();
    if (kg == 0 && valid) {
        float bias = b[c];
        #pragma unroll
        for (int bi = 0; bi < 16; ++bi) {
            float v = acc[bi] + red[bi*64 + lane] + red[(16 + bi)*64 + lane]
                    + red[(32 + bi)*64 + lane] + bias;
            if (relu) v = fmaxf(v, 0.f);
            O[bi*Ncol + c] = v;
        }
    }
}

__global__ void gebn_k(const float* __restrict__ g2, const float* __restrict__ g,
                       const float* __restrict__ b, float* __restrict__ featg)
{
    int c = threadIdx.x;
    float m = 0.f;
    for (int i = 0; i < 16; ++i) m += g2[i*128 + c];
    m *= (1.f/16.f);
    float v = 0.f;
    for (int i = 0; i < 16; ++i) { float d = g2[i*128 + c] - m; v += d*d; }
    v *= (1.f/16.f);
    float s = g[c] * rsqrtf(v + 1e-5f);
    for (int i = 0; i < 16; ++i)
        featg[i*512 + c] = fmaxf((g2[i*128 + c] - m)*s + b[c], 0.f);
}

__global__ void finalize_feat_k(float* __restrict__ feat, const float* __restrict__ cntm,
                                const float* __restrict__ cntz, const float* __restrict__ fcb)
{
    int t = blockIdx.x*256 + threadIdx.x;
    if (t >= 8192) return;
    int bi = t >> 9, c = t & 511;
    float v = feat[t];
    if      (c < 128) v /= fmaxf(cntm[bi], 1.f);
    else if (c < 256) v /= fmaxf(cntz[bi], 1.f);
    else if (c >= 384) v = fmaxf(v + fcb[c - 384], 0.f);
    feat[t] = v;
}

// =====================================================================================
extern "C" void kernel_launch(void* const* d_in, const int* in_sizes, int n_in,
                              void* d_out, int out_size, void* d_ws, size_t ws_size,
                              hipStream_t stream)
{
    const int*   mol_x  = (const int*)  d_in[0];
    const float* mol_q  = (const float*)d_in[1];
    const int*   mol_ei = (const int*)  d_in[2];
    const float* mol_ew = (const float*)d_in[3];
    const int*   mol_bv = (const int*)  d_in[4];
    const int*   zeo_x  = (const int*)  d_in[5];
    const int*   zeo_ei = (const int*)  d_in[6];
    const int*   zeo_bv = (const int*)  d_in[7];
    const float* voxel  = (const float*)d_in[8];
    const float* gattr  = (const float*)d_in[9];
    const float* ea  = (const float*)d_in[10];
    const float* ed  = (const float*)d_in[11];
    const float* ec  = (const float*)d_in[12];
    const float* eh  = (const float*)d_in[13];
    const float* ear = (const float*)d_in[14];
    const float* ech = (const float*)d_in[15];
    const float* mc1w=(const float*)d_in[16]; const float* mc1b=(const float*)d_in[17];
    const float* mc2w=(const float*)d_in[18]; const float* mc2b=(const float*)d_in[19];
    const float* zc1w=(const float*)d_in[20]; const float* zc1b=(const float*)d_in[21];
    const float* zc2w=(const float*)d_in[22]; const float* zc2b=(const float*)d_in[23];
    const float* cv1w=(const float*)d_in[24]; const float* cv1b=(const float*)d_in[25];
    const float* bn1g=(const float*)d_in[26]; const float* bn1b=(const float*)d_in[27];
    const float* cv2w=(const float*)d_in[28]; const float* cv2b=(const float*)d_in[29];
    const float* bn2g=(const float*)d_in[30]; const float* bn2b=(const float*)d_in[31];
    const float* cv3w=(const float*)d_in[32]; const float* cv3b=(const float*)d_in[33];
    const float* bn3g=(const float*)d_in[34]; const float* bn3b=(const float*)d_in[35];
    const float* fcw =(const float*)d_in[36]; const float* fcb =(const float*)d_in[37];
    const float* ge1w=(const float*)d_in[38]; const float* ge1b=(const float*)d_in[39];
    const float* ge2w=(const float*)d_in[40]; const float* ge2b=(const float*)d_in[41];
    const float* gbng=(const float*)d_in[42]; const float* gbnb=(const float*)d_in[43];
    const float* h1w =(const float*)d_in[44]; const float* h1b =(const float*)d_in[45];
    const float* h2w =(const float*)d_in[46]; const float* h2b =(const float*)d_in[47];
    const float* h3w =(const float*)d_in[48]; const float* h3b =(const float*)d_in[49];

    const int Nm = in_sizes[0]/6, Em = in_sizes[2]/2;
    const int Nz = in_sizes[5]/6, Ez = in_sizes[6]/2;
    const int NBm = (Nm + 1023)/1024, NBz = (Nz + 1023)/1024;

    float* WS = (float*)d_ws;
    float* A  = WS;
    float* Bb = WS + 16777216;
    float* S  = WS + 33554432;
    ushort* X0 = (ushort*)A;
    ushort* X1 = (ushort*)A + 16777216;
    ushort* X2 = (ushort*)Bb;
    ushort* X3 = (ushort*)Bb + 16777216;
    // conv-phase channels-last bf16 buffers (GNN buffers dead by then)
    ushort* Au   = (ushort*)A;
    ushort* pm1  = Au;                      // [16][32^3][16]
    ushort* pn1  = Au + 8388608;
    ushort* Xcl0 = Au + 16777216;           // [16][64^3][2]
    ushort* Xcl1 = (ushort*)Bb;             // [16][32^3][16]
    ushort* pm2  = Au;                      // [16][16^3][32]
    ushort* pn2  = Au + 2097152;
    ushort* Xcl2 = Au + 4194304;
    ushort* pm3  = (ushort*)Bb;             // [16][8^3][64]
    ushort* pn3  = (ushort*)Bb + 524288;
    ushort* Xcl3 = (ushort*)Bb + 1048576;
    float* deg  = S;
    float* dis  = S + 131072;
    float* csr_nrm = S + 262144;
    float* T    = S + 786432;
    float* cntm = S + 807040;
    float* cntz = S + 807056;
    float* feat = S + 807072;
    float* st1  = S + 815264; float* st2 = st1 + 32; float* st3 = st1 + 96;
    float* sc1  = S + 815488; float* sh1 = sc1 + 16;
    float* sc2  = sc1 + 32;   float* sh2 = sc1 + 64;
    float* sc3  = sc1 + 96;   float* sh3 = sc1 + 160;
    float* g1   = S + 815712;
    float* g2   = S + 816736;
    float* H1   = S + 818784;
    float* H2   = S + 826976;
    int* rowptr  = (int*)(S + 831072);          // 131073
    int* cursor  = (int*)(S + 962176);          // 131072
    int* csr_src = (int*)(S + 1093248);         // 524288 (ends S+1617536)
    ushort* wf2 = (ushort*)(S + 1617536);       // 14336 ush
    ushort* wf3 = (ushort*)(S + 1624704);       // 57344 ush
    int* bsum   = (int*)(S + 1653376);          // 256 ints
    ushort* wf1 = (ushort*)(S + 1653632);       // 2560 ush
    float* stp1 = S + 1655040;                  // 128*32
    float* stp2 = S + 1659136;                  // 32*64
    float* stp3 = S + 1661184;                  // 8*128 (ends S+1662208)
    float* fcpart = S + 1662208;                // 8*2048 (ends S+1678592)

    hipMemsetAsync(S, 0, (size_t)831072*sizeof(float), stream);
    hipMemsetAsync(stp1, 0, (size_t)(7168 + 16384)*sizeof(float), stream);  // stp1..3 + fcpart

    // weight prepacks for MFMA convs
    wfrag1_k<<<10,256,0,stream>>>(cv1w, wf1);
    wfrag_k<<<56,256,0,stream>>>(cv2w, wf2, 16, 2, 14336);
    wfrag_k<<<224,256,0,stream>>>(cv3w, wf3, 32, 4, 57344);

    // ---------------- molecule branch ----------------
    build_tables_k<<<161,128,0,stream>>>(ea,ed,ec,eh,ear,ech, mc1w, T);
    init_deg_k   <<<Nm/256,256,0,stream>>>(deg, Nm);
    deg_scatter_k<<<Em/256,256,0,stream>>>(mol_ei+Em, mol_ew, deg, Em);
    dis_k        <<<Nm/256,256,0,stream>>>(deg, dis, Nm);
    hipMemsetAsync(cursor, 0, (size_t)Nm*sizeof(int), stream);
    count_in_k   <<<Em/256,256,0,stream>>>(mol_ei+Em, cursor, Em);
    blocksum_k   <<<NBm,256,0,stream>>>(cursor, bsum, Nm);
    scan_bsum_k  <<<1,256,0,stream>>>(bsum, NBm);
    scan_apply_k <<<NBm,256,0,stream>>>(cursor, bsum, rowptr, Nm, Em);
    fill_csr_k   <<<Em/256,256,0,stream>>>(mol_ei, mol_ei+Em, mol_ew, dis, cursor, csr_src, csr_nrm, Em);
    embed_lookup_k<<<Nm/8,256,0,stream>>>(mol_x, mol_q, T, mc1w + 112*128, X0, Nm);
    gcn_gather_k <<<Nm/8,256,0,stream>>>(X0, rowptr, csr_src, csr_nrm, dis, mc1b, X1, Nm);
    gemm_mfma_k  <<<Nm/64,256,0,stream>>>(X1, mc2w, X2, Nm);
    gcn_gather_k <<<Nm/8,256,0,stream>>>(X2, rowptr, csr_src, csr_nrm, dis, mc2b, X3, Nm);
    count_batch_k<<<Nm/256,256,0,stream>>>(mol_bv, cntm, Nm);
    mean_pool_sum_k<<<2048,128,0,stream>>>(X3, mol_bv, feat + 0, (Nm+2047)/2048, Nm);

    // ---------------- zeolite branch ----------------
    build_tables_k<<<161,128,0,stream>>>(ea,ed,ec,eh,ear,ech, zc1w, T);
    init_deg_k   <<<Nz/256,256,0,stream>>>(deg, Nz);
    deg_scatter_k<<<Ez/256,256,0,stream>>>(zeo_ei+Ez, nullptr, deg, Ez);
    dis_k        <<<Nz/256,256,0,stream>>>(deg, dis, Nz);
    hipMemsetAsync(cursor, 0, (size_t)Nz*sizeof(int), stream);
    count_in_k   <<<Ez/256,256,0,stream>>>(zeo_ei+Ez, cursor, Ez);
    blocksum_k   <<<NBz,256,0,stream>>>(cursor, bsum, Nz);
    scan_bsum_k  <<<1,256,0,stream>>>(bsum, NBz);
    scan_apply_k <<<NBz,256,0,stream>>>(cursor, bsum, rowptr, Nz, Ez);
    fill_csr_k   <<<Ez/256,256,0,stream>>>(zeo_ei, zeo_ei+Ez, nullptr, dis, cursor, csr_src, csr_nrm, Ez);
    embed_lookup_k<<<Nz/8,256,0,stream>>>(zeo_x, nullptr, T, nullptr, X0, Nz);
    gcn_gather_k <<<Nz/8,256,0,stream>>>(X0, rowptr, csr_src, csr_nrm, dis, zc1b, X1, Nz);
    gemm_mfma_k  <<<Nz/64,256,0,stream>>>(X1, zc2w, X2, Nz);
    gcn_gather_k <<<Nz/8,256,0,stream>>>(X2, rowptr, csr_src, csr_nrm, dis, zc2b, X3, Nz);
    count_batch_k<<<Nz/256,256,0,stream>>>(zeo_bv, cntz, Nz);
    mean_pool_sum_k<<<2048,128,0,stream>>>(X3, zeo_bv, feat + 128, (Nz+2047)/2048, Nz);

    // ---------------- voxel CNN (all layers MFMA implicit-GEMM) ----------------
    cvt_cl0_k<<<16384,256,0,stream>>>(voxel, (unsigned*)Xcl0);
    conv1_mfma_k<<<dim3(1024,16),256,0,stream>>>(Xcl0, wf1, cv1b, pm1, pn1, stp1);
    stats_reduce_k<<<1,64,0,stream>>>(stp1, st1, 128, 32);
    bn_final_k<<<1,64,0,stream>>>(st1, bn1g, bn1b, sc1, sh1, 16, 1.f/(16.f*262144.f));
    bn_select_cl23_k<<<32768,256,0,stream>>>(pm1, pn1, sc1, sh1, Xcl1, 15, 8388608);

    conv_mfma_k<1,2,32,16,32><<<dim3(128,16),256,0,stream>>>(Xcl1, wf2, cv2b, pm2, pn2, stp2, 31);
    stats_reduce_k<<<1,64,0,stream>>>(stp2, st2, 32, 64);
    bn_final_k<<<1,64,0,stream>>>(st2, bn2g, bn2b, sc2, sh2, 32, 1.f/(16.f*32768.f));
    bn_select_cl23_k<<<8192,256,0,stream>>>(pm2, pn2, sc2, sh2, Xcl2, 31, 2097152);

    conv_mfma_k<2,4,16,32,64><<<dim3(16,16),256,0,stream>>>(Xcl2, wf3, cv3b, pm3, pn3, stp3, 7);
    stats_reduce_k<<<2,64,0,stream>>>(stp3, st3, 8, 128);
    bn_final_k<<<1,64,0,stream>>>(st3, bn3g, bn3b, sc3, sh3, 64, 1.f/(16.f*4096.f));
    bn_select_cl23_k<<<2048,256,0,stream>>>(pm3, pn3, sc3, sh3, Xcl3, 63, 524288);

    fc_acc2_k<<<512,128,0,stream>>>(Xcl3, fcw, fcpart);
    fc_reduce_k<<<8,256,0,stream>>>(fcpart, feat);

    // ---------------- global encoder ----------------
    head2_k<<<1,256,0,stream>>>(gattr, ge1w, ge1b, g1, 17, 64, 1);
    head2_k<<<2,256,0,stream>>>(g1, ge2w, ge2b, g2, 64, 128, 0);
    gebn_k<<<1,128,0,stream>>>(g2, gbng, gbnb, feat + 256);

    // ---------------- fusion head ----------------
    finalize_feat_k<<<32,256,0,stream>>>(feat, cntm, cntz, fcb);
    head2_k<<<8,256,0,stream>>>(feat, h1w, h1b, H1, 512, 512, 1);
    head2_k<<<4,256,0,stream>>>(H1, h2w, h2b, H2, 512, 256, 1);
    head2_k<<<1,256,0,stream>>>(H2, h3w, h3b, (float*)d_out, 256, 3, 0);
}

// Round 18
// 747.700 us; speedup vs baseline: 2.0529x; 1.0741x over previous
//
#include <hip/hip_runtime.h>
#include <math.h>

#define DEV static __device__ __forceinline__

DEV float4 ld4(const float* p){ return *(const float4*)p; }
DEV float2 ld2(const float* p){ return *(const float2*)p; }
DEV void   st4(float* p, float4 v){ *(float4*)p = v; }
DEV float4 f4add(float4 a, float4 b){ return make_float4(a.x+b.x,a.y+b.y,a.z+b.z,a.w+b.w); }
DEV float4 f4fma(float s, float4 a, float4 c){ return make_float4(fmaf(s,a.x,c.x),fmaf(s,a.y,c.y),fmaf(s,a.z,c.z),fmaf(s,a.w,c.w)); }

// bf16 helpers (RNE pack, exact unpack)
DEV float  b2f(ushort u){ return __uint_as_float(((unsigned)u) << 16); }
DEV ushort f2b(float f){
    unsigned u = __float_as_uint(f);
    return (ushort)((u + 0x7FFFu + ((u >> 16) & 1u)) >> 16);
}
DEV float4 b2f4(ushort4 v){ return make_float4(b2f(v.x), b2f(v.y), b2f(v.z), b2f(v.w)); }
DEV ushort4 f2b4(float4 v){ ushort4 o; o.x=f2b(v.x); o.y=f2b(v.y); o.z=f2b(v.z); o.w=f2b(v.w); return o; }

typedef __attribute__((ext_vector_type(8))) short short8v;            // 8 bf16 = 4 VGPR
typedef __attribute__((ext_vector_type(8))) unsigned short ushort8v;
typedef __attribute__((ext_vector_type(4))) float f32x4;

DEV short8v ld_a8(const ushort* p){   // 8B-aligned 16B LDS read as 2x b64
    ushort4 a = *(const ushort4*)p;
    ushort4 b = *(const ushort4*)(p+4);
    short8v r;
    r[0]=a.x; r[1]=a.y; r[2]=a.z; r[3]=a.w;
    r[4]=b.x; r[5]=b.y; r[6]=b.z; r[7]=b.w;
    return r;
}

// ---------------- GNN: embedding tables  T[161][128] = emb_f @ W_slice ----------------
__global__ __launch_bounds__(128) void build_tables_k(
    const float* __restrict__ ea, const float* __restrict__ ed, const float* __restrict__ ec,
    const float* __restrict__ eh, const float* __restrict__ ear, const float* __restrict__ ech,
    const float* __restrict__ Wm, float* __restrict__ T)
{
    int r = blockIdx.x, c = threadIdx.x;
    const float* e; int dim, woff, rl;
    if      (r < 120) { e=ea;  dim=64; woff=0;   rl=r; }
    else if (r < 132) { e=ed;  dim=16; woff=64;  rl=r-120; }
    else if (r < 147) { e=ec;  dim=16; woff=80;  rl=r-132; }
    else if (r < 155) { e=eh;  dim=8;  woff=96;  rl=r-147; }
    else if (r < 157) { e=ear; dim=4;  woff=104; rl=r-155; }
    else              { e=ech; dim=4;  woff=108; rl=r-157; }
    float acc = 0.f;
    for (int k = 0; k < dim; ++k) acc += e[rl*dim + k] * Wm[(woff + k)*128 + c];
    T[r*128 + c] = acc;
}

__global__ __launch_bounds__(256) void embed_lookup_k(
    const int* __restrict__ xi, const float* __restrict__ charge,
    const float* __restrict__ T, const float* __restrict__ wq,
    ushort* __restrict__ H, int N)
{
    int t = threadIdx.x;
    int node = blockIdx.x*8 + (t >> 5);
    if (node >= N) return;
    int c = (t & 31)*4;
    const int* xp = xi + node*6;
    float4 acc = ld4(T + (       xp[0])*128 + c);
    acc = f4add(acc, ld4(T + (120+xp[1])*128 + c));
    acc = f4add(acc, ld4(T + (132+xp[2])*128 + c));
    acc = f4add(acc, ld4(T + (147+xp[3])*128 + c));
    acc = f4add(acc, ld4(T + (155+xp[4])*128 + c));
    acc = f4add(acc, ld4(T + (157+xp[5])*128 + c));
    if (charge) acc = f4fma(charge[node], ld4(wq + c), acc);
    *(ushort4*)(H + (size_t)node*128 + c) = f2b4(acc);
}

// ---------------- GCN degree / norm / CSR build ----------------
__global__ void init_deg_k(float* deg, int N){ int i = blockIdx.x*256+threadIdx.x; if (i<N) deg[i]=1.f; }

__global__ void deg_scatter_k(const int* __restrict__ col, const float* __restrict__ ew, float* deg, int E){
    int e = blockIdx.x*256+threadIdx.x; if (e>=E) return;
    unsafeAtomicAdd(deg + col[e], ew ? ew[e] : 1.f);
}

__global__ void dis_k(const float* __restrict__ deg, float* __restrict__ dis, int N){
    int i = blockIdx.x*256+threadIdx.x; if (i<N) dis[i] = 1.f/sqrtf(deg[i]);
}

__global__ void count_in_k(const int* __restrict__ col, int* __restrict__ cnt, int E){
    int e = blockIdx.x*256+threadIdx.x; if (e>=E) return;
    atomicAdd(&cnt[col[e]], 1);
}

// ---- multi-block exclusive scan (3 phases; 1024 elems / block) ----
__global__ __launch_bounds__(256) void blocksum_k(const int* __restrict__ cnt, int* __restrict__ bsum, int N){
    int b = blockIdx.x, t = threadIdx.x;
    int base = b*1024 + t*4;
    int s = 0;
    if (base + 3 < N) { int4 v = *(const int4*)(cnt + base); s = v.x + v.y + v.z + v.w; }
    else { for (int i = 0; i < 4; ++i) { int idx = base + i; if (idx < N) s += cnt[idx]; } }
    __shared__ int red[256];
    red[t] = s; __syncthreads();
    for (int off = 128; off; off >>= 1) { if (t < off) red[t] += red[t+off]; __syncthreads(); }
    if (!t) bsum[b] = red[0];
}

__global__ __launch_bounds__(256) void scan_bsum_k(int* __restrict__ bsum, int NB){
    int t = threadIdx.x;
    __shared__ int sh[256];
    sh[t] = (t < NB) ? bsum[t] : 0;
    __syncthreads();
    for (int off = 1; off < 256; off <<= 1) {
        int v = (t >= off) ? sh[t-off] : 0;
        __syncthreads();
        sh[t] += v;
        __syncthreads();
    }
    if (t < NB) bsum[t] = (t == 0) ? 0 : sh[t-1];
}

__global__ __launch_bounds__(256) void scan_apply_k(int* cur, const int* __restrict__ bsum,
                                                    int* __restrict__ rowptr, int N, int E){
    int b = blockIdx.x, t = threadIdx.x;
    int base = b*1024 + t*4;
    int c[4]; int s = 0;
    #pragma unroll
    for (int i = 0; i < 4; ++i) { int idx = base + i; c[i] = (idx < N) ? cur[idx] : 0; s += c[i]; }
    __shared__ int sh[256];
    sh[t] = s; __syncthreads();
    for (int off = 1; off < 256; off <<= 1) {
        int v = (t >= off) ? sh[t-off] : 0;
        __syncthreads();
        sh[t] += v;
        __syncthreads();
    }
    int run = bsum[b] + ((t == 0) ? 0 : sh[t-1]);
    #pragma unroll
    for (int i = 0; i < 4; ++i) {
        int idx = base + i;
        if (idx < N) { rowptr[idx] = run; cur[idx] = run; run += c[i]; }
    }
    if (b == 0 && t == 0) rowptr[N] = E;
}

__global__ void fill_csr_k(const int* __restrict__ row, const int* __restrict__ col,
                           const float* __restrict__ ew, const float* __restrict__ dis,
                           int* __restrict__ cursor, int* __restrict__ csr_src,
                           float* __restrict__ csr_nrm, int E)
{
    int e = blockIdx.x*256+threadIdx.x; if (e>=E) return;
    int r = row[e], c = col[e];
    int pos = atomicAdd(&cursor[c], 1);
    csr_src[pos] = r;
    csr_nrm[pos] = dis[r] * (ew ? ew[e] : 1.f) * dis[c];
}

// O[i] = bias + dis[i]^2 * H[i] + sum_j nrm_j * H[src_j]   -- bf16 in/out, fp32 math
__global__ __launch_bounds__(256) void gcn_gather_k(
    const ushort* __restrict__ H, const int* __restrict__ rowptr,
    const int* __restrict__ csr_src, const float* __restrict__ csr_nrm,
    const float* __restrict__ dis, const float* __restrict__ bias,
    ushort* __restrict__ O, int N)
{
    int node = blockIdx.x*8 + (threadIdx.x >> 5);
    if (node >= N) return;
    int lane = (threadIdx.x & 31)*4;
    float s = dis[node]; s *= s;
    float4 h = b2f4(*(const ushort4*)(H + (size_t)node*128 + lane));
    float4 b = ld4(bias + lane);
    float4 acc = f4fma(s, h, b);
    int j = rowptr[node], end = rowptr[node+1];
    for (; j + 4 <= end; j += 4) {
        int   s0 = csr_src[j],   s1 = csr_src[j+1], s2 = csr_src[j+2], s3 = csr_src[j+3];
        float n0 = csr_nrm[j],   n1 = csr_nrm[j+1], n2 = csr_nrm[j+2], n3 = csr_nrm[j+3];
        float4 h0 = b2f4(*(const ushort4*)(H + (size_t)s0*128 + lane));
        float4 h1 = b2f4(*(const ushort4*)(H + (size_t)s1*128 + lane));
        float4 h2 = b2f4(*(const ushort4*)(H + (size_t)s2*128 + lane));
        float4 h3 = b2f4(*(const ushort4*)(H + (size_t)s3*128 + lane));
        acc = f4fma(n0, h0, acc);
        acc = f4fma(n1, h1, acc);
        acc = f4fma(n2, h2, acc);
        acc = f4fma(n3, h3, acc);
    }
    for (; j < end; ++j) {
        float4 h0 = b2f4(*(const ushort4*)(H + (size_t)csr_src[j]*128 + lane));
        acc = f4fma(csr_nrm[j], h0, acc);
    }
    *(ushort4*)(O + (size_t)node*128 + lane) = f2b4(acc);
}

// prepack 128x128 fp32 W into MFMA B-fragment-order bf16 [ct][ks][kg][col][j]
__global__ void wfragg_k(const float* __restrict__ W, ushort* __restrict__ out){
    int i = blockIdx.x*256 + threadIdx.x;
    if (i >= 16384) return;
    int j = i & 7, col = (i >> 3) & 15, kg = (i >> 7) & 3, ks = (i >> 9) & 3, ct = i >> 11;
    out[i] = f2b(W[(ks*32 + kg*8 + j)*128 + ct*16 + col]);
}

// O = relu(A) @ W via bf16 MFMA; A:[N,128] bf16, WF pre-fragged bf16, O bf16
__global__ __launch_bounds__(256) void gemm_mfma_k(
    const ushort* __restrict__ A, const ushort* __restrict__ WF,
    ushort* __restrict__ O, int N)
{
    __shared__ ushort WsF[16384];
    __shared__ ushort As[64*136];
    int t = threadIdx.x;
    for (int i = t; i < 2048; i += 256)
        *(ushort8v*)(WsF + i*8) = *(const ushort8v*)(WF + i*8);
    int row0 = blockIdx.x*64;
    for (int i = t; i < 64*32; i += 256) {
        int r = i >> 5, c4 = (i & 31)*4;
        ushort4 v = *(const ushort4*)(A + (size_t)(row0 + r)*128 + c4);
        v.x = (v.x & 0x8000) ? 0 : v.x;
        v.y = (v.y & 0x8000) ? 0 : v.y;
        v.z = (v.z & 0x8000) ? 0 : v.z;
        v.w = (v.w & 0x8000) ? 0 : v.w;
        *(ushort4*)(As + r*136 + c4) = v;
    }
    __syncthreads();
    int w = t >> 6, l = t & 63;
    int m16 = l & 15, kg = l >> 4;
    short8v af[4];
    #pragma unroll
    for (int ks = 0; ks < 4; ++ks)
        af[ks] = *(const short8v*)(As + (w*16 + m16)*136 + ks*32 + kg*8);
    #pragma unroll
    for (int ct = 0; ct < 8; ++ct) {
        f32x4 acc = {0.f, 0.f, 0.f, 0.f};
        #pragma unroll
        for (int ks = 0; ks < 4; ++ks) {
            short8v bf = *(const short8v*)(WsF + ((ct*4 + ks)*4 + kg)*128 + m16*8);
            acc = __builtin_amdgcn_mfma_f32_16x16x32_bf16(af[ks], bf, acc, 0, 0, 0);
        }
        int col = ct*16 + m16;
        int rbase = row0 + w*16 + kg*4;
        #pragma unroll
        for (int j = 0; j < 4; ++j)
            O[(size_t)(rbase + j)*128 + col] = f2b(acc[j]);
    }
}

// ---------------- mean pool (bf16 input): 4-way pipelined, LDS-direct accumulation ----
__global__ __launch_bounds__(128) void mean_pool_sum_k(
    const ushort* __restrict__ X, const int* __restrict__ bv,
    float* __restrict__ featp, int chunk, int N)
{
    __shared__ float acc[16*128];
    int t = threadIdx.x;
    #pragma unroll
    for (int b = 0; b < 16; ++b) acc[b*128 + t] = 0.f;
    int i0 = blockIdx.x * chunk;
    int iend = min(i0 + chunk, N);
    int i = i0;
    for (; i + 4 <= iend; i += 4) {
        int b0 = bv[i], b1 = bv[i+1], b2 = bv[i+2], b3 = bv[i+3];
        float v0 = fmaxf(b2f(X[(size_t)i*128 + t]),     0.f);
        float v1 = fmaxf(b2f(X[(size_t)(i+1)*128 + t]), 0.f);
        float v2 = fmaxf(b2f(X[(size_t)(i+2)*128 + t]), 0.f);
        float v3 = fmaxf(b2f(X[(size_t)(i+3)*128 + t]), 0.f);
        acc[b0*128 + t] += v0;
        acc[b1*128 + t] += v1;
        acc[b2*128 + t] += v2;
        acc[b3*128 + t] += v3;
    }
    for (; i < iend; ++i) {
        int b = bv[i];
        acc[b*128 + t] += fmaxf(b2f(X[(size_t)i*128 + t]), 0.f);
    }
    #pragma unroll
    for (int b = 0; b < 16; ++b) {
        float v = acc[b*128 + t];
        if (v != 0.f) unsafeAtomicAdd(featp + b*512 + t, v);
    }
}

__global__ void count_batch_k(const int* __restrict__ bv, float* __restrict__ cnt, int N){
    __shared__ int h[16];
    int t = threadIdx.x;
    if (t < 16) h[t] = 0;
    __syncthreads();
    int i = blockIdx.x*256 + t;
    if (i < N) atomicAdd(&h[bv[i]], 1);
    __syncthreads();
    if (t < 16 && h[t]) unsafeAtomicAdd(&cnt[t], (float)h[t]);
}

// ---------------- voxel fp32 NCDHW -> bf16 channels-last [n][64^3][2] ----------------
__global__ __launch_bounds__(256) void cvt_cl0_k(const float* __restrict__ vox, unsigned* __restrict__ out){
    int idx = blockIdx.x*256 + threadIdx.x;       // 16 * 262144
    int n = idx >> 18, v = idx & 262143;
    float a = vox[((size_t)n*2    )*262144 + v];
    float b = vox[((size_t)n*2 + 1)*262144 + v];
    out[idx] = (unsigned)f2b(a) | ((unsigned)f2b(b) << 16);
}

// conv1 weight prepack: k = rowIdx*16 + dx*4 + ci (ci padded 2->4, rows padded 9->10)
__global__ void wfrag1_k(const float* __restrict__ wt, ushort* __restrict__ out){
    int i = blockIdx.x*256 + threadIdx.x;
    if (i >= 2560) return;
    int j = i & 7, col = (i >> 3) & 15, kg = (i >> 7) & 3, ks = i >> 9;
    int rowIdx = ks*2 + (kg >> 1);
    int dx = (kg & 1)*2 + (j >> 2), ci = j & 3;
    ushort v = 0;
    if (rowIdx < 9 && dx < 3 && ci < 2)
        v = f2b(wt[(col*2 + ci)*27 + (rowIdx/3)*9 + (rowIdx%3)*3 + dx]);
    out[i] = v;
}

// conv1 implicit-GEMM MFMA: CL bf16 [n][64^3][2] -> pooled max/min CL [n][32^3][16]
__global__ __launch_bounds__(256) void conv1_mfma_k(
    const ushort* __restrict__ Xcl0, const ushort* __restrict__ wf,
    const float* __restrict__ bias,
    ushort* __restrict__ outmax, ushort* __restrict__ outmin, float* __restrict__ stats_part)
{
    __shared__ __align__(16) ushort Ast[2896];    // [10z][4y][18x][4ci-pad] (2880) + guard
    __shared__ __align__(16) ushort Bfr[2560];
    __shared__ float red[128];

    int tid = threadIdx.x;
    int n = blockIdx.y;
    int bx = blockIdx.x;
    int xb = bx & 3, yb = (bx >> 2) & 31, zb = bx >> 7;
    int w = tid >> 6, l = tid & 63;
    int col = l & 15, kg = l >> 4;

    for (int i = tid; i < 320; i += 256)
        *(ushort8v*)(Bfr + i*8) = *(const ushort8v*)(wf + i*8);
    for (int i = tid; i < 720; i += 256) {
        int z = i/72, r = i - z*72, y = r/18, x = r - y*18;
        int gz = zb*8 - 1 + z, gy = yb*2 - 1 + y, gx = xb*16 - 1 + x;
        unsigned packed = 0;
        if ((unsigned)gz < 64u && (unsigned)gy < 64u && (unsigned)gx < 64u)
            packed = *(const unsigned*)(Xcl0 + ((((size_t)n << 18) + ((gz*64 + gy)*64 + gx)) << 1));
        *(uint2*)(Ast + i*4) = make_uint2(packed, 0u);
    }
    if (tid < 2) *(uint2*)(Ast + 2880 + tid*4) = make_uint2(0u, 0u);
    __syncthreads();

    int halfoff = (kg & 1)*2;
    f32x4 acc[4];
    #pragma unroll
    for (int mt = 0; mt < 4; ++mt) acc[mt] = (f32x4){0.f,0.f,0.f,0.f};

    #pragma unroll
    for (int ks = 0; ks < 5; ++ks) {
        int rowIdx = ks*2 + (kg >> 1); if (rowIdx >= 9) rowIdx = 0;
        int kd = rowIdx/3, kh = rowIdx - kd*3;
        int off = kd*288 + kh*72 + (col + halfoff)*4;
        short8v bb = *(const short8v*)(Bfr + (ks*4 + kg)*128 + col*8);
        #pragma unroll
        for (int mt = 0; mt < 4; ++mt) {
            const ushort* p = Ast + (2*w + (mt>>1))*288 + (mt&1)*72 + off;
            short8v a = ld_a8(p);
            acc[mt] = __builtin_amdgcn_mfma_f32_16x16x32_bf16(a, bb, acc[mt], 0, 0, 0);
        }
    }

    int zp = zb*4 + w, yp = yb;
    float bl = bias[col];
    float s = 0.f, q = 0.f;
    float mx0=-1e30f, mx1=-1e30f, mn0=1e30f, mn1=1e30f;
    #pragma unroll
    for (int mt = 0; mt < 4; ++mt)
        #pragma unroll
        for (int j = 0; j < 4; ++j) {
            float v = acc[mt][j] + bl;
            s += v; q = fmaf(v, v, q);
            if (j < 2) { mx0 = fmaxf(mx0, v); mn0 = fminf(mn0, v); }
            else       { mx1 = fmaxf(mx1, v); mn1 = fminf(mn1, v); }
        }
    s += __shfl_xor(s, 16); s += __shfl_xor(s, 32);
    q += __shfl_xor(q, 16); q += __shfl_xor(q, 32);
    if (kg == 0) { red[(w*16 + col)*2] = s; red[(w*16 + col)*2 + 1] = q; }
    size_t ob = ((((size_t)(n*32 + zp))*32 + yp)*32 + xb*8 + kg*2)*16 + col;
    outmax[ob]      = f2b(mx0); outmin[ob]      = f2b(mn0);
    outmax[ob + 16] = f2b(mx1); outmin[ob + 16] = f2b(mn1);
    __syncthreads();
    if (tid < 32) {
        float t = red[tid] + red[32 + tid] + red[64 + tid] + red[96 + tid];
        unsafeAtomicAdd(&stats_part[((bx & 127) << 5) + tid], t);
    }
}

// sum partial stats -> final stats
__global__ void stats_reduce_k(const float* __restrict__ part, float* __restrict__ out,
                               int npart, int n)
{
    int c = blockIdx.x*64 + threadIdx.x;
    if (c >= n) return;
    float s = 0.f;
    for (int p = 0; p < npart; ++p) s += part[p*n + c];
    out[c] = s;
}

__global__ void bn_final_k(const float* __restrict__ stats, const float* __restrict__ g,
                           const float* __restrict__ b, float* __restrict__ sc, float* __restrict__ sh,
                           int C, float invN)
{
    int c = threadIdx.x; if (c >= C) return;
    float m = stats[c*2] * invN;
    float v = stats[c*2+1] * invN - m*m;
    float s = g[c] * rsqrtf(v + 1e-5f);
    sc[c] = s; sh[c] = b[c] - m*s;
}

// prepack conv weights into MFMA B-fragment order (bf16), K padded to 448 per ci-half
__global__ void wfrag_k(const float* __restrict__ wt, ushort* __restrict__ out,
                        int CIN, int COT, int total)
{
    int i = blockIdx.x*256 + threadIdx.x;
    if (i >= total) return;
    int per_h = COT*7168;
    int h  = i / per_h;
    int r0 = i - h*per_h;
    int ct = r0 / 7168;
    int r  = r0 - ct*7168;
    int ks = r >> 9;
    int r2 = r & 511;
    int kg = r2 >> 7, col = (r2 >> 3) & 15, j = r2 & 7;
    int k = ks*32 + kg*8 + j;
    int nbr = k >> 4, ci = (k & 15) + h*16;
    out[i] = (nbr < 27) ? f2b(wt[((size_t)(ct*16 + col)*CIN + ci)*27 + nbr]) : (ushort)0;
}

// ---------------- implicit-GEMM MFMA conv + bias + BN-stats(partial) + max/min pool ----
template<int CIHALVES, int COT, int D, int CIN, int COUT>
__global__ __launch_bounds__(256) void conv_mfma_k(
    const ushort* __restrict__ Xcl, const ushort* __restrict__ WfragG,
    const float* __restrict__ bias,
    ushort* __restrict__ outmax, ushort* __restrict__ outmin,
    float* __restrict__ stats_part, int pmask)
{
    constexpr int PD = D/2;
    constexpr int XT = D/16, YT = D/2;
    __shared__ __align__(16) ushort Ast[17280];
    __shared__ __align__(16) ushort Bfr[COT*7168];
    __shared__ float red[4*COT*32];

    int tid = threadIdx.x;
    int n = blockIdx.y;
    int bx = blockIdx.x;
    int xb = bx % XT, yb = (bx/XT) % YT, zb = bx/(XT*YT);
    int w = tid >> 6, l = tid & 63;
    int col = l & 15, kg = l >> 4;

    int laneoff[14];
    #pragma unroll
    for (int ks = 0; ks < 14; ++ks) {
        int nbr = ks*2 + (l >> 5);
        if (nbr >= 27) nbr = 0;
        int dz = nbr/9, r9 = nbr - dz*9, dy = r9/3, dx = r9 - dy*3;
        laneoff[ks] = dz*1728 + dy*432 + (col + dx)*24 + ((l>>4)&1)*8;
    }
    int Mbase[4];
    #pragma unroll
    for (int mt = 0; mt < 4; ++mt)
        Mbase[mt] = (2*w + (mt>>1))*1728 + (mt&1)*432;

    f32x4 acc[4][COT];
    #pragma unroll
    for (int mt = 0; mt < 4; ++mt)
        #pragma unroll
        for (int ct = 0; ct < COT; ++ct)
            acc[mt][ct] = (f32x4){0.f,0.f,0.f,0.f};

    for (int h = 0; h < CIHALVES; ++h) {
        __syncthreads();
        for (int i = tid; i < 1440; i += 256) {
            int vec = i >> 1, hi8 = (i & 1) << 3;
            int z = vec/72, r = vec - z*72, y = r/18, x = r - y*18;
            int gz = zb*8 - 1 + z, gy = yb*2 - 1 + y, gx = xb*16 - 1 + x;
            ushort8v val = {0,0,0,0,0,0,0,0};
            if ((unsigned)gz < (unsigned)D && (unsigned)gy < (unsigned)D && (unsigned)gx < (unsigned)D) {
                size_t gi = (((size_t)n*D*D*D) + ((size_t)gz*D + gy)*D + gx)*CIN + h*16 + hi8;
                val = *(const ushort8v*)(Xcl + gi);
            }
            *(ushort8v*)(Ast + (vec)*24 + hi8) = val;
        }
        for (int i = tid; i < COT*896; i += 256)
            *(ushort8v*)(Bfr + i*8) = *(const ushort8v*)(WfragG + (size_t)h*COT*7168 + i*8);
        __syncthreads();

        #pragma unroll
        for (int ks = 0; ks < 14; ++ks) {
            short8v a[4];
            #pragma unroll
            for (int mt = 0; mt < 4; ++mt)
                a[mt] = *(const short8v*)(Ast + Mbase[mt] + laneoff[ks]);
            short8v bb[COT];
            #pragma unroll
            for (int ct = 0; ct < COT; ++ct)
                bb[ct] = *(const short8v*)(Bfr + ct*7168 + ks*512 + kg*128 + col*8);
            #pragma unroll
            for (int mt = 0; mt < 4; ++mt)
                #pragma unroll
                for (int ct = 0; ct < COT; ++ct)
                    acc[mt][ct] = __builtin_amdgcn_mfma_f32_16x16x32_bf16(a[mt], bb[ct], acc[mt][ct], 0, 0, 0);
        }
    }

    int zp = zb*4 + w, yp = yb;
    #pragma unroll
    for (int ct = 0; ct < COT; ++ct) {
        float bl = bias[ct*16 + col];
        float s = 0.f, q = 0.f;
        float mx0 = -1e30f, mx1 = -1e30f, mn0 = 1e30f, mn1 = 1e30f;
        #pragma unroll
        for (int mt = 0; mt < 4; ++mt) {
            #pragma unroll
            for (int j = 0; j < 4; ++j) {
                float v = acc[mt][ct][j] + bl;
                s += v; q = fmaf(v, v, q);
                if (j < 2) { mx0 = fmaxf(mx0, v); mn0 = fminf(mn0, v); }
                else       { mx1 = fmaxf(mx1, v); mn1 = fminf(mn1, v); }
            }
        }
        s += __shfl_xor(s, 16); s += __shfl_xor(s, 32);
        q += __shfl_xor(q, 16); q += __shfl_xor(q, 32);
        if (kg == 0) {
            red[((w*COT + ct)*16 + col)*2]     = s;
            red[((w*COT + ct)*16 + col)*2 + 1] = q;
        }
        size_t ob = (((size_t)((n*PD + zp)*PD + yp))*PD + xb*8 + kg*2)*COUT + ct*16 + col;
        outmax[ob]        = f2b(mx0);
        outmin[ob]        = f2b(mn0);
        outmax[ob + COUT] = f2b(mx1);
        outmin[ob + COUT] = f2b(mn1);
    }
    __syncthreads();
    if (tid < COT*32) {
        float t = red[tid] + red[COT*32 + tid] + red[2*COT*32 + tid] + red[3*COT*32 + tid];
        unsafeAtomicAdd(&stats_part[(bx & pmask)*(COT*32) + tid], t);
    }
}

// channels-last bf16 pooled max/min -> BN+ReLU -> bf16
__global__ __launch_bounds__(256) void bn_select_cl23_k(
    const ushort* __restrict__ mx, const ushort* __restrict__ mn,
    const float* __restrict__ sc, const float* __restrict__ sh,
    ushort* __restrict__ out, int cmask, int total)
{
    int idx = blockIdx.x*256 + threadIdx.x;
    if (idx >= total) return;
    int ci = idx & cmask;
    float s = sc[ci];
    float v = b2f((s >= 0.f) ? mx[idx] : mn[idx]);
    out[idx] = f2b(fmaxf(fmaf(v, s, sh[ci]), 0.f));
}

// fc: X channels-last bf16 [16][512][64] @ W[32768,128] -> 8 partial slices
__global__ __launch_bounds__(128) void fc_acc2_k(
    const ushort* __restrict__ X, const float* __restrict__ W, float* __restrict__ part)
{
    __shared__ float Xs[16*64];
    int t = threadIdx.x;
    int bx = blockIdx.x;
    int k0 = bx*64;
    int c0 = k0 >> 9, sp0 = k0 & 511;
    for (int i = t; i < 1024; i += 128) {
        int b = i >> 6, spo = i & 63;
        Xs[b*64 + spo] = b2f(X[(size_t)(b*512 + sp0 + spo)*64 + c0]);
    }
    __syncthreads();
    float acc[16];
    #pragma unroll
    for (int b = 0; b < 16; ++b) acc[b] = 0.f;
    #pragma unroll 4
    for (int kk = 0; kk < 64; ++kk) {
        float w = W[(size_t)(k0 + kk)*128 + t];
        #pragma unroll
        for (int b = 0; b < 16; ++b) acc[b] = fmaf(Xs[b*64 + kk], w, acc[b]);
    }
    float* pp = part + (bx & 7)*2048;
    #pragma unroll
    for (int b = 0; b < 16; ++b) unsafeAtomicAdd(pp + b*128 + t, acc[b]);
}

// sum fc partials -> feat[:,384:512]
__global__ void fc_reduce_k(const float* __restrict__ part, float* __restrict__ feat)
{
    int i = blockIdx.x*256 + threadIdx.x;    // 2048
    if (i >= 2048) return;
    int b = i >> 7, t = i & 127;
    float s = 0.f;
    #pragma unroll
    for (int p = 0; p < 8; ++p) s += part[p*2048 + b*128 + t];
    feat[b*512 + 384 + t] = s;
}

// ---------------- dense head layers: K-parallel (4 kgroups x 64 cols), 4-deep MLP -----
__global__ __launch_bounds__(256) void head2_k(
    const float* __restrict__ X, const float* __restrict__ W, const float* __restrict__ b,
    float* __restrict__ O, int K, int Ncol, int relu)
{
    __shared__ float Xs[512*16];      // transposed: [k][bi]
    __shared__ float red[3*16*64];
    int t = threadIdx.x;
    int kg = t >> 6, lane = t & 63;
    int c = blockIdx.x*64 + lane;
    bool valid = (c < Ncol);
    for (int i = t; i < 16*K; i += 256) {
        int bi = i & 15, k = i >> 4;
        Xs[k*16 + bi] = X[bi*K + k];
    }
    __syncthreads();
    float acc[16];
    #pragma unroll
    for (int bi = 0; bi < 16; ++bi) acc[bi] = 0.f;
    int k = kg;
    for (; k + 12 < K; k += 16) {
        float w0 = valid ? W[(size_t)k*Ncol + c] : 0.f;
        float w1 = valid ? W[(size_t)(k+4)*Ncol + c] : 0.f;
        float w2 = valid ? W[(size_t)(k+8)*Ncol + c] : 0.f;
        float w3 = valid ? W[(size_t)(k+12)*Ncol + c] : 0.f;
        const float* xp0 = Xs + k*16;
        const float* xp1 = Xs + (k+4)*16;
        const float* xp2 = Xs + (k+8)*16;
        const float* xp3 = Xs + (k+12)*16;
        #pragma unroll
        for (int bi = 0; bi < 16; ++bi) {
            acc[bi] = fmaf(xp0[bi], w0, acc[bi]);
            acc[bi] = fmaf(xp1[bi], w1, acc[bi]);
            acc[bi] = fmaf(xp2[bi], w2, acc[bi]);
            acc[bi] = fmaf(xp3[bi], w3, acc[bi]);
        }
    }
    for (; k < K; k += 4) {
        float w = valid ? W[(size_t)k*Ncol + c] : 0.f;
        const float* xp = Xs + k*16;
        #pragma unroll
        for (int bi = 0; bi < 16; ++bi) acc[bi] = fmaf(xp[bi], w, acc[bi]);
    }
    if (kg) {
        #pragma unroll
        for (int bi = 0; bi < 16; ++bi) red[((kg-1)*16 + bi)*64 + lane] = acc[bi];
    }
    __syncthreads();
    if (kg == 0 && valid) {
        float bias = b[c];
        #pragma unroll
        for (int bi = 0; bi < 16; ++bi) {
            float v = acc[bi] + red[bi*64 + lane] + red[(16 + bi)*64 + lane]
                    + red[(32 + bi)*64 + lane] + bias;
            if (relu) v = fmaxf(v, 0.f);
            O[bi*Ncol + c] = v;
        }
    }
}

__global__ void gebn_k(const float* __restrict__ g2, const float* __restrict__ g,
                       const float* __restrict__ b, float* __restrict__ featg)
{
    int c = threadIdx.x;
    float m = 0.f;
    for (int i = 0; i < 16; ++i) m += g2[i*128 + c];
    m *= (1.f/16.f);
    float v = 0.f;
    for (int i = 0; i < 16; ++i) { float d = g2[i*128 + c] - m; v += d*d; }
    v *= (1.f/16.f);
    float s = g[c] * rsqrtf(v + 1e-5f);
    for (int i = 0; i < 16; ++i)
        featg[i*512 + c] = fmaxf((g2[i*128 + c] - m)*s + b[c], 0.f);
}

__global__ void finalize_feat_k(float* __restrict__ feat, const float* __restrict__ cntm,
                                const float* __restrict__ cntz, const float* __restrict__ fcb)
{
    int t = blockIdx.x*256 + threadIdx.x;
    if (t >= 8192) return;
    int bi = t >> 9, c = t & 511;
    float v = feat[t];
    if      (c < 128) v /= fmaxf(cntm[bi], 1.f);
    else if (c < 256) v /= fmaxf(cntz[bi], 1.f);
    else if (c >= 384) v = fmaxf(v + fcb[c - 384], 0.f);
    feat[t] = v;
}

// =====================================================================================
extern "C" void kernel_launch(void* const* d_in, const int* in_sizes, int n_in,
                              void* d_out, int out_size, void* d_ws, size_t ws_size,
                              hipStream_t stream)
{
    const int*   mol_x  = (const int*)  d_in[0];
    const float* mol_q  = (const float*)d_in[1];
    const int*   mol_ei = (const int*)  d_in[2];
    const float* mol_ew = (const float*)d_in[3];
    const int*   mol_bv = (const int*)  d_in[4];
    const int*   zeo_x  = (const int*)  d_in[5];
    const int*   zeo_ei = (const int*)  d_in[6];
    const int*   zeo_bv = (const int*)  d_in[7];
    const float* voxel  = (const float*)d_in[8];
    const float* gattr  = (const float*)d_in[9];
    const float* ea  = (const float*)d_in[10];
    const float* ed  = (const float*)d_in[11];
    const float* ec  = (const float*)d_in[12];
    const float* eh  = (const float*)d_in[13];
    const float* ear = (const float*)d_in[14];
    const float* ech = (const float*)d_in[15];
    const float* mc1w=(const float*)d_in[16]; const float* mc1b=(const float*)d_in[17];
    const float* mc2w=(const float*)d_in[18]; const float* mc2b=(const float*)d_in[19];
    const float* zc1w=(const float*)d_in[20]; const float* zc1b=(const float*)d_in[21];
    const float* zc2w=(const float*)d_in[22]; const float* zc2b=(const float*)d_in[23];
    const float* cv1w=(const float*)d_in[24]; const float* cv1b=(const float*)d_in[25];
    const float* bn1g=(const float*)d_in[26]; const float* bn1b=(const float*)d_in[27];
    const float* cv2w=(const float*)d_in[28]; const float* cv2b=(const float*)d_in[29];
    const float* bn2g=(const float*)d_in[30]; const float* bn2b=(const float*)d_in[31];
    const float* cv3w=(const float*)d_in[32]; const float* cv3b=(const float*)d_in[33];
    const float* bn3g=(const float*)d_in[34]; const float* bn3b=(const float*)d_in[35];
    const float* fcw =(const float*)d_in[36]; const float* fcb =(const float*)d_in[37];
    const float* ge1w=(const float*)d_in[38]; const float* ge1b=(const float*)d_in[39];
    const float* ge2w=(const float*)d_in[40]; const float* ge2b=(const float*)d_in[41];
    const float* gbng=(const float*)d_in[42]; const float* gbnb=(const float*)d_in[43];
    const float* h1w =(const float*)d_in[44]; const float* h1b =(const float*)d_in[45];
    const float* h2w =(const float*)d_in[46]; const float* h2b =(const float*)d_in[47];
    const float* h3w =(const float*)d_in[48]; const float* h3b =(const float*)d_in[49];

    const int Nm = in_sizes[0]/6, Em = in_sizes[2]/2;
    const int Nz = in_sizes[5]/6, Ez = in_sizes[6]/2;
    const int NBm = (Nm + 1023)/1024, NBz = (Nz + 1023)/1024;

    float* WS = (float*)d_ws;
    float* A  = WS;
    float* Bb = WS + 16777216;
    float* S  = WS + 33554432;
    ushort* X0 = (ushort*)A;
    ushort* X1 = (ushort*)A + 16777216;
    ushort* X2 = (ushort*)Bb;
    ushort* X3 = (ushort*)Bb + 16777216;
    // conv-phase channels-last bf16 buffers (GNN buffers dead by then)
    ushort* Au   = (ushort*)A;
    ushort* pm1  = Au;                      // [16][32^3][16]
    ushort* pn1  = Au + 8388608;
    ushort* Xcl0 = Au + 16777216;           // [16][64^3][2]
    ushort* Xcl1 = (ushort*)Bb;             // [16][32^3][16]
    ushort* pm2  = Au;                      // [16][16^3][32]
    ushort* pn2  = Au + 2097152;
    ushort* Xcl2 = Au + 4194304;
    ushort* pm3  = (ushort*)Bb;             // [16][8^3][64]
    ushort* pn3  = (ushort*)Bb + 524288;
    ushort* Xcl3 = (ushort*)Bb + 1048576;
    float* deg  = S;
    float* dis  = S + 131072;
    float* csr_nrm = S + 262144;
    float* T    = S + 786432;
    float* cntm = S + 807040;
    float* cntz = S + 807056;
    float* feat = S + 807072;
    float* st1  = S + 815264; float* st2 = st1 + 32; float* st3 = st1 + 96;
    float* sc1  = S + 815488; float* sh1 = sc1 + 16;
    float* sc2  = sc1 + 32;   float* sh2 = sc1 + 64;
    float* sc3  = sc1 + 96;   float* sh3 = sc1 + 160;
    float* g1   = S + 815712;
    float* g2   = S + 816736;
    float* H1   = S + 818784;
    float* H2   = S + 826976;
    int* rowptr  = (int*)(S + 831072);          // 131073
    int* cursor  = (int*)(S + 962176);          // 131072
    int* csr_src = (int*)(S + 1093248);         // 524288 (ends S+1617536)
    ushort* wf2 = (ushort*)(S + 1617536);       // 14336 ush
    ushort* wf3 = (ushort*)(S + 1624704);       // 57344 ush
    int* bsum   = (int*)(S + 1653376);          // 256 ints
    ushort* wf1 = (ushort*)(S + 1653632);       // 2560 ush
    float* stp1 = S + 1655040;                  // 128*32
    float* stp2 = S + 1659136;                  // 32*64
    float* stp3 = S + 1661184;                  // 8*128 (ends S+1662208)
    float* fcpart = S + 1662208;                // 8*2048 (ends S+1678592)
    ushort* wfgm = (ushort*)(S + 1678592);      // 16384 ush (8192 f)
    ushort* wfgz = (ushort*)(S + 1686784);      // 16384 ush (ends S+1694976)

    hipMemsetAsync(S, 0, (size_t)831072*sizeof(float), stream);
    hipMemsetAsync(stp1, 0, (size_t)(7168 + 16384)*sizeof(float), stream);  // stp1..3 + fcpart

    // weight prepacks (conv + gemm)
    wfrag1_k<<<10,256,0,stream>>>(cv1w, wf1);
    wfrag_k<<<56,256,0,stream>>>(cv2w, wf2, 16, 2, 14336);
    wfrag_k<<<224,256,0,stream>>>(cv3w, wf3, 32, 4, 57344);
    wfragg_k<<<64,256,0,stream>>>(mc2w, wfgm);
    wfragg_k<<<64,256,0,stream>>>(zc2w, wfgz);

    // ---------------- molecule branch ----------------
    build_tables_k<<<161,128,0,stream>>>(ea,ed,ec,eh,ear,ech, mc1w, T);
    init_deg_k   <<<Nm/256,256,0,stream>>>(deg, Nm);
    deg_scatter_k<<<Em/256,256,0,stream>>>(mol_ei+Em, mol_ew, deg, Em);
    dis_k        <<<Nm/256,256,0,stream>>>(deg, dis, Nm);
    hipMemsetAsync(cursor, 0, (size_t)Nm*sizeof(int), stream);
    count_in_k   <<<Em/256,256,0,stream>>>(mol_ei+Em, cursor, Em);
    blocksum_k   <<<NBm,256,0,stream>>>(cursor, bsum, Nm);
    scan_bsum_k  <<<1,256,0,stream>>>(bsum, NBm);
    scan_apply_k <<<NBm,256,0,stream>>>(cursor, bsum, rowptr, Nm, Em);
    fill_csr_k   <<<Em/256,256,0,stream>>>(mol_ei, mol_ei+Em, mol_ew, dis, cursor, csr_src, csr_nrm, Em);
    embed_lookup_k<<<Nm/8,256,0,stream>>>(mol_x, mol_q, T, mc1w + 112*128, X0, Nm);
    gcn_gather_k <<<Nm/8,256,0,stream>>>(X0, rowptr, csr_src, csr_nrm, dis, mc1b, X1, Nm);
    gemm_mfma_k  <<<Nm/64,256,0,stream>>>(X1, wfgm, X2, Nm);
    gcn_gather_k <<<Nm/8,256,0,stream>>>(X2, rowptr, csr_src, csr_nrm, dis, mc2b, X3, Nm);
    count_batch_k<<<Nm/256,256,0,stream>>>(mol_bv, cntm, Nm);
    mean_pool_sum_k<<<2048,128,0,stream>>>(X3, mol_bv, feat + 0, (Nm+2047)/2048, Nm);

    // ---------------- zeolite branch ----------------
    build_tables_k<<<161,128,0,stream>>>(ea,ed,ec,eh,ear,ech, zc1w, T);
    init_deg_k   <<<Nz/256,256,0,stream>>>(deg, Nz);
    deg_scatter_k<<<Ez/256,256,0,stream>>>(zeo_ei+Ez, nullptr, deg, Ez);
    dis_k        <<<Nz/256,256,0,stream>>>(deg, dis, Nz);
    hipMemsetAsync(cursor, 0, (size_t)Nz*sizeof(int), stream);
    count_in_k   <<<Ez/256,256,0,stream>>>(zeo_ei+Ez, cursor, Ez);
    blocksum_k   <<<NBz,256,0,stream>>>(cursor, bsum, Nz);
    scan_bsum_k  <<<1,256,0,stream>>>(bsum, NBz);
    scan_apply_k <<<NBz,256,0,stream>>>(cursor, bsum, rowptr, Nz, Ez);
    fill_csr_k   <<<Ez/256,256,0,stream>>>(zeo_ei, zeo_ei+Ez, nullptr, dis, cursor, csr_src, csr_nrm, Ez);
    embed_lookup_k<<<Nz/8,256,0,stream>>>(zeo_x, nullptr, T, nullptr, X0, Nz);
    gcn_gather_k <<<Nz/8,256,0,stream>>>(X0, rowptr, csr_src, csr_nrm, dis, zc1b, X1, Nz);
    gemm_mfma_k  <<<Nz/64,256,0,stream>>>(X1, wfgz, X2, Nz);
    gcn_gather_k <<<Nz/8,256,0,stream>>>(X2, rowptr, csr_src, csr_nrm, dis, zc2b, X3, Nz);
    count_batch_k<<<Nz/256,256,0,stream>>>(zeo_bv, cntz, Nz);
    mean_pool_sum_k<<<2048,128,0,stream>>>(X3, zeo_bv, feat + 128, (Nz+2047)/2048, Nz);

    // ---------------- voxel CNN (all layers MFMA implicit-GEMM) ----------------
    cvt_cl0_k<<<16384,256,0,stream>>>(voxel, (unsigned*)Xcl0);
    conv1_mfma_k<<<dim3(1024,16),256,0,stream>>>(Xcl0, wf1, cv1b, pm1, pn1, stp1);
    stats_reduce_k<<<1,64,0,stream>>>(stp1, st1, 128, 32);
    bn_final_k<<<1,64,0,stream>>>(st1, bn1g, bn1b, sc1, sh1, 16, 1.f/(16.f*262144.f));
    bn_select_cl23_k<<<32768,256,0,stream>>>(pm1, pn1, sc1, sh1, Xcl1, 15, 8388608);

    conv_mfma_k<1,2,32,16,32><<<dim3(128,16),256,0,stream>>>(Xcl1, wf2, cv2b, pm2, pn2, stp2, 31);
    stats_reduce_k<<<1,64,0,stream>>>(stp2, st2, 32, 64);
    bn_final_k<<<1,64,0,stream>>>(st2, bn2g, bn2b, sc2, sh2, 32, 1.f/(16.f*32768.f));
    bn_select_cl23_k<<<8192,256,0,stream>>>(pm2, pn2, sc2, sh2, Xcl2, 31, 2097152);

    conv_mfma_k<2,4,16,32,64><<<dim3(16,16),256,0,stream>>>(Xcl2, wf3, cv3b, pm3, pn3, stp3, 7);
    stats_reduce_k<<<2,64,0,stream>>>(stp3, st3, 8, 128);
    bn_final_k<<<1,64,0,stream>>>(st3, bn3g, bn3b, sc3, sh3, 64, 1.f/(16.f*4096.f));
    bn_select_cl23_k<<<2048,256,0,stream>>>(pm3, pn3, sc3, sh3, Xcl3, 63, 524288);

    fc_acc2_k<<<512,128,0,stream>>>(Xcl3, fcw, fcpart);
    fc_reduce_k<<<8,256,0,stream>>>(fcpart, feat);

    // ---------------- global encoder ----------------
    head2_k<<<1,256,0,stream>>>(gattr, ge1w, ge1b, g1, 17, 64, 1);
    head2_k<<<2,256,0,stream>>>(g1, ge2w, ge2b, g2, 64, 128, 0);
    gebn_k<<<1,128,0,stream>>>(g2, gbng, gbnb, feat + 256);

    // ---------------- fusion head ----------------
    finalize_feat_k<<<32,256,0,stream>>>(feat, cntm, cntz, fcb);
    head2_k<<<8,256,0,stream>>>(feat, h1w, h1b, H1, 512, 512, 1);
    head2_k<<<4,256,0,stream>>>(H1, h2w, h2b, H2, 512, 256, 1);
    head2_k<<<1,256,0,stream>>>(H2, h3w, h3b, (float*)d_out, 256, 3, 0);
}